// Round 5
// baseline (1241.617 us; speedup 1.0000x reference)
//
#include <hip/hip_runtime.h>
#include <hip/hip_bf16.h>

// Problem constants (fixed by setup_inputs)
constexpr int B    = 4;
constexpr int CIN  = 512;
constexpr int NN   = 4096;
constexpr int CI   = 128;   // inter_channels
constexpr int CQ   = 32;    // PAM q/k dim
constexpr int COUT = 256;

// ---------------------------------------------------------------------------
// Generic 1x1-conv GEMM: Y[b,co,n] = epilogue( sum_k W[co,k] * X[b,k,n] )
// epilogue: v = acc + bias[co]; if RELU v=max(v,0); v *= gamma; v += resid
// Tile 64(co) x 64(n), BK=16, 256 threads, 4x4 per-thread register tile.
// W may be per-batch (wbs = per-batch element stride, 0 for shared weights).
// ---------------------------------------------------------------------------
template<bool RELU>
__global__ __launch_bounds__(256) void gemm1x1(
    const float* __restrict__ W, long wbs,
    const float* __restrict__ X, const float* __restrict__ X2,
    float* __restrict__ Y,
    const float* __restrict__ bias,
    const float* __restrict__ gamma_ptr,
    const float* __restrict__ resid,
    int Co, int K, int N)
{
    const int b   = blockIdx.z;
    const int n0  = blockIdx.x * 64;
    const int co0 = blockIdx.y * 64;
    const float* Wb = W + (size_t)b * wbs;
    const float* Xb = X + (size_t)b * K * N;
    const float* X2b = X2 ? (X2 + (size_t)b * K * N) : nullptr;
    const size_t ybase = (size_t)b * Co * N;

    __shared__ float Ws[16][65];   // [k][co]
    __shared__ float Xs[16][65];   // [k][n]

    float acc[4][4] = {};
    const int t  = threadIdx.x;
    const int ty = t >> 4;   // 0..15 (co dim)
    const int tx = t & 15;   // 0..15 (n dim)

    for (int kb = 0; kb < K; kb += 16) {
        // W tile [64co][16k] -> Ws[k][co]; coalesced along K
        #pragma unroll
        for (int idx = t; idx < 1024; idx += 256) {
            int a = idx >> 4, c = idx & 15;
            int co = co0 + a;
            Ws[c][a] = (co < Co) ? Wb[(size_t)co * K + kb + c] : 0.f;
        }
        // X tile [16k][64n] -> Xs[k][n]; coalesced along n
        #pragma unroll
        for (int idx = t; idx < 1024; idx += 256) {
            int r = idx >> 6, j = idx & 63;
            size_t off = (size_t)(kb + r) * N + n0 + j;
            float xv = Xb[off];
            if (X2b) xv += X2b[off];
            Xs[r][j] = xv;
        }
        __syncthreads();
        #pragma unroll
        for (int kk = 0; kk < 16; ++kk) {
            float wv[4], xv[4];
            #pragma unroll
            for (int i = 0; i < 4; ++i) wv[i] = Ws[kk][ty + 16 * i];
            #pragma unroll
            for (int j = 0; j < 4; ++j) xv[j] = Xs[kk][tx + 16 * j];
            #pragma unroll
            for (int i = 0; i < 4; ++i)
                #pragma unroll
                for (int j = 0; j < 4; ++j)
                    acc[i][j] += wv[i] * xv[j];
        }
        __syncthreads();
    }

    const float g = gamma_ptr ? *gamma_ptr : 1.f;
    #pragma unroll
    for (int i = 0; i < 4; ++i) {
        int co = co0 + ty + 16 * i;
        if (co >= Co) continue;
        float bv = bias ? bias[co] : 0.f;
        #pragma unroll
        for (int j = 0; j < 4; ++j) {
            int n = n0 + tx + 16 * j;
            float val = acc[i][j] + bv;
            if (RELU) val = fmaxf(val, 0.f);
            val *= g;
            size_t off = ybase + (size_t)co * N + n;
            if (resid) val += resid[off];
            Y[off] = val;
        }
    }
}

// ---------------------------------------------------------------------------
// PAM flash attention.
// q,k: [B,32,N]  v: [B,128,N]  f1 residual: [B,128,N]
// sa[b,c,n] = gamma * sum_m softmax_m(sum_c' q[c',n]k[c',m]) * v[c,m] + f1[b,c,n]
// One block = 32 query rows (n), 256 threads, iterate m in tiles of 32.
// ---------------------------------------------------------------------------
__global__ __launch_bounds__(256) void pam_flash(
    const float* __restrict__ q, const float* __restrict__ k,
    const float* __restrict__ v, const float* __restrict__ f1,
    const float* __restrict__ gamma_ptr,
    float* __restrict__ sa, int N)
{
    const int b  = blockIdx.y;
    const int n0 = blockIdx.x * 32;
    const float* qb = q + (size_t)b * CQ * N;
    const float* kb = k + (size_t)b * CQ * N;
    const float* vb = v + (size_t)b * CI * N;

    __shared__ float qs[32][33];   // [row r][c]
    __shared__ float ks[32][33];   // [m][c]
    __shared__ float vs[128][33];  // [c][mm]
    __shared__ float ps[32][33];   // [r][mm]
    __shared__ float mrow[32], lrow[32], srow[32];

    const int t = threadIdx.x;
    // score phase mapping
    const int sr  = t >> 3;          // row 0..31
    const int sm0 = (t & 7) * 4;     // 4 m's per thread
    // PV phase mapping
    const int rg = t & 7;            // row group: rows rg*4..rg*4+3
    const int cg = t >> 3;           // col group: cols cg, cg+32, cg+64, cg+96

    for (int idx = t; idx < 32 * 32; idx += 256) {
        int c = idx >> 5, r = idx & 31;
        qs[r][c] = qb[(size_t)c * N + n0 + r];
    }
    if (t < 32) { mrow[t] = -1e30f; lrow[t] = 0.f; srow[t] = 0.f; }
    float acc[4][4] = {};
    __syncthreads();

    for (int m0 = 0; m0 < N; m0 += 32) {
        // stage K and V tiles
        for (int idx = t; idx < 32 * 32; idx += 256) {
            int c = idx >> 5, mm = idx & 31;
            ks[mm][c] = kb[(size_t)c * N + m0 + mm];
        }
        for (int idx = t; idx < 128 * 32; idx += 256) {
            int c = idx >> 5, mm = idx & 31;
            vs[c][mm] = vb[(size_t)c * N + m0 + mm];
        }
        __syncthreads();

        // scores for 4 m's of this thread's row
        float s[4] = {};
        #pragma unroll
        for (int c = 0; c < 32; ++c) {
            float qv = qs[sr][c];
            #pragma unroll
            for (int j = 0; j < 4; ++j) s[j] += qv * ks[sm0 + j][c];
        }
        float tmax = fmaxf(fmaxf(s[0], s[1]), fmaxf(s[2], s[3]));
        #pragma unroll
        for (int off = 1; off < 8; off <<= 1) tmax = fmaxf(tmax, __shfl_xor(tmax, off));
        const float mold = mrow[sr];
        const float mnew = fmaxf(mold, tmax);
        float p[4], psum = 0.f;
        #pragma unroll
        for (int j = 0; j < 4; ++j) { p[j] = __expf(s[j] - mnew); psum += p[j]; }
        #pragma unroll
        for (int off = 1; off < 8; off <<= 1) psum += __shfl_xor(psum, off);
        const float scale = __expf(mold - mnew);
        if ((t & 7) == 0) {
            mrow[sr] = mnew;
            lrow[sr] = lrow[sr] * scale + psum;
            srow[sr] = scale;
        }
        #pragma unroll
        for (int j = 0; j < 4; ++j) ps[sr][sm0 + j] = p[j];
        __syncthreads();

        // PV accumulate: out[r][c] += p[r][m] * v[c][m]
        float scl[4];
        #pragma unroll
        for (int rr = 0; rr < 4; ++rr) scl[rr] = srow[rg * 4 + rr];
        #pragma unroll
        for (int rr = 0; rr < 4; ++rr)
            #pragma unroll
            for (int cc = 0; cc < 4; ++cc) acc[rr][cc] *= scl[rr];
        #pragma unroll
        for (int mm = 0; mm < 32; ++mm) {
            float pv[4], vv[4];
            #pragma unroll
            for (int rr = 0; rr < 4; ++rr) pv[rr] = ps[rg * 4 + rr][mm];
            #pragma unroll
            for (int cc = 0; cc < 4; ++cc) vv[cc] = vs[cg + 32 * cc][mm];
            #pragma unroll
            for (int rr = 0; rr < 4; ++rr)
                #pragma unroll
                for (int cc = 0; cc < 4; ++cc) acc[rr][cc] += pv[rr] * vv[cc];
        }
        __syncthreads();
    }

    const float g = *gamma_ptr;
    float linv[4];
    #pragma unroll
    for (int rr = 0; rr < 4; ++rr) linv[rr] = 1.f / lrow[rg * 4 + rr];
    #pragma unroll
    for (int rr = 0; rr < 4; ++rr) {
        int r = rg * 4 + rr;
        #pragma unroll
        for (int cc = 0; cc < 4; ++cc) {
            int c = cg + 32 * cc;
            size_t off = ((size_t)(b * CI + c)) * N + n0 + r;
            sa[off] = g * acc[rr][cc] * linv[rr] + f1[off];
        }
    }
}

// ---------------------------------------------------------------------------
// CAM energy: e[b,i,j] = sum_n f2[b,i,n] * f2[b,j,n]   (128x128 per batch)
// ---------------------------------------------------------------------------
__global__ __launch_bounds__(256) void cam_energy(
    const float* __restrict__ f2, float* __restrict__ e, int N)
{
    const int b  = blockIdx.z;
    const int i0 = blockIdx.y * 16;
    const int j0 = blockIdx.x * 16;
    const float* fb = f2 + (size_t)b * CI * N;
    __shared__ float fa[16][129], fbs[16][129];
    const int t = threadIdx.x;
    const int ti = t >> 4, tj = t & 15;
    float acc = 0.f;
    for (int nb = 0; nb < N; nb += 128) {
        for (int idx = t; idx < 16 * 128; idx += 256) {
            int r = idx >> 7, c = idx & 127;
            fa[r][c]  = fb[(size_t)(i0 + r) * N + nb + c];
            fbs[r][c] = fb[(size_t)(j0 + r) * N + nb + c];
        }
        __syncthreads();
        #pragma unroll 8
        for (int c = 0; c < 128; ++c) acc += fa[ti][c] * fbs[tj][c];
        __syncthreads();
    }
    e[((size_t)b * CI + i0 + ti) * CI + j0 + tj] = acc;
}

// ---------------------------------------------------------------------------
// CAM softmax: attn[row, j] = exp(rowmin - e[row,j]) / sum_j exp(rowmin - e[row,j])
// (softmax(rowmax - e) simplifies: the rowmax cancels)
// ---------------------------------------------------------------------------
__global__ __launch_bounds__(64) void cam_softmax(
    const float* __restrict__ e, float* __restrict__ attn)
{
    const int row = blockIdx.x;   // b*128 + i
    const float* er = e + (size_t)row * CI;
    const int t = threadIdx.x;
    float v0 = er[t], v1 = er[t + 64];
    float mn = fminf(v0, v1);
    #pragma unroll
    for (int off = 32; off; off >>= 1) mn = fminf(mn, __shfl_xor(mn, off));
    float p0 = __expf(mn - v0), p1 = __expf(mn - v1);
    float s = p0 + p1;
    #pragma unroll
    for (int off = 32; off; off >>= 1) s += __shfl_xor(s, off);
    float inv = 1.f / s;
    attn[(size_t)row * CI + t]      = p0 * inv;
    attn[(size_t)row * CI + t + 64] = p1 * inv;
}

// ---------------------------------------------------------------------------
extern "C" void kernel_launch(void* const* d_in, const int* in_sizes, int n_in,
                              void* d_out, int out_size, void* d_ws, size_t ws_size,
                              hipStream_t stream)
{
    const float* x    = (const float*)d_in[0];
    const float* Wa   = (const float*)d_in[1];
    const float* Wc   = (const float*)d_in[2];
    const float* Wq   = (const float*)d_in[3];
    const float* bq   = (const float*)d_in[4];
    const float* Wk   = (const float*)d_in[5];
    const float* bk   = (const float*)d_in[6];
    const float* Wv   = (const float*)d_in[7];
    const float* bv   = (const float*)d_in[8];
    const float* gpam = (const float*)d_in[9];
    const float* gcam = (const float*)d_in[10];
    const float* Wa1  = (const float*)d_in[11];
    const float* Wc1  = (const float*)d_in[12];
    const float* W1   = (const float*)d_in[13];
    const float* b1   = (const float*)d_in[14];
    const float* W2   = (const float*)d_in[15];
    const float* b2   = (const float*)d_in[16];
    const float* W3   = (const float*)d_in[17];
    const float* b3   = (const float*)d_in[18];
    float* out = (float*)d_out;

    // workspace layout (fp32 elements) — compact, ~46.7 MB total
    float* ws   = (float*)d_ws;
    float* A    = ws;                 // [B,128,N] 2,097,152  (f1, later f2)
    float* Bv   = A  + 2097152;       // [B,128,N]            (v, later sa2/sc2)
    float* C    = Bv + 2097152;       // [B,128,N]            (sa, later sc)
    float* T    = C  + 2097152;       // [B,256,N] 4,194,304  (t1+t2 accumulator)
    float* Q    = T  + 4194304;       // [B,32,N]   524,288
    float* K2   = Q  + 524288;        // [B,32,N]   524,288
    float* came = K2 + 524288;        // [B,128,128] 65,536
    float* cama = came + 65536;       // [B,128,128] 65,536

    const dim3 blk(256);
    auto grid_g = [](int Co) { return dim3(NN / 64, (Co + 63) / 64, B); };

    // ---- PAM branch ----
    // f1 = relu(Wa @ x) -> A
    gemm1x1<true><<<grid_g(CI), blk, 0, stream>>>(
        Wa, 0, x, nullptr, A, nullptr, nullptr, nullptr, CI, CIN, NN);
    // q,k,v
    gemm1x1<false><<<grid_g(CQ), blk, 0, stream>>>(
        Wq, 0, A, nullptr, Q, bq, nullptr, nullptr, CQ, CI, NN);
    gemm1x1<false><<<grid_g(CQ), blk, 0, stream>>>(
        Wk, 0, A, nullptr, K2, bk, nullptr, nullptr, CQ, CI, NN);
    gemm1x1<false><<<grid_g(CI), blk, 0, stream>>>(
        Wv, 0, A, nullptr, Bv, bv, nullptr, nullptr, CI, CI, NN);
    // sa = flash(q,k,v) * gamma + f1 -> C
    pam_flash<<<dim3(NN / 32, B), blk, 0, stream>>>(Q, K2, Bv, A, gpam, C, NN);
    // sa2 = relu(Wa1 @ sa) -> Bv
    gemm1x1<true><<<grid_g(CI), blk, 0, stream>>>(
        Wa1, 0, C, nullptr, Bv, nullptr, nullptr, nullptr, CI, CI, NN);
    // T = W1 @ sa2 + b1
    gemm1x1<false><<<grid_g(COUT), blk, 0, stream>>>(
        W1, 0, Bv, nullptr, T, b1, nullptr, nullptr, COUT, CI, NN);

    // ---- CAM branch ----
    // f2 = relu(Wc @ x) -> A   (f1 dead after pam_flash)
    gemm1x1<true><<<grid_g(CI), blk, 0, stream>>>(
        Wc, 0, x, nullptr, A, nullptr, nullptr, nullptr, CI, CIN, NN);
    cam_energy<<<dim3(8, 8, B), blk, 0, stream>>>(A, came, NN);
    cam_softmax<<<dim3(B * CI), dim3(64), 0, stream>>>(came, cama);
    // sc = gamma_cam * (attn @ f2) + f2 -> C
    gemm1x1<false><<<grid_g(CI), blk, 0, stream>>>(
        cama, (long)CI * CI, A, nullptr, C, nullptr, gcam, A, CI, CI, NN);
    // sc2 = relu(Wc1 @ sc) -> Bv
    gemm1x1<true><<<grid_g(CI), blk, 0, stream>>>(
        Wc1, 0, C, nullptr, Bv, nullptr, nullptr, nullptr, CI, CI, NN);
    // T += W2 @ sc2 + b2   (in-place residual add: same element read+write per thread)
    gemm1x1<false><<<grid_g(COUT), blk, 0, stream>>>(
        W2, 0, Bv, nullptr, T, b2, nullptr, T, COUT, CI, NN);

    // ---- out = W3 @ T + b3 ----
    gemm1x1<false><<<grid_g(COUT), blk, 0, stream>>>(
        W3, 0, T, nullptr, out, b3, nullptr, nullptr, COUT, COUT, NN);
}

// Round 7
// 1137.483 us; speedup vs baseline: 1.0915x; 1.0915x over previous
//
#include <hip/hip_runtime.h>
#include <hip/hip_bf16.h>

// Problem constants (fixed by setup_inputs)
constexpr int B    = 4;
constexpr int CIN  = 512;
constexpr int NN   = 4096;
constexpr int CI   = 128;   // inter_channels
constexpr int CQ   = 32;    // PAM q/k dim
constexpr int COUT = 256;
constexpr int NSPLIT = 4;              // KV splits for pam flash
constexpr int KVLEN  = NN / NSPLIT;    // 1024 KV cols per split

// ---------------------------------------------------------------------------
// Generic 1x1-conv GEMM: Y[b,co,n] = epilogue( sum_k W[co,k] * X[b,k,n] )
// epilogue: v = acc + bias[co]; if RELU v=max(v,0); v *= gamma; v += resid
// Tile 64(co) x 64(n), BK=16, 256 threads, 4x4 per-thread register tile.
// W may be per-batch (wbs = per-batch element stride, 0 for shared weights).
// ---------------------------------------------------------------------------
template<bool RELU>
__global__ __launch_bounds__(256) void gemm1x1(
    const float* __restrict__ W, long wbs,
    const float* __restrict__ X, const float* __restrict__ X2,
    float* __restrict__ Y,
    const float* __restrict__ bias,
    const float* __restrict__ gamma_ptr,
    const float* __restrict__ resid,
    int Co, int K, int N)
{
    const int b   = blockIdx.z;
    const int n0  = blockIdx.x * 64;
    const int co0 = blockIdx.y * 64;
    const float* Wb = W + (size_t)b * wbs;
    const float* Xb = X + (size_t)b * K * N;
    const float* X2b = X2 ? (X2 + (size_t)b * K * N) : nullptr;
    const size_t ybase = (size_t)b * Co * N;

    __shared__ float Ws[16][65];   // [k][co]
    __shared__ float Xs[16][65];   // [k][n]

    float acc[4][4] = {};
    const int t  = threadIdx.x;
    const int ty = t >> 4;   // 0..15 (co dim)
    const int tx = t & 15;   // 0..15 (n dim)

    for (int kb = 0; kb < K; kb += 16) {
        // W tile [64co][16k] -> Ws[k][co]; coalesced along K
        #pragma unroll
        for (int idx = t; idx < 1024; idx += 256) {
            int a = idx >> 4, c = idx & 15;
            int co = co0 + a;
            Ws[c][a] = (co < Co) ? Wb[(size_t)co * K + kb + c] : 0.f;
        }
        // X tile [16k][64n] -> Xs[k][n]; coalesced along n
        #pragma unroll
        for (int idx = t; idx < 1024; idx += 256) {
            int r = idx >> 6, j = idx & 63;
            size_t off = (size_t)(kb + r) * N + n0 + j;
            float xv = Xb[off];
            if (X2b) xv += X2b[off];
            Xs[r][j] = xv;
        }
        __syncthreads();
        #pragma unroll
        for (int kk = 0; kk < 16; ++kk) {
            float wv[4], xv[4];
            #pragma unroll
            for (int i = 0; i < 4; ++i) wv[i] = Ws[kk][ty + 16 * i];
            #pragma unroll
            for (int j = 0; j < 4; ++j) xv[j] = Xs[kk][tx + 16 * j];
            #pragma unroll
            for (int i = 0; i < 4; ++i)
                #pragma unroll
                for (int j = 0; j < 4; ++j)
                    acc[i][j] += wv[i] * xv[j];
        }
        __syncthreads();
    }

    const float g = gamma_ptr ? *gamma_ptr : 1.f;
    #pragma unroll
    for (int i = 0; i < 4; ++i) {
        int co = co0 + ty + 16 * i;
        if (co >= Co) continue;
        float bv = bias ? bias[co] : 0.f;
        #pragma unroll
        for (int j = 0; j < 4; ++j) {
            int n = n0 + tx + 16 * j;
            float val = acc[i][j] + bv;
            if (RELU) val = fmaxf(val, 0.f);
            val *= g;
            size_t off = ybase + (size_t)co * N + n;
            if (resid) val += resid[off];
            Y[off] = val;
        }
    }
}

// ---------------------------------------------------------------------------
// PAM flash attention, KV-split partial.
// blockIdx = (n-tile, b, split s). Each split covers KV cols [s*KVLEN, (s+1)*KVLEN).
// Writes UNNORMALIZED partial O (running sum in frame m_s) plus per-row m_s, l_s.
// Opart layout: split s -> (s<2 ? Oa : Ob) + (s&1)*B*CI*N, elem [b][c][n].
// mp/lp layout: [s][b][n].
// ---------------------------------------------------------------------------
__global__ __launch_bounds__(256) void pam_flash_part(
    const float* __restrict__ q, const float* __restrict__ k,
    const float* __restrict__ v,
    float* __restrict__ Oa, float* __restrict__ Ob,
    float* __restrict__ mp, float* __restrict__ lp, int N)
{
    const int b  = blockIdx.y;
    const int s  = blockIdx.z;
    const int n0 = blockIdx.x * 32;
    const float* qb = q + (size_t)b * CQ * N;
    const float* kb = k + (size_t)b * CQ * N;
    const float* vb = v + (size_t)b * CI * N;
    const size_t PART = (size_t)B * CI * N;
    float* Op = (s < 2 ? Oa : Ob) + (size_t)(s & 1) * PART;

    __shared__ float qs[32][33];   // [row r][c]
    __shared__ float ks[32][33];   // [m][c]
    __shared__ float vs[128][33];  // [c][mm]
    __shared__ float ps[32][33];   // [r][mm]
    __shared__ float mrow[32], lrow[32], srow[32];

    const int t = threadIdx.x;
    // score phase mapping
    const int sr  = t >> 3;          // row 0..31
    const int sm0 = (t & 7) * 4;     // 4 m's per thread
    // PV phase mapping
    const int rg = t & 7;            // row group: rows rg*4..rg*4+3
    const int cg = t >> 3;           // col group: cols cg, cg+32, cg+64, cg+96

    for (int idx = t; idx < 32 * 32; idx += 256) {
        int c = idx >> 5, r = idx & 31;
        qs[r][c] = qb[(size_t)c * N + n0 + r];
    }
    if (t < 32) { mrow[t] = -1e30f; lrow[t] = 0.f; srow[t] = 0.f; }
    float acc[4][4] = {};
    __syncthreads();

    const int mstart = s * KVLEN;
    for (int m0 = mstart; m0 < mstart + KVLEN; m0 += 32) {
        // stage K and V tiles
        for (int idx = t; idx < 32 * 32; idx += 256) {
            int c = idx >> 5, mm = idx & 31;
            ks[mm][c] = kb[(size_t)c * N + m0 + mm];
        }
        for (int idx = t; idx < 128 * 32; idx += 256) {
            int c = idx >> 5, mm = idx & 31;
            vs[c][mm] = vb[(size_t)c * N + m0 + mm];
        }
        __syncthreads();

        // scores for 4 m's of this thread's row
        float sreg[4] = {};
        #pragma unroll
        for (int c = 0; c < 32; ++c) {
            float qv = qs[sr][c];
            #pragma unroll
            for (int j = 0; j < 4; ++j) sreg[j] += qv * ks[sm0 + j][c];
        }
        float tmax = fmaxf(fmaxf(sreg[0], sreg[1]), fmaxf(sreg[2], sreg[3]));
        #pragma unroll
        for (int off = 1; off < 8; off <<= 1) tmax = fmaxf(tmax, __shfl_xor(tmax, off));
        const float mold = mrow[sr];
        const float mnew = fmaxf(mold, tmax);
        float p[4], psum = 0.f;
        #pragma unroll
        for (int j = 0; j < 4; ++j) { p[j] = __expf(sreg[j] - mnew); psum += p[j]; }
        #pragma unroll
        for (int off = 1; off < 8; off <<= 1) psum += __shfl_xor(psum, off);
        const float scale = __expf(mold - mnew);
        if ((t & 7) == 0) {
            mrow[sr] = mnew;
            lrow[sr] = lrow[sr] * scale + psum;
            srow[sr] = scale;
        }
        #pragma unroll
        for (int j = 0; j < 4; ++j) ps[sr][sm0 + j] = p[j];
        __syncthreads();

        // PV accumulate: out[r][c] += p[r][m] * v[c][m]
        float scl[4];
        #pragma unroll
        for (int rr = 0; rr < 4; ++rr) scl[rr] = srow[rg * 4 + rr];
        #pragma unroll
        for (int rr = 0; rr < 4; ++rr)
            #pragma unroll
            for (int cc = 0; cc < 4; ++cc) acc[rr][cc] *= scl[rr];
        #pragma unroll
        for (int mm = 0; mm < 32; ++mm) {
            float pv[4], vv[4];
            #pragma unroll
            for (int rr = 0; rr < 4; ++rr) pv[rr] = ps[rg * 4 + rr][mm];
            #pragma unroll
            for (int cc = 0; cc < 4; ++cc) vv[cc] = vs[cg + 32 * cc][mm];
            #pragma unroll
            for (int rr = 0; rr < 4; ++rr)
                #pragma unroll
                for (int cc = 0; cc < 4; ++cc) acc[rr][cc] += pv[rr] * vv[cc];
        }
        __syncthreads();
    }

    // write unnormalized partial + (m,l) per row
    #pragma unroll
    for (int rr = 0; rr < 4; ++rr) {
        int r = rg * 4 + rr;
        #pragma unroll
        for (int cc = 0; cc < 4; ++cc) {
            int c = cg + 32 * cc;
            Op[((size_t)(b * CI + c)) * N + n0 + r] = acc[rr][cc];
        }
    }
    if (t < 32) {
        mp[(size_t)(s * B + b) * N + n0 + t] = mrow[t];
        lp[(size_t)(s * B + b) * N + n0 + t] = lrow[t];
    }
}

// ---------------------------------------------------------------------------
// Merge NSPLIT flash partials: per (b,c,n):
//   M = max_s m_s; w_s = exp(m_s - M); L = sum_s l_s w_s;
//   O = sum_s O_s w_s / L; sa = gamma*O + f1.
// ---------------------------------------------------------------------------
__global__ __launch_bounds__(256) void pam_merge(
    const float* __restrict__ Oa, const float* __restrict__ Ob,
    const float* __restrict__ mp, const float* __restrict__ lp,
    const float* __restrict__ f1, const float* __restrict__ gamma_ptr,
    float* __restrict__ sa)
{
    const size_t PART = (size_t)B * CI * NN;
    size_t idx = (size_t)blockIdx.x * 256 + threadIdx.x;   // over B*CI*NN
    const int n = (int)(idx & (NN - 1));
    const int b = (int)(idx >> 19);                        // idx / (CI*NN), CI*NN = 2^19

    float m0 = mp[(size_t)(0 * B + b) * NN + n];
    float m1 = mp[(size_t)(1 * B + b) * NN + n];
    float m2 = mp[(size_t)(2 * B + b) * NN + n];
    float m3 = mp[(size_t)(3 * B + b) * NN + n];
    float M = fmaxf(fmaxf(m0, m1), fmaxf(m2, m3));
    float w0 = __expf(m0 - M), w1 = __expf(m1 - M);
    float w2 = __expf(m2 - M), w3 = __expf(m3 - M);
    float L = lp[(size_t)(0 * B + b) * NN + n] * w0
            + lp[(size_t)(1 * B + b) * NN + n] * w1
            + lp[(size_t)(2 * B + b) * NN + n] * w2
            + lp[(size_t)(3 * B + b) * NN + n] * w3;
    float O = Oa[idx] * w0 + Oa[PART + idx] * w1
            + Ob[idx] * w2 + Ob[PART + idx] * w3;
    sa[idx] = (*gamma_ptr) * (O / L) + f1[idx];
}

// ---------------------------------------------------------------------------
// CAM energy: e[b,i,j] = sum_n f2[b,i,n] * f2[b,j,n]   (128x128 per batch)
// ---------------------------------------------------------------------------
__global__ __launch_bounds__(256) void cam_energy(
    const float* __restrict__ f2, float* __restrict__ e, int N)
{
    const int b  = blockIdx.z;
    const int i0 = blockIdx.y * 16;
    const int j0 = blockIdx.x * 16;
    const float* fb = f2 + (size_t)b * CI * N;
    __shared__ float fa[16][129], fbs[16][129];
    const int t = threadIdx.x;
    const int ti = t >> 4, tj = t & 15;
    float acc = 0.f;
    for (int nb = 0; nb < N; nb += 128) {
        for (int idx = t; idx < 16 * 128; idx += 256) {
            int r = idx >> 7, c = idx & 127;
            fa[r][c]  = fb[(size_t)(i0 + r) * N + nb + c];
            fbs[r][c] = fb[(size_t)(j0 + r) * N + nb + c];
        }
        __syncthreads();
        #pragma unroll 8
        for (int c = 0; c < 128; ++c) acc += fa[ti][c] * fbs[tj][c];
        __syncthreads();
    }
    e[((size_t)b * CI + i0 + ti) * CI + j0 + tj] = acc;
}

// ---------------------------------------------------------------------------
// CAM softmax: attn[row, j] = exp(rowmin - e[row,j]) / sum_j exp(rowmin - e[row,j])
// (softmax(rowmax - e) simplifies: the rowmax cancels)
// ---------------------------------------------------------------------------
__global__ __launch_bounds__(64) void cam_softmax(
    const float* __restrict__ e, float* __restrict__ attn)
{
    const int row = blockIdx.x;   // b*128 + i
    const float* er = e + (size_t)row * CI;
    const int t = threadIdx.x;
    float v0 = er[t], v1 = er[t + 64];
    float mn = fminf(v0, v1);
    #pragma unroll
    for (int off = 32; off; off >>= 1) mn = fminf(mn, __shfl_xor(mn, off));
    float p0 = __expf(mn - v0), p1 = __expf(mn - v1);
    float s = p0 + p1;
    #pragma unroll
    for (int off = 32; off; off >>= 1) s += __shfl_xor(s, off);
    float inv = 1.f / s;
    attn[(size_t)row * CI + t]      = p0 * inv;
    attn[(size_t)row * CI + t + 64] = p1 * inv;
}

// ---------------------------------------------------------------------------
extern "C" void kernel_launch(void* const* d_in, const int* in_sizes, int n_in,
                              void* d_out, int out_size, void* d_ws, size_t ws_size,
                              hipStream_t stream)
{
    const float* x    = (const float*)d_in[0];
    const float* Wa   = (const float*)d_in[1];
    const float* Wc   = (const float*)d_in[2];
    const float* Wq   = (const float*)d_in[3];
    const float* bq   = (const float*)d_in[4];
    const float* Wk   = (const float*)d_in[5];
    const float* bk   = (const float*)d_in[6];
    const float* Wv   = (const float*)d_in[7];
    const float* bv   = (const float*)d_in[8];
    const float* gpam = (const float*)d_in[9];
    const float* gcam = (const float*)d_in[10];
    const float* Wa1  = (const float*)d_in[11];
    const float* Wc1  = (const float*)d_in[12];
    const float* W1   = (const float*)d_in[13];
    const float* b1   = (const float*)d_in[14];
    const float* W2   = (const float*)d_in[15];
    const float* b2   = (const float*)d_in[16];
    const float* W3   = (const float*)d_in[17];
    const float* b3   = (const float*)d_in[18];
    float* out = (float*)d_out;

    // workspace layout (fp32 elements) — ~64.0 MB total
    float* ws   = (float*)d_ws;
    float* A    = ws;                 // [B,128,N] 2,097,152  (f1, later f2)
    float* Bv   = A  + 2097152;       // [B,128,N]            (v, later sa2/sc2)
    float* C    = Bv + 2097152;       // [B,128,N]            (sa, later sc)
    float* T    = C  + 2097152;       // [B,256,N] 4,194,304  (t1+t2 accumulator)
    float* Q    = T  + 4194304;       // [B,32,N]   524,288
    float* K2   = Q  + 524288;        // [B,32,N]   524,288
    float* came = K2 + 524288;        // [B,128,128] 65,536
    float* cama = came + 65536;       // [B,128,128] 65,536
    // flash split scratch: splits 0,1 alias T (dead until W1); splits 2,3 new.
    float* Oa   = T;                  // 2 x [B,128,N] partials
    float* Ob   = cama + 65536;       // 2 x [B,128,N] partials  4,194,304
    float* mpart= Ob + 4194304;       // [4][B][N]   65,536
    float* lpart= mpart + 65536;      // [4][B][N]   65,536

    const dim3 blk(256);
    auto grid_g = [](int Co) { return dim3(NN / 64, (Co + 63) / 64, B); };

    // ---- PAM branch ----
    // f1 = relu(Wa @ x) -> A
    gemm1x1<true><<<grid_g(CI), blk, 0, stream>>>(
        Wa, 0, x, nullptr, A, nullptr, nullptr, nullptr, CI, CIN, NN);
    // q,k,v
    gemm1x1<false><<<grid_g(CQ), blk, 0, stream>>>(
        Wq, 0, A, nullptr, Q, bq, nullptr, nullptr, CQ, CI, NN);
    gemm1x1<false><<<grid_g(CQ), blk, 0, stream>>>(
        Wk, 0, A, nullptr, K2, bk, nullptr, nullptr, CQ, CI, NN);
    gemm1x1<false><<<grid_g(CI), blk, 0, stream>>>(
        Wv, 0, A, nullptr, Bv, bv, nullptr, nullptr, CI, CI, NN);
    // flash partials over 4 KV splits, then merge: sa -> C
    pam_flash_part<<<dim3(NN / 32, B, NSPLIT), blk, 0, stream>>>(
        Q, K2, Bv, Oa, Ob, mpart, lpart, NN);
    pam_merge<<<dim3((B * CI * NN) / 256), blk, 0, stream>>>(
        Oa, Ob, mpart, lpart, A, gpam, C);
    // sa2 = relu(Wa1 @ sa) -> Bv
    gemm1x1<true><<<grid_g(CI), blk, 0, stream>>>(
        Wa1, 0, C, nullptr, Bv, nullptr, nullptr, nullptr, CI, CI, NN);
    // T = W1 @ sa2 + b1   (T free again: flash partials already merged)
    gemm1x1<false><<<grid_g(COUT), blk, 0, stream>>>(
        W1, 0, Bv, nullptr, T, b1, nullptr, nullptr, COUT, CI, NN);

    // ---- CAM branch ----
    // f2 = relu(Wc @ x) -> A   (f1 dead after pam_merge)
    gemm1x1<true><<<grid_g(CI), blk, 0, stream>>>(
        Wc, 0, x, nullptr, A, nullptr, nullptr, nullptr, CI, CIN, NN);
    cam_energy<<<dim3(8, 8, B), blk, 0, stream>>>(A, came, NN);
    cam_softmax<<<dim3(B * CI), dim3(64), 0, stream>>>(came, cama);
    // sc = gamma_cam * (attn @ f2) + f2 -> C
    gemm1x1<false><<<grid_g(CI), blk, 0, stream>>>(
        cama, (long)CI * CI, A, nullptr, C, nullptr, gcam, A, CI, CI, NN);
    // sc2 = relu(Wc1 @ sc) -> Bv
    gemm1x1<true><<<grid_g(CI), blk, 0, stream>>>(
        Wc1, 0, C, nullptr, Bv, nullptr, nullptr, nullptr, CI, CI, NN);
    // T += W2 @ sc2 + b2   (in-place residual add: same element read+write per thread)
    gemm1x1<false><<<grid_g(COUT), blk, 0, stream>>>(
        W2, 0, Bv, nullptr, T, b2, nullptr, T, COUT, CI, NN);

    // ---- out = W3 @ T + b3 ----
    gemm1x1<false><<<grid_g(COUT), blk, 0, stream>>>(
        W3, 0, T, nullptr, out, b3, nullptr, nullptr, COUT, COUT, NN);
}

// Round 8
// 653.139 us; speedup vs baseline: 1.9010x; 1.7416x over previous
//
#include <hip/hip_runtime.h>
#include <hip/hip_bf16.h>

// Problem constants (fixed by setup_inputs)
constexpr int B    = 4;
constexpr int CIN  = 512;
constexpr int NN   = 4096;
constexpr int CI   = 128;   // inter_channels
constexpr int CQ   = 32;    // PAM q/k dim
constexpr int COUT = 256;
constexpr int NSPLIT = 4;              // KV splits for pam flash
constexpr int KVLEN  = NN / NSPLIT;    // 1024 KV cols per split

typedef __bf16 bf16x8 __attribute__((ext_vector_type(8)));
typedef float  f32x4  __attribute__((ext_vector_type(4)));

// ---------------------------------------------------------------------------
// Generic 1x1-conv GEMM: Y[b,co,n] = epilogue( sum_k W[co,k] * X[b,k,n] )
// (unchanged from round 5/7 baseline)
// ---------------------------------------------------------------------------
template<bool RELU>
__global__ __launch_bounds__(256) void gemm1x1(
    const float* __restrict__ W, long wbs,
    const float* __restrict__ X, const float* __restrict__ X2,
    float* __restrict__ Y,
    const float* __restrict__ bias,
    const float* __restrict__ gamma_ptr,
    const float* __restrict__ resid,
    int Co, int K, int N)
{
    const int b   = blockIdx.z;
    const int n0  = blockIdx.x * 64;
    const int co0 = blockIdx.y * 64;
    const float* Wb = W + (size_t)b * wbs;
    const float* Xb = X + (size_t)b * K * N;
    const float* X2b = X2 ? (X2 + (size_t)b * K * N) : nullptr;
    const size_t ybase = (size_t)b * Co * N;

    __shared__ float Ws[16][65];   // [k][co]
    __shared__ float Xs[16][65];   // [k][n]

    float acc[4][4] = {};
    const int t  = threadIdx.x;
    const int ty = t >> 4;   // 0..15 (co dim)
    const int tx = t & 15;   // 0..15 (n dim)

    for (int kb = 0; kb < K; kb += 16) {
        #pragma unroll
        for (int idx = t; idx < 1024; idx += 256) {
            int a = idx >> 4, cc = idx & 15;
            int co = co0 + a;
            Ws[cc][a] = (co < Co) ? Wb[(size_t)co * K + kb + cc] : 0.f;
        }
        #pragma unroll
        for (int idx = t; idx < 1024; idx += 256) {
            int r = idx >> 6, j = idx & 63;
            size_t off = (size_t)(kb + r) * N + n0 + j;
            float xv = Xb[off];
            if (X2b) xv += X2b[off];
            Xs[r][j] = xv;
        }
        __syncthreads();
        #pragma unroll
        for (int kk = 0; kk < 16; ++kk) {
            float wv[4], xv[4];
            #pragma unroll
            for (int i = 0; i < 4; ++i) wv[i] = Ws[kk][ty + 16 * i];
            #pragma unroll
            for (int j = 0; j < 4; ++j) xv[j] = Xs[kk][tx + 16 * j];
            #pragma unroll
            for (int i = 0; i < 4; ++i)
                #pragma unroll
                for (int j = 0; j < 4; ++j)
                    acc[i][j] += wv[i] * xv[j];
        }
        __syncthreads();
    }

    const float g = gamma_ptr ? *gamma_ptr : 1.f;
    #pragma unroll
    for (int i = 0; i < 4; ++i) {
        int co = co0 + ty + 16 * i;
        if (co >= Co) continue;
        float bv = bias ? bias[co] : 0.f;
        #pragma unroll
        for (int j = 0; j < 4; ++j) {
            int n = n0 + tx + 16 * j;
            float val = acc[i][j] + bv;
            if (RELU) val = fmaxf(val, 0.f);
            val *= g;
            size_t off = ybase + (size_t)co * N + n;
            if (resid) val += resid[off];
            Y[off] = val;
        }
    }
}

// ---------------------------------------------------------------------------
// PAM flash attention partial, MFMA bf16 (16x16x32; K=32 == CQ in one step).
// Block: 256 thr / 4 waves; 128 Q-rows per block (32 per wave).
// Grid: (NN/128, B, NSPLIT). Each split covers KV cols [s*KVLEN,(s+1)*KVLEN).
// Writes UNNORMALIZED partial O (frame m_s) + per-row m_s, l_s (merge unchanged).
//
// Fragment layouts (guide §3, m89/m91-verified):
//   A: row = lane&15, k = (lane>>4)*8 + j   (8 bf16 = 1 ds_read_b128)
//   B: col = lane&15, k = (lane>>4)*8 + j
//   C/D: col = lane&15, row = (lane>>4)*4 + reg
// LDS tiles padded to 40 bf16/row: 16B-aligned b128 frags, 2-way banks (free).
// ---------------------------------------------------------------------------
__global__ __launch_bounds__(256) void pam_flash_mfma(
    const float* __restrict__ q, const float* __restrict__ k,
    const float* __restrict__ v,
    float* __restrict__ Oa, float* __restrict__ Ob,
    float* __restrict__ mp, float* __restrict__ lp, int N)
{
    const int b  = blockIdx.y;
    const int s  = blockIdx.z;
    const int n0 = blockIdx.x * 128;
    const float* qb = q + (size_t)b * CQ * N;
    const float* kb = k + (size_t)b * CQ * N;
    const float* vb = v + (size_t)b * CI * N;
    const size_t PART = (size_t)B * CI * N;
    float* Op = (s < 2 ? Oa : Ob) + (size_t)(s & 1) * PART;

    __shared__ __bf16 Klds[32][40];    // [m][c]  (K^T)
    __shared__ __bf16 Vlds[128][40];   // [vc][m]
    __shared__ __bf16 QP[128][40];     // Q^T staging [n][c]; then per-wave P [row][m]

    const int t    = threadIdx.x;
    const int w    = t >> 6;
    const int lane = t & 63;
    const int g    = lane >> 4;   // 0..3
    const int c    = lane & 15;   // 0..15

    // ---- stage Q^T once: QP[n][cq] = q[cq][n0+n], bf16
    {
        const int cq = t >> 3;           // 0..31
        const int nb = (t & 7) * 16;     // 0..112
        const float* src = qb + (size_t)cq * N + n0 + nb;
        #pragma unroll
        for (int j = 0; j < 4; ++j) {
            float4 f = *reinterpret_cast<const float4*>(src + 4 * j);
            QP[nb + 4*j + 0][cq] = (__bf16)f.x;
            QP[nb + 4*j + 1][cq] = (__bf16)f.y;
            QP[nb + 4*j + 2][cq] = (__bf16)f.z;
            QP[nb + 4*j + 3][cq] = (__bf16)f.w;
        }
    }
    __syncthreads();
    // Q A-frags (K-invariant) -> registers
    bf16x8 qa[2];
    #pragma unroll
    for (int rb = 0; rb < 2; ++rb)
        qa[rb] = *reinterpret_cast<const bf16x8*>(&QP[32*w + 16*rb + c][g * 8]);
    __syncthreads();   // QP region now recycled as per-wave P buffer

    f32x4 acc[2][8];
    #pragma unroll
    for (int rb = 0; rb < 2; ++rb)
        #pragma unroll
        for (int vbk = 0; vbk < 8; ++vbk)
            acc[rb][vbk] = (f32x4){0.f, 0.f, 0.f, 0.f};
    float ms[2][4], ls[2][4];
    #pragma unroll
    for (int rb = 0; rb < 2; ++rb)
        #pragma unroll
        for (int r = 0; r < 4; ++r) { ms[rb][r] = -1e30f; ls[rb][r] = 0.f; }

    const int mstart = s * KVLEN;
    for (int mt = 0; mt < KVLEN / 32; ++mt) {
        const int m0 = mstart + mt * 32;
        // ---- stage K^T tile: Klds[m][ck]
        {
            const int ck = t >> 3;        // 0..31
            const int m4 = (t & 7) * 4;
            float4 f = *reinterpret_cast<const float4*>(kb + (size_t)ck * N + m0 + m4);
            Klds[m4 + 0][ck] = (__bf16)f.x;
            Klds[m4 + 1][ck] = (__bf16)f.y;
            Klds[m4 + 2][ck] = (__bf16)f.z;
            Klds[m4 + 3][ck] = (__bf16)f.w;
        }
        // ---- stage V tile: Vlds[cv][m]
        {
            const int cv = t >> 1;        // 0..127
            const int mh = (t & 1) * 16;
            const float* src = vb + (size_t)cv * N + m0 + mh;
            #pragma unroll
            for (int j = 0; j < 2; ++j) {
                float4 f0 = *reinterpret_cast<const float4*>(src + 8 * j);
                float4 f1 = *reinterpret_cast<const float4*>(src + 8 * j + 4);
                bf16x8 u;
                u[0]=(__bf16)f0.x; u[1]=(__bf16)f0.y; u[2]=(__bf16)f0.z; u[3]=(__bf16)f0.w;
                u[4]=(__bf16)f1.x; u[5]=(__bf16)f1.y; u[6]=(__bf16)f1.z; u[7]=(__bf16)f1.w;
                *reinterpret_cast<bf16x8*>(&Vlds[cv][mh + 8 * j]) = u;
            }
        }
        __syncthreads();

        // ---- QK^T: S[32 qrow x 32 m] per wave = 4 MFMAs
        f32x4 sv[2][2];
        #pragma unroll
        for (int cb = 0; cb < 2; ++cb) {
            bf16x8 kf = *reinterpret_cast<const bf16x8*>(&Klds[16*cb + c][g * 8]);
            #pragma unroll
            for (int rb = 0; rb < 2; ++rb)
                sv[rb][cb] = __builtin_amdgcn_mfma_f32_16x16x32_bf16(
                    qa[rb], kf, (f32x4){0.f, 0.f, 0.f, 0.f}, 0, 0, 0);
        }

        // ---- online softmax, per row (rb,reg); rows replicated over 16 lanes
        float scale[2][4];
        #pragma unroll
        for (int rb = 0; rb < 2; ++rb) {
            #pragma unroll
            for (int r = 0; r < 4; ++r) {
                float mx = fmaxf(sv[rb][0][r], sv[rb][1][r]);
                #pragma unroll
                for (int off = 1; off < 16; off <<= 1)
                    mx = fmaxf(mx, __shfl_xor(mx, off));
                float mnew = fmaxf(ms[rb][r], mx);
                scale[rb][r] = __expf(ms[rb][r] - mnew);
                ms[rb][r] = mnew;
                float p0 = __expf(sv[rb][0][r] - mnew);
                float p1 = __expf(sv[rb][1][r] - mnew);
                sv[rb][0][r] = p0; sv[rb][1][r] = p1;
                float psum = p0 + p1;
                #pragma unroll
                for (int off = 1; off < 16; off <<= 1)
                    psum += __shfl_xor(psum, off);
                ls[rb][r] = ls[rb][r] * scale[rb][r] + psum;
            }
        }

        // ---- P -> LDS (own wave's 32-row slice; same-wave DS ordering)
        #pragma unroll
        for (int rb = 0; rb < 2; ++rb)
            #pragma unroll
            for (int cb = 0; cb < 2; ++cb)
                #pragma unroll
                for (int r = 0; r < 4; ++r)
                    QP[32*w + 16*rb + 4*g + r][16*cb + c] = (__bf16)sv[rb][cb][r];

        // ---- rescale acc into new max-frame
        #pragma unroll
        for (int rb = 0; rb < 2; ++rb)
            #pragma unroll
            for (int vbk = 0; vbk < 8; ++vbk)
                #pragma unroll
                for (int r = 0; r < 4; ++r)
                    acc[rb][vbk][r] *= scale[rb][r];

        // ---- PV: D2[32 qrow x 128 vc] per wave = 16 MFMAs
        bf16x8 pa[2];
        #pragma unroll
        for (int rb = 0; rb < 2; ++rb)
            pa[rb] = *reinterpret_cast<const bf16x8*>(&QP[32*w + 16*rb + c][g * 8]);
        #pragma unroll
        for (int vbk = 0; vbk < 8; ++vbk) {
            bf16x8 vf = *reinterpret_cast<const bf16x8*>(&Vlds[16*vbk + c][g * 8]);
            #pragma unroll
            for (int rb = 0; rb < 2; ++rb)
                acc[rb][vbk] = __builtin_amdgcn_mfma_f32_16x16x32_bf16(
                    pa[rb], vf, acc[rb][vbk], 0, 0, 0);
        }
        __syncthreads();   // protect Klds/Vlds restage
    }

    // ---- epilogue: unnormalized partial O + per-row (m,l)
    #pragma unroll
    for (int rb = 0; rb < 2; ++rb)
        #pragma unroll
        for (int vbk = 0; vbk < 8; ++vbk) {
            float4 o = { acc[rb][vbk][0], acc[rb][vbk][1],
                         acc[rb][vbk][2], acc[rb][vbk][3] };
            *reinterpret_cast<float4*>(
                &Op[((size_t)(b * CI + 16*vbk + c)) * N + n0 + 32*w + 16*rb + 4*g]) = o;
        }
    if (c == 0) {
        #pragma unroll
        for (int rb = 0; rb < 2; ++rb)
            #pragma unroll
            for (int r = 0; r < 4; ++r) {
                int n = n0 + 32*w + 16*rb + 4*g + r;
                mp[(size_t)(s * B + b) * N + n] = ms[rb][r];
                lp[(size_t)(s * B + b) * N + n] = ls[rb][r];
            }
    }
}

// ---------------------------------------------------------------------------
// Merge NSPLIT flash partials (unchanged): per (b,c,n):
//   M = max_s m_s; w_s = exp(m_s - M); L = sum_s l_s w_s;
//   O = sum_s O_s w_s / L; sa = gamma*O + f1.
// ---------------------------------------------------------------------------
__global__ __launch_bounds__(256) void pam_merge(
    const float* __restrict__ Oa, const float* __restrict__ Ob,
    const float* __restrict__ mp, const float* __restrict__ lp,
    const float* __restrict__ f1, const float* __restrict__ gamma_ptr,
    float* __restrict__ sa)
{
    const size_t PART = (size_t)B * CI * NN;
    size_t idx = (size_t)blockIdx.x * 256 + threadIdx.x;   // over B*CI*NN
    const int n = (int)(idx & (NN - 1));
    const int b = (int)(idx >> 19);                        // CI*NN = 2^19

    float m0 = mp[(size_t)(0 * B + b) * NN + n];
    float m1 = mp[(size_t)(1 * B + b) * NN + n];
    float m2 = mp[(size_t)(2 * B + b) * NN + n];
    float m3 = mp[(size_t)(3 * B + b) * NN + n];
    float M = fmaxf(fmaxf(m0, m1), fmaxf(m2, m3));
    float w0 = __expf(m0 - M), w1 = __expf(m1 - M);
    float w2 = __expf(m2 - M), w3 = __expf(m3 - M);
    float L = lp[(size_t)(0 * B + b) * NN + n] * w0
            + lp[(size_t)(1 * B + b) * NN + n] * w1
            + lp[(size_t)(2 * B + b) * NN + n] * w2
            + lp[(size_t)(3 * B + b) * NN + n] * w3;
    float O = Oa[idx] * w0 + Oa[PART + idx] * w1
            + Ob[idx] * w2 + Ob[PART + idx] * w3;
    sa[idx] = (*gamma_ptr) * (O / L) + f1[idx];
}

// ---------------------------------------------------------------------------
// CAM energy: e[b,i,j] = sum_n f2[b,i,n] * f2[b,j,n]   (128x128 per batch)
// ---------------------------------------------------------------------------
__global__ __launch_bounds__(256) void cam_energy(
    const float* __restrict__ f2, float* __restrict__ e, int N)
{
    const int b  = blockIdx.z;
    const int i0 = blockIdx.y * 16;
    const int j0 = blockIdx.x * 16;
    const float* fb = f2 + (size_t)b * CI * N;
    __shared__ float fa[16][129], fbs[16][129];
    const int t = threadIdx.x;
    const int ti = t >> 4, tj = t & 15;
    float acc = 0.f;
    for (int nb = 0; nb < N; nb += 128) {
        for (int idx = t; idx < 16 * 128; idx += 256) {
            int r = idx >> 7, cc = idx & 127;
            fa[r][cc]  = fb[(size_t)(i0 + r) * N + nb + cc];
            fbs[r][cc] = fb[(size_t)(j0 + r) * N + nb + cc];
        }
        __syncthreads();
        #pragma unroll 8
        for (int cc = 0; cc < 128; ++cc) acc += fa[ti][cc] * fbs[tj][cc];
        __syncthreads();
    }
    e[((size_t)b * CI + i0 + ti) * CI + j0 + tj] = acc;
}

// ---------------------------------------------------------------------------
// CAM softmax: attn[row, j] = exp(rowmin - e[row,j]) / sum_j exp(rowmin - e[row,j])
// ---------------------------------------------------------------------------
__global__ __launch_bounds__(64) void cam_softmax(
    const float* __restrict__ e, float* __restrict__ attn)
{
    const int row = blockIdx.x;   // b*128 + i
    const float* er = e + (size_t)row * CI;
    const int t = threadIdx.x;
    float v0 = er[t], v1 = er[t + 64];
    float mn = fminf(v0, v1);
    #pragma unroll
    for (int off = 32; off; off >>= 1) mn = fminf(mn, __shfl_xor(mn, off));
    float p0 = __expf(mn - v0), p1 = __expf(mn - v1);
    float s = p0 + p1;
    #pragma unroll
    for (int off = 32; off; off >>= 1) s += __shfl_xor(s, off);
    float inv = 1.f / s;
    attn[(size_t)row * CI + t]      = p0 * inv;
    attn[(size_t)row * CI + t + 64] = p1 * inv;
}

// ---------------------------------------------------------------------------
extern "C" void kernel_launch(void* const* d_in, const int* in_sizes, int n_in,
                              void* d_out, int out_size, void* d_ws, size_t ws_size,
                              hipStream_t stream)
{
    const float* x    = (const float*)d_in[0];
    const float* Wa   = (const float*)d_in[1];
    const float* Wc   = (const float*)d_in[2];
    const float* Wq   = (const float*)d_in[3];
    const float* bq   = (const float*)d_in[4];
    const float* Wk   = (const float*)d_in[5];
    const float* bk   = (const float*)d_in[6];
    const float* Wv   = (const float*)d_in[7];
    const float* bv   = (const float*)d_in[8];
    const float* gpam = (const float*)d_in[9];
    const float* gcam = (const float*)d_in[10];
    const float* Wa1  = (const float*)d_in[11];
    const float* Wc1  = (const float*)d_in[12];
    const float* W1   = (const float*)d_in[13];
    const float* b1   = (const float*)d_in[14];
    const float* W2   = (const float*)d_in[15];
    const float* b2   = (const float*)d_in[16];
    const float* W3   = (const float*)d_in[17];
    const float* b3   = (const float*)d_in[18];
    float* out = (float*)d_out;

    // workspace layout (fp32 elements) — ~64.0 MB total
    float* ws   = (float*)d_ws;
    float* A    = ws;                 // [B,128,N] 2,097,152  (f1, later f2)
    float* Bv   = A  + 2097152;       // [B,128,N]            (v, later sa2/sc2)
    float* C    = Bv + 2097152;       // [B,128,N]            (sa, later sc)
    float* T    = C  + 2097152;       // [B,256,N] 4,194,304  (t1+t2 accumulator)
    float* Q    = T  + 4194304;       // [B,32,N]   524,288
    float* K2   = Q  + 524288;        // [B,32,N]   524,288
    float* came = K2 + 524288;        // [B,128,128] 65,536
    float* cama = came + 65536;       // [B,128,128] 65,536
    // flash split scratch: splits 0,1 alias T (dead until W1); splits 2,3 new.
    float* Oa   = T;                  // 2 x [B,128,N] partials
    float* Ob   = cama + 65536;       // 2 x [B,128,N] partials  4,194,304
    float* mpart= Ob + 4194304;       // [4][B][N]   65,536
    float* lpart= mpart + 65536;      // [4][B][N]   65,536

    const dim3 blk(256);
    auto grid_g = [](int Co) { return dim3(NN / 64, (Co + 63) / 64, B); };

    // ---- PAM branch ----
    gemm1x1<true><<<grid_g(CI), blk, 0, stream>>>(
        Wa, 0, x, nullptr, A, nullptr, nullptr, nullptr, CI, CIN, NN);
    gemm1x1<false><<<grid_g(CQ), blk, 0, stream>>>(
        Wq, 0, A, nullptr, Q, bq, nullptr, nullptr, CQ, CI, NN);
    gemm1x1<false><<<grid_g(CQ), blk, 0, stream>>>(
        Wk, 0, A, nullptr, K2, bk, nullptr, nullptr, CQ, CI, NN);
    gemm1x1<false><<<grid_g(CI), blk, 0, stream>>>(
        Wv, 0, A, nullptr, Bv, bv, nullptr, nullptr, CI, CI, NN);
    // flash partials (MFMA) over 4 KV splits, then merge: sa -> C
    pam_flash_mfma<<<dim3(NN / 128, B, NSPLIT), blk, 0, stream>>>(
        Q, K2, Bv, Oa, Ob, mpart, lpart, NN);
    pam_merge<<<dim3((B * CI * NN) / 256), blk, 0, stream>>>(
        Oa, Ob, mpart, lpart, A, gpam, C);
    gemm1x1<true><<<grid_g(CI), blk, 0, stream>>>(
        Wa1, 0, C, nullptr, Bv, nullptr, nullptr, nullptr, CI, CI, NN);
    gemm1x1<false><<<grid_g(COUT), blk, 0, stream>>>(
        W1, 0, Bv, nullptr, T, b1, nullptr, nullptr, COUT, CI, NN);

    // ---- CAM branch ----
    gemm1x1<true><<<grid_g(CI), blk, 0, stream>>>(
        Wc, 0, x, nullptr, A, nullptr, nullptr, nullptr, CI, CIN, NN);
    cam_energy<<<dim3(8, 8, B), blk, 0, stream>>>(A, came, NN);
    cam_softmax<<<dim3(B * CI), dim3(64), 0, stream>>>(came, cama);
    gemm1x1<false><<<grid_g(CI), blk, 0, stream>>>(
        cama, (long)CI * CI, A, nullptr, C, nullptr, gcam, A, CI, CI, NN);
    gemm1x1<true><<<grid_g(CI), blk, 0, stream>>>(
        Wc1, 0, C, nullptr, Bv, nullptr, nullptr, nullptr, CI, CI, NN);
    gemm1x1<false><<<grid_g(COUT), blk, 0, stream>>>(
        W2, 0, Bv, nullptr, T, b2, nullptr, T, COUT, CI, NN);

    // ---- out = W3 @ T + b3 ----
    gemm1x1<false><<<grid_g(COUT), blk, 0, stream>>>(
        W3, 0, T, nullptr, out, b3, nullptr, nullptr, COUT, COUT, NN);
}

// Round 9
// 332.383 us; speedup vs baseline: 3.7355x; 1.9650x over previous
//
#include <hip/hip_runtime.h>
#include <hip/hip_bf16.h>

// Problem constants (fixed by setup_inputs)
constexpr int B    = 4;
constexpr int CIN  = 512;
constexpr int NN   = 4096;
constexpr int CI   = 128;   // inter_channels
constexpr int CQ   = 32;    // PAM q/k dim
constexpr int COUT = 256;
constexpr int NSPLIT = 4;              // KV splits for pam flash
constexpr int KVLEN  = NN / NSPLIT;    // 1024 KV cols per split
constexpr int ESPLIT = 16;             // K splits for cam energy

typedef __bf16 bf16x8 __attribute__((ext_vector_type(8)));
typedef float  f32x4  __attribute__((ext_vector_type(4)));

// ---------------------------------------------------------------------------
// MFMA 1x1-conv GEMM, split-bf16 (hi/lo) for ~fp32 precision.
// Y[b,co,n] = epi( sum_k W[co,k] * X[b,k,n] ), epi = +bias, relu, *gamma, +resid
// Block: 64 n x 128 co, 4 waves (wave = 16 n x 128 co), BK=32.
// Grid: (N/64, ceil(Co/128), B). W per-batch via wbs (0 = shared).
// Fragment layout (HW-validated by round-8 flash): A row=lane&15 k=(lane>>4)*8+j;
// B col=lane&15 same k; D col=lane&15, row=(lane>>4)*4+reg.
// A = X^T tile (rows=n), B = W tile (cols=co) -> D row=n (float4 store).
// ---------------------------------------------------------------------------
template<bool RELU>
__global__ __launch_bounds__(256) void conv_mfma(
    const float* __restrict__ W, long wbs,
    const float* __restrict__ X,
    float* __restrict__ Y,
    const float* __restrict__ bias,
    const float* __restrict__ gamma_ptr,
    const float* __restrict__ resid,
    int Co, int K, int N)
{
    const int b   = blockIdx.z;
    const int n0  = blockIdx.x * 64;
    const int co0 = blockIdx.y * 128;
    const float* Wb = W + (size_t)b * wbs;
    const float* Xb = X + (size_t)b * K * N;

    __shared__ __bf16 Xh[64][40],  Xl[64][40];    // [n][k] (transposed)
    __shared__ __bf16 Wh[128][40], Wl[128][40];   // [co][k]

    const int t    = threadIdx.x;
    const int w    = t >> 6;
    const int lane = t & 63;
    const int gq   = lane >> 4;   // 0..3
    const int c    = lane & 15;   // 0..15

    f32x4 acc[8];
    #pragma unroll
    for (int cb = 0; cb < 8; ++cb) acc[cb] = (f32x4){0.f, 0.f, 0.f, 0.f};

    for (int kb = 0; kb < K; kb += 32) {
        // ---- stage X^T tile: X[b][kb+k][n0+n] -> Xh/Xl[n][k]
        {
            const int k  = t >> 3;          // 0..31
            const int n8 = (t & 7) * 8;     // 0..56
            const float* src = Xb + (size_t)(kb + k) * N + n0 + n8;
            float4 f0 = *reinterpret_cast<const float4*>(src);
            float4 f1 = *reinterpret_cast<const float4*>(src + 4);
            float fv[8] = {f0.x, f0.y, f0.z, f0.w, f1.x, f1.y, f1.z, f1.w};
            #pragma unroll
            for (int j = 0; j < 8; ++j) {
                __bf16 hi = (__bf16)fv[j];
                Xh[n8 + j][k] = hi;
                Xl[n8 + j][k] = (__bf16)(fv[j] - (float)hi);
            }
        }
        // ---- stage W tile: W[co0+co][kb+kh..] -> Wh/Wl[co][k]
        {
            const int co = t >> 1;          // 0..127
            const int kh = (t & 1) * 16;    // 0 or 16
            float fv[16];
            if (co0 + co < Co) {
                const float* src = Wb + (size_t)(co0 + co) * K + kb + kh;
                #pragma unroll
                for (int j = 0; j < 4; ++j) {
                    float4 f = *reinterpret_cast<const float4*>(src + 4 * j);
                    fv[4*j+0] = f.x; fv[4*j+1] = f.y; fv[4*j+2] = f.z; fv[4*j+3] = f.w;
                }
            } else {
                #pragma unroll
                for (int j = 0; j < 16; ++j) fv[j] = 0.f;
            }
            bf16x8 uh0, uh1, ul0, ul1;
            #pragma unroll
            for (int j = 0; j < 8; ++j) {
                __bf16 h0 = (__bf16)fv[j];
                __bf16 h1 = (__bf16)fv[8 + j];
                uh0[j] = h0; ul0[j] = (__bf16)(fv[j] - (float)h0);
                uh1[j] = h1; ul1[j] = (__bf16)(fv[8 + j] - (float)h1);
            }
            *reinterpret_cast<bf16x8*>(&Wh[co][kh])     = uh0;
            *reinterpret_cast<bf16x8*>(&Wh[co][kh + 8]) = uh1;
            *reinterpret_cast<bf16x8*>(&Wl[co][kh])     = ul0;
            *reinterpret_cast<bf16x8*>(&Wl[co][kh + 8]) = ul1;
        }
        __syncthreads();

        bf16x8 xah = *reinterpret_cast<const bf16x8*>(&Xh[16*w + c][gq * 8]);
        bf16x8 xal = *reinterpret_cast<const bf16x8*>(&Xl[16*w + c][gq * 8]);
        #pragma unroll
        for (int cb = 0; cb < 8; ++cb) {
            bf16x8 wbh = *reinterpret_cast<const bf16x8*>(&Wh[16*cb + c][gq * 8]);
            bf16x8 wbl = *reinterpret_cast<const bf16x8*>(&Wl[16*cb + c][gq * 8]);
            acc[cb] = __builtin_amdgcn_mfma_f32_16x16x32_bf16(xah, wbh, acc[cb], 0, 0, 0);
            acc[cb] = __builtin_amdgcn_mfma_f32_16x16x32_bf16(xah, wbl, acc[cb], 0, 0, 0);
            acc[cb] = __builtin_amdgcn_mfma_f32_16x16x32_bf16(xal, wbh, acc[cb], 0, 0, 0);
        }
        __syncthreads();
    }

    // ---- epilogue: D row = n (contiguous), col = co
    const float g = gamma_ptr ? *gamma_ptr : 1.f;
    const int nb = n0 + 16 * w + 4 * gq;
    #pragma unroll
    for (int cb = 0; cb < 8; ++cb) {
        int co = co0 + 16 * cb + c;
        if (co >= Co) continue;
        float bv = bias ? bias[co] : 0.f;
        size_t base = (size_t)(b * Co + co) * N + nb;
        float4 o;
        float* op = &o.x;
        #pragma unroll
        for (int r = 0; r < 4; ++r) {
            float val = acc[cb][r] + bv;
            if (RELU) val = fmaxf(val, 0.f);
            val *= g;
            op[r] = val;
        }
        if (resid) {
            float4 rv = *reinterpret_cast<const float4*>(&resid[base]);
            o.x += rv.x; o.y += rv.y; o.z += rv.z; o.w += rv.w;
        }
        *reinterpret_cast<float4*>(&Y[base]) = o;
    }
}

// ---------------------------------------------------------------------------
// PAM flash attention partial, MFMA bf16 (unchanged from round 8).
// ---------------------------------------------------------------------------
__global__ __launch_bounds__(256) void pam_flash_mfma(
    const float* __restrict__ q, const float* __restrict__ k,
    const float* __restrict__ v,
    float* __restrict__ Oa, float* __restrict__ Ob,
    float* __restrict__ mp, float* __restrict__ lp, int N)
{
    const int b  = blockIdx.y;
    const int s  = blockIdx.z;
    const int n0 = blockIdx.x * 128;
    const float* qb = q + (size_t)b * CQ * N;
    const float* kb = k + (size_t)b * CQ * N;
    const float* vb = v + (size_t)b * CI * N;
    const size_t PART = (size_t)B * CI * N;
    float* Op = (s < 2 ? Oa : Ob) + (size_t)(s & 1) * PART;

    __shared__ __bf16 Klds[32][40];    // [m][c]  (K^T)
    __shared__ __bf16 Vlds[128][40];   // [vc][m]
    __shared__ __bf16 QP[128][40];     // Q^T staging [n][c]; then per-wave P [row][m]

    const int t    = threadIdx.x;
    const int w    = t >> 6;
    const int lane = t & 63;
    const int g    = lane >> 4;   // 0..3
    const int c    = lane & 15;   // 0..15

    // ---- stage Q^T once: QP[n][cq] = q[cq][n0+n], bf16
    {
        const int cq = t >> 3;           // 0..31
        const int nb = (t & 7) * 16;     // 0..112
        const float* src = qb + (size_t)cq * N + n0 + nb;
        #pragma unroll
        for (int j = 0; j < 4; ++j) {
            float4 f = *reinterpret_cast<const float4*>(src + 4 * j);
            QP[nb + 4*j + 0][cq] = (__bf16)f.x;
            QP[nb + 4*j + 1][cq] = (__bf16)f.y;
            QP[nb + 4*j + 2][cq] = (__bf16)f.z;
            QP[nb + 4*j + 3][cq] = (__bf16)f.w;
        }
    }
    __syncthreads();
    bf16x8 qa[2];
    #pragma unroll
    for (int rb = 0; rb < 2; ++rb)
        qa[rb] = *reinterpret_cast<const bf16x8*>(&QP[32*w + 16*rb + c][g * 8]);
    __syncthreads();   // QP region now recycled as per-wave P buffer

    f32x4 acc[2][8];
    #pragma unroll
    for (int rb = 0; rb < 2; ++rb)
        #pragma unroll
        for (int vbk = 0; vbk < 8; ++vbk)
            acc[rb][vbk] = (f32x4){0.f, 0.f, 0.f, 0.f};
    float ms[2][4], ls[2][4];
    #pragma unroll
    for (int rb = 0; rb < 2; ++rb)
        #pragma unroll
        for (int r = 0; r < 4; ++r) { ms[rb][r] = -1e30f; ls[rb][r] = 0.f; }

    const int mstart = s * KVLEN;
    for (int mt = 0; mt < KVLEN / 32; ++mt) {
        const int m0 = mstart + mt * 32;
        {
            const int ck = t >> 3;        // 0..31
            const int m4 = (t & 7) * 4;
            float4 f = *reinterpret_cast<const float4*>(kb + (size_t)ck * N + m0 + m4);
            Klds[m4 + 0][ck] = (__bf16)f.x;
            Klds[m4 + 1][ck] = (__bf16)f.y;
            Klds[m4 + 2][ck] = (__bf16)f.z;
            Klds[m4 + 3][ck] = (__bf16)f.w;
        }
        {
            const int cv = t >> 1;        // 0..127
            const int mh = (t & 1) * 16;
            const float* src = vb + (size_t)cv * N + m0 + mh;
            #pragma unroll
            for (int j = 0; j < 2; ++j) {
                float4 f0 = *reinterpret_cast<const float4*>(src + 8 * j);
                float4 f1 = *reinterpret_cast<const float4*>(src + 8 * j + 4);
                bf16x8 u;
                u[0]=(__bf16)f0.x; u[1]=(__bf16)f0.y; u[2]=(__bf16)f0.z; u[3]=(__bf16)f0.w;
                u[4]=(__bf16)f1.x; u[5]=(__bf16)f1.y; u[6]=(__bf16)f1.z; u[7]=(__bf16)f1.w;
                *reinterpret_cast<bf16x8*>(&Vlds[cv][mh + 8 * j]) = u;
            }
        }
        __syncthreads();

        f32x4 sv[2][2];
        #pragma unroll
        for (int cb = 0; cb < 2; ++cb) {
            bf16x8 kf = *reinterpret_cast<const bf16x8*>(&Klds[16*cb + c][g * 8]);
            #pragma unroll
            for (int rb = 0; rb < 2; ++rb)
                sv[rb][cb] = __builtin_amdgcn_mfma_f32_16x16x32_bf16(
                    qa[rb], kf, (f32x4){0.f, 0.f, 0.f, 0.f}, 0, 0, 0);
        }

        float scale[2][4];
        #pragma unroll
        for (int rb = 0; rb < 2; ++rb) {
            #pragma unroll
            for (int r = 0; r < 4; ++r) {
                float mx = fmaxf(sv[rb][0][r], sv[rb][1][r]);
                #pragma unroll
                for (int off = 1; off < 16; off <<= 1)
                    mx = fmaxf(mx, __shfl_xor(mx, off));
                float mnew = fmaxf(ms[rb][r], mx);
                scale[rb][r] = __expf(ms[rb][r] - mnew);
                ms[rb][r] = mnew;
                float p0 = __expf(sv[rb][0][r] - mnew);
                float p1 = __expf(sv[rb][1][r] - mnew);
                sv[rb][0][r] = p0; sv[rb][1][r] = p1;
                float psum = p0 + p1;
                #pragma unroll
                for (int off = 1; off < 16; off <<= 1)
                    psum += __shfl_xor(psum, off);
                ls[rb][r] = ls[rb][r] * scale[rb][r] + psum;
            }
        }

        #pragma unroll
        for (int rb = 0; rb < 2; ++rb)
            #pragma unroll
            for (int cb = 0; cb < 2; ++cb)
                #pragma unroll
                for (int r = 0; r < 4; ++r)
                    QP[32*w + 16*rb + 4*g + r][16*cb + c] = (__bf16)sv[rb][cb][r];

        #pragma unroll
        for (int rb = 0; rb < 2; ++rb)
            #pragma unroll
            for (int vbk = 0; vbk < 8; ++vbk)
                #pragma unroll
                for (int r = 0; r < 4; ++r)
                    acc[rb][vbk][r] *= scale[rb][r];

        bf16x8 pa[2];
        #pragma unroll
        for (int rb = 0; rb < 2; ++rb)
            pa[rb] = *reinterpret_cast<const bf16x8*>(&QP[32*w + 16*rb + c][g * 8]);
        #pragma unroll
        for (int vbk = 0; vbk < 8; ++vbk) {
            bf16x8 vf = *reinterpret_cast<const bf16x8*>(&Vlds[16*vbk + c][g * 8]);
            #pragma unroll
            for (int rb = 0; rb < 2; ++rb)
                acc[rb][vbk] = __builtin_amdgcn_mfma_f32_16x16x32_bf16(
                    pa[rb], vf, acc[rb][vbk], 0, 0, 0);
        }
        __syncthreads();
    }

    #pragma unroll
    for (int rb = 0; rb < 2; ++rb)
        #pragma unroll
        for (int vbk = 0; vbk < 8; ++vbk) {
            float4 o = { acc[rb][vbk][0], acc[rb][vbk][1],
                         acc[rb][vbk][2], acc[rb][vbk][3] };
            *reinterpret_cast<float4*>(
                &Op[((size_t)(b * CI + 16*vbk + c)) * N + n0 + 32*w + 16*rb + 4*g]) = o;
        }
    if (c == 0) {
        #pragma unroll
        for (int rb = 0; rb < 2; ++rb)
            #pragma unroll
            for (int r = 0; r < 4; ++r) {
                int n = n0 + 32*w + 16*rb + 4*g + r;
                mp[(size_t)(s * B + b) * N + n] = ms[rb][r];
                lp[(size_t)(s * B + b) * N + n] = ls[rb][r];
            }
    }
}

// ---------------------------------------------------------------------------
// Merge NSPLIT flash partials (unchanged).
// ---------------------------------------------------------------------------
__global__ __launch_bounds__(256) void pam_merge(
    const float* __restrict__ Oa, const float* __restrict__ Ob,
    const float* __restrict__ mp, const float* __restrict__ lp,
    const float* __restrict__ f1, const float* __restrict__ gamma_ptr,
    float* __restrict__ sa)
{
    const size_t PART = (size_t)B * CI * NN;
    size_t idx = (size_t)blockIdx.x * 256 + threadIdx.x;   // over B*CI*NN
    const int n = (int)(idx & (NN - 1));
    const int b = (int)(idx >> 19);                        // CI*NN = 2^19

    float m0 = mp[(size_t)(0 * B + b) * NN + n];
    float m1 = mp[(size_t)(1 * B + b) * NN + n];
    float m2 = mp[(size_t)(2 * B + b) * NN + n];
    float m3 = mp[(size_t)(3 * B + b) * NN + n];
    float M = fmaxf(fmaxf(m0, m1), fmaxf(m2, m3));
    float w0 = __expf(m0 - M), w1 = __expf(m1 - M);
    float w2 = __expf(m2 - M), w3 = __expf(m3 - M);
    float L = lp[(size_t)(0 * B + b) * NN + n] * w0
            + lp[(size_t)(1 * B + b) * NN + n] * w1
            + lp[(size_t)(2 * B + b) * NN + n] * w2
            + lp[(size_t)(3 * B + b) * NN + n] * w3;
    float O = Oa[idx] * w0 + Oa[PART + idx] * w1
            + Ob[idx] * w2 + Ob[PART + idx] * w3;
    sa[idx] = (*gamma_ptr) * (O / L) + f1[idx];
}

// ---------------------------------------------------------------------------
// CAM energy, K-split partials: ep[s][b][i][j] = sum_{n in chunk s} f2[i,n]f2[j,n]
// Grid (B, ESPLIT); block 256 thr, 8x8 register tile per thread; fp32 exact.
// ---------------------------------------------------------------------------
__global__ __launch_bounds__(256) void cam_energy_part(
    const float* __restrict__ f2, float* __restrict__ ep, int N)
{
    const int b = blockIdx.x;
    const int s = blockIdx.y;
    const float* fb = f2 + (size_t)b * CI * N;
    const int kbase = s * (NN / ESPLIT);       // 256-wide chunk

    __shared__ float fs[128][33];
    const int t  = threadIdx.x;
    const int ti = t >> 4;     // 0..15  (i block: rows ti*8..)
    const int tj = t & 15;     // 0..15  (j block)

    float acc[8][8] = {};
    for (int st = 0; st < (NN / ESPLIT) / 32; ++st) {
        const int k0 = kbase + st * 32;
        {
            const int ch  = t >> 1;
            const int k16 = (t & 1) * 16;
            const float* src = fb + (size_t)ch * N + k0 + k16;
            #pragma unroll
            for (int j = 0; j < 4; ++j)
                *reinterpret_cast<float4*>(&fs[ch][k16 + 4*j]) =
                    *reinterpret_cast<const float4*>(src + 4*j);
        }
        __syncthreads();
        #pragma unroll 4
        for (int k = 0; k < 32; ++k) {
            float av[8], bv[8];
            #pragma unroll
            for (int ii = 0; ii < 8; ++ii) av[ii] = fs[ti * 8 + ii][k];
            #pragma unroll
            for (int jj = 0; jj < 8; ++jj) bv[jj] = fs[tj * 8 + jj][k];
            #pragma unroll
            for (int ii = 0; ii < 8; ++ii)
                #pragma unroll
                for (int jj = 0; jj < 8; ++jj)
                    acc[ii][jj] += av[ii] * bv[jj];
        }
        __syncthreads();
    }
    float* dst = ep + ((size_t)(s * B + b)) * CI * CI;
    #pragma unroll
    for (int ii = 0; ii < 8; ++ii)
        #pragma unroll
        for (int jj = 0; jj < 8; ++jj)
            dst[(size_t)(ti * 8 + ii) * CI + tj * 8 + jj] = acc[ii][jj];
}

// came[idx] = sum_s ep[s][idx],  idx over B*CI*CI
__global__ __launch_bounds__(256) void cam_energy_reduce(
    const float* __restrict__ ep, float* __restrict__ came)
{
    const size_t n = (size_t)B * CI * CI;
    size_t idx = (size_t)blockIdx.x * 256 + threadIdx.x;
    float s = 0.f;
    #pragma unroll
    for (int j = 0; j < ESPLIT; ++j) s += ep[j * n + idx];
    came[idx] = s;
}

// ---------------------------------------------------------------------------
// CAM softmax: attn[row, j] = exp(rowmin - e[row,j]) / sum (rowmax cancels)
// ---------------------------------------------------------------------------
__global__ __launch_bounds__(64) void cam_softmax(
    const float* __restrict__ e, float* __restrict__ attn)
{
    const int row = blockIdx.x;   // b*128 + i
    const float* er = e + (size_t)row * CI;
    const int t = threadIdx.x;
    float v0 = er[t], v1 = er[t + 64];
    float mn = fminf(v0, v1);
    #pragma unroll
    for (int off = 32; off; off >>= 1) mn = fminf(mn, __shfl_xor(mn, off));
    float p0 = __expf(mn - v0), p1 = __expf(mn - v1);
    float s = p0 + p1;
    #pragma unroll
    for (int off = 32; off; off >>= 1) s += __shfl_xor(s, off);
    float inv = 1.f / s;
    attn[(size_t)row * CI + t]      = p0 * inv;
    attn[(size_t)row * CI + t + 64] = p1 * inv;
}

// ---------------------------------------------------------------------------
extern "C" void kernel_launch(void* const* d_in, const int* in_sizes, int n_in,
                              void* d_out, int out_size, void* d_ws, size_t ws_size,
                              hipStream_t stream)
{
    const float* x    = (const float*)d_in[0];
    const float* Wa   = (const float*)d_in[1];
    const float* Wc   = (const float*)d_in[2];
    const float* Wq   = (const float*)d_in[3];
    const float* bq   = (const float*)d_in[4];
    const float* Wk   = (const float*)d_in[5];
    const float* bk   = (const float*)d_in[6];
    const float* Wv   = (const float*)d_in[7];
    const float* bv   = (const float*)d_in[8];
    const float* gpam = (const float*)d_in[9];
    const float* gcam = (const float*)d_in[10];
    const float* Wa1  = (const float*)d_in[11];
    const float* Wc1  = (const float*)d_in[12];
    const float* W1   = (const float*)d_in[13];
    const float* b1   = (const float*)d_in[14];
    const float* W2   = (const float*)d_in[15];
    const float* b2   = (const float*)d_in[16];
    const float* W3   = (const float*)d_in[17];
    const float* b3   = (const float*)d_in[18];
    float* out = (float*)d_out;

    // workspace layout (fp32 elements) — ~68 MB total
    float* ws    = (float*)d_ws;
    float* A     = ws;                 // [B,128,N] 2,097,152  (f1, later f2)
    float* Bv    = A  + 2097152;       // [B,128,N]            (v, later sa2/sc2)
    float* C     = Bv + 2097152;       // [B,128,N]            (sa, later sc)
    float* T     = C  + 2097152;       // [B,256,N] 4,194,304  (t1+t2 accumulator)
    float* Q     = T  + 4194304;       // [B,32,N]   524,288
    float* K2    = Q  + 524288;        // [B,32,N]   524,288
    float* came  = K2 + 524288;        // [B,128,128] 65,536
    float* cama  = came + 65536;       // [B,128,128] 65,536
    float* Oa    = T;                  // alias: 2 x [B,128,N] flash partials
    float* Ob    = cama + 65536;       // 2 x [B,128,N]       4,194,304
    float* mpart = Ob + 4194304;       // [4][B][N]   65,536
    float* lpart = mpart + 65536;      // [4][B][N]   65,536
    float* epart = lpart + 65536;      // [16][B][128][128] 1,048,576

    const dim3 blk(256);
    auto grid_c = [](int Co) { return dim3(NN / 64, (Co + 127) / 128, B); };

    // ---- PAM branch ----
    conv_mfma<true><<<grid_c(CI), blk, 0, stream>>>(
        Wa, 0, x, A, nullptr, nullptr, nullptr, CI, CIN, NN);
    conv_mfma<false><<<grid_c(CQ), blk, 0, stream>>>(
        Wq, 0, A, Q, bq, nullptr, nullptr, CQ, CI, NN);
    conv_mfma<false><<<grid_c(CQ), blk, 0, stream>>>(
        Wk, 0, A, K2, bk, nullptr, nullptr, CQ, CI, NN);
    conv_mfma<false><<<grid_c(CI), blk, 0, stream>>>(
        Wv, 0, A, Bv, bv, nullptr, nullptr, CI, CI, NN);
    pam_flash_mfma<<<dim3(NN / 128, B, NSPLIT), blk, 0, stream>>>(
        Q, K2, Bv, Oa, Ob, mpart, lpart, NN);
    pam_merge<<<dim3((B * CI * NN) / 256), blk, 0, stream>>>(
        Oa, Ob, mpart, lpart, A, gpam, C);
    conv_mfma<true><<<grid_c(CI), blk, 0, stream>>>(
        Wa1, 0, C, Bv, nullptr, nullptr, nullptr, CI, CI, NN);
    conv_mfma<false><<<grid_c(COUT), blk, 0, stream>>>(
        W1, 0, Bv, T, b1, nullptr, nullptr, COUT, CI, NN);

    // ---- CAM branch ----
    conv_mfma<true><<<grid_c(CI), blk, 0, stream>>>(
        Wc, 0, x, A, nullptr, nullptr, nullptr, CI, CIN, NN);
    cam_energy_part<<<dim3(B, ESPLIT), blk, 0, stream>>>(A, epart, NN);
    cam_energy_reduce<<<dim3((B * CI * CI) / 256), blk, 0, stream>>>(epart, came);
    cam_softmax<<<dim3(B * CI), dim3(64), 0, stream>>>(came, cama);
    conv_mfma<false><<<grid_c(CI), blk, 0, stream>>>(
        cama, (long)CI * CI, A, C, nullptr, gcam, A, CI, CI, NN);
    conv_mfma<true><<<grid_c(CI), blk, 0, stream>>>(
        Wc1, 0, C, Bv, nullptr, nullptr, nullptr, CI, CI, NN);
    conv_mfma<false><<<grid_c(COUT), blk, 0, stream>>>(
        W2, 0, Bv, T, b2, nullptr, T, COUT, CI, NN);

    // ---- out = W3 @ T + b3 ----
    conv_mfma<false><<<grid_c(COUT), blk, 0, stream>>>(
        W3, 0, T, out, b3, nullptr, nullptr, COUT, COUT, NN);
}

// Round 10
// 327.157 us; speedup vs baseline: 3.7952x; 1.0160x over previous
//
#include <hip/hip_runtime.h>
#include <hip/hip_bf16.h>

// Problem constants (fixed by setup_inputs)
constexpr int B    = 4;
constexpr int CIN  = 512;
constexpr int NN   = 4096;
constexpr int CI   = 128;   // inter_channels
constexpr int CQ   = 32;    // PAM q/k dim
constexpr int COUT = 256;
constexpr int NSPLIT = 8;              // KV splits for pam flash
constexpr int KVLEN  = NN / NSPLIT;    // 512 KV cols per split

typedef __bf16 bf16x8 __attribute__((ext_vector_type(8)));
typedef float  f32x4  __attribute__((ext_vector_type(4)));

struct Ptr8 { float* p[8]; };

// ---------------------------------------------------------------------------
// MFMA 1x1-conv GEMM, plain bf16 (absmax budget verified: floor is 0.0156
// with fp32 compute, threshold 0.0875).
// Block: 64 n x 64 co, 4 waves (wave = 16 n x 64 co), BK=32.
// Grid: (N/64, ceil(Co/64), B). W per-batch via wbs (0 = shared).
// Fragment layout (HW-validated rounds 8/9): A row=lane&15 k=(lane>>4)*8+j;
// B col=lane&15 same k; D col=lane&15, row=(lane>>4)*4+reg.
// X scalar LDS stores use j-rotation to spread banks (8->~3x fewer conflicts).
// ---------------------------------------------------------------------------
template<bool RELU>
__global__ __launch_bounds__(256) void conv_mfma(
    const float* __restrict__ W, long wbs,
    const float* __restrict__ X,
    float* __restrict__ Y,
    const float* __restrict__ bias,
    const float* __restrict__ gamma_ptr,
    const float* __restrict__ resid,
    int Co, int K, int N)
{
    const int b   = blockIdx.z;
    const int n0  = blockIdx.x * 64;
    const int co0 = blockIdx.y * 64;
    const float* Wb = W + (size_t)b * wbs;
    const float* Xb = X + (size_t)b * K * N;

    __shared__ __bf16 Xs[64][40];   // [n][k] (transposed)
    __shared__ __bf16 Ws[64][40];   // [co][k]

    const int t    = threadIdx.x;
    const int w    = t >> 6;
    const int lane = t & 63;
    const int gq   = lane >> 4;   // 0..3
    const int c    = lane & 15;   // 0..15

    f32x4 acc[4];
    #pragma unroll
    for (int cb = 0; cb < 4; ++cb) acc[cb] = (f32x4){0.f, 0.f, 0.f, 0.f};

    for (int kb = 0; kb < K; kb += 32) {
        // ---- stage X^T tile: X[b][kb+k][n0+n] -> Xs[n][k], rotated stores
        {
            const int k  = t >> 3;          // 0..31
            const int n8 = (t & 7) * 8;     // 0..56
            const float* src = Xb + (size_t)(kb + k) * N + n0 + n8;
            float4 f0 = *reinterpret_cast<const float4*>(src);
            float4 f1 = *reinterpret_cast<const float4*>(src + 4);
            float fv[8] = {f0.x, f0.y, f0.z, f0.w, f1.x, f1.y, f1.z, f1.w};
            #pragma unroll
            for (int j = 0; j < 8; ++j) {
                int jj = (j + (k & 7)) & 7;   // bank-spread rotation
                Xs[n8 + jj][k] = (__bf16)fv[jj];
            }
        }
        // ---- stage W tile: W[co0+co][kb+kh..] -> Ws[co][k], vector stores
        {
            const int co = t >> 2;          // 0..63
            const int kh = (t & 3) * 8;     // 0,8,16,24
            float fv[8];
            if (co0 + co < Co) {
                const float* src = Wb + (size_t)(co0 + co) * K + kb + kh;
                float4 f0 = *reinterpret_cast<const float4*>(src);
                float4 f1 = *reinterpret_cast<const float4*>(src + 4);
                fv[0]=f0.x; fv[1]=f0.y; fv[2]=f0.z; fv[3]=f0.w;
                fv[4]=f1.x; fv[5]=f1.y; fv[6]=f1.z; fv[7]=f1.w;
            } else {
                #pragma unroll
                for (int j = 0; j < 8; ++j) fv[j] = 0.f;
            }
            bf16x8 u;
            #pragma unroll
            for (int j = 0; j < 8; ++j) u[j] = (__bf16)fv[j];
            *reinterpret_cast<bf16x8*>(&Ws[co][kh]) = u;
        }
        __syncthreads();

        bf16x8 xa = *reinterpret_cast<const bf16x8*>(&Xs[16*w + c][gq * 8]);
        #pragma unroll
        for (int cb = 0; cb < 4; ++cb) {
            bf16x8 wf = *reinterpret_cast<const bf16x8*>(&Ws[16*cb + c][gq * 8]);
            acc[cb] = __builtin_amdgcn_mfma_f32_16x16x32_bf16(xa, wf, acc[cb], 0, 0, 0);
        }
        __syncthreads();
    }

    // ---- epilogue: D row = n (contiguous float4), col = co
    const float g = gamma_ptr ? *gamma_ptr : 1.f;
    const int nb = n0 + 16 * w + 4 * gq;
    #pragma unroll
    for (int cb = 0; cb < 4; ++cb) {
        int co = co0 + 16 * cb + c;
        if (co >= Co) continue;
        float bv = bias ? bias[co] : 0.f;
        size_t base = (size_t)(b * Co + co) * N + nb;
        float4 o;
        float* op = &o.x;
        #pragma unroll
        for (int r = 0; r < 4; ++r) {
            float val = acc[cb][r] + bv;
            if (RELU) val = fmaxf(val, 0.f);
            val *= g;
            op[r] = val;
        }
        if (resid) {
            float4 rv = *reinterpret_cast<const float4*>(&resid[base]);
            o.x += rv.x; o.y += rv.y; o.z += rv.z; o.w += rv.w;
        }
        *reinterpret_cast<float4*>(&Y[base]) = o;
    }
}

// ---------------------------------------------------------------------------
// PAM flash attention partial, MFMA bf16. NSPLIT=8 for occupancy.
// Grid: (NN/128, B, NSPLIT); block 256 thr / 4 waves; 128 Q-rows per block.
// Adds: defer-rescale (exact skip when scale==1), rotated scalar LDS stores.
// ---------------------------------------------------------------------------
__global__ __launch_bounds__(256) void pam_flash_mfma(
    const float* __restrict__ q, const float* __restrict__ k,
    const float* __restrict__ v,
    Ptr8 op8,
    float* __restrict__ mp, float* __restrict__ lp, int N)
{
    const int b  = blockIdx.y;
    const int s  = blockIdx.z;
    const int n0 = blockIdx.x * 128;
    const float* qb = q + (size_t)b * CQ * N;
    const float* kb = k + (size_t)b * CQ * N;
    const float* vb = v + (size_t)b * CI * N;
    float* Op = op8.p[s];

    __shared__ __bf16 Klds[32][40];    // [m][c]  (K^T)
    __shared__ __bf16 Vlds[128][40];   // [vc][m]
    __shared__ __bf16 QP[128][40];     // Q^T staging [n][c]; then per-wave P

    const int t    = threadIdx.x;
    const int w    = t >> 6;
    const int lane = t & 63;
    const int g    = lane >> 4;   // 0..3
    const int c    = lane & 15;   // 0..15

    // ---- stage Q^T once: QP[n][cq] = q[cq][n0+n], rotated stores
    {
        const int cq = t >> 3;           // 0..31
        const int nb = (t & 7) * 16;     // 0..112
        const float* src = qb + (size_t)cq * N + n0 + nb;
        float fq[16];
        #pragma unroll
        for (int j = 0; j < 4; ++j) {
            float4 f = *reinterpret_cast<const float4*>(src + 4 * j);
            fq[4*j+0] = f.x; fq[4*j+1] = f.y; fq[4*j+2] = f.z; fq[4*j+3] = f.w;
        }
        #pragma unroll
        for (int idx = 0; idx < 16; ++idx) {
            int id2 = (idx + cq) & 15;   // bank-spread rotation
            QP[nb + id2][cq] = (__bf16)fq[id2];
        }
    }
    __syncthreads();
    bf16x8 qa[2];
    #pragma unroll
    for (int rb = 0; rb < 2; ++rb)
        qa[rb] = *reinterpret_cast<const bf16x8*>(&QP[32*w + 16*rb + c][g * 8]);
    __syncthreads();   // QP region now recycled as per-wave P buffer

    f32x4 acc[2][8];
    #pragma unroll
    for (int rb = 0; rb < 2; ++rb)
        #pragma unroll
        for (int vbk = 0; vbk < 8; ++vbk)
            acc[rb][vbk] = (f32x4){0.f, 0.f, 0.f, 0.f};
    float ms[2][4], ls[2][4];
    #pragma unroll
    for (int rb = 0; rb < 2; ++rb)
        #pragma unroll
        for (int r = 0; r < 4; ++r) { ms[rb][r] = -1e30f; ls[rb][r] = 0.f; }

    const int mstart = s * KVLEN;
    for (int mt = 0; mt < KVLEN / 32; ++mt) {
        const int m0 = mstart + mt * 32;
        // ---- stage K^T tile (rotated scalar stores)
        {
            const int ck = t >> 3;        // 0..31
            const int m4 = (t & 7) * 4;
            float4 f = *reinterpret_cast<const float4*>(kb + (size_t)ck * N + m0 + m4);
            float fk[4] = {f.x, f.y, f.z, f.w};
            #pragma unroll
            for (int j = 0; j < 4; ++j) {
                int jj = (j + ck) & 3;
                Klds[m4 + jj][ck] = (__bf16)fk[jj];
            }
        }
        // ---- stage V tile (vector stores)
        {
            const int cv = t >> 1;        // 0..127
            const int mh = (t & 1) * 16;
            const float* src = vb + (size_t)cv * N + m0 + mh;
            #pragma unroll
            for (int j = 0; j < 2; ++j) {
                float4 f0 = *reinterpret_cast<const float4*>(src + 8 * j);
                float4 f1 = *reinterpret_cast<const float4*>(src + 8 * j + 4);
                bf16x8 u;
                u[0]=(__bf16)f0.x; u[1]=(__bf16)f0.y; u[2]=(__bf16)f0.z; u[3]=(__bf16)f0.w;
                u[4]=(__bf16)f1.x; u[5]=(__bf16)f1.y; u[6]=(__bf16)f1.z; u[7]=(__bf16)f1.w;
                *reinterpret_cast<bf16x8*>(&Vlds[cv][mh + 8 * j]) = u;
            }
        }
        __syncthreads();

        // ---- QK^T: 4 MFMAs per wave
        f32x4 sv[2][2];
        #pragma unroll
        for (int cb = 0; cb < 2; ++cb) {
            bf16x8 kf = *reinterpret_cast<const bf16x8*>(&Klds[16*cb + c][g * 8]);
            #pragma unroll
            for (int rb = 0; rb < 2; ++rb)
                sv[rb][cb] = __builtin_amdgcn_mfma_f32_16x16x32_bf16(
                    qa[rb], kf, (f32x4){0.f, 0.f, 0.f, 0.f}, 0, 0, 0);
        }

        // ---- online softmax
        float scale[2][4];
        bool need = false;
        #pragma unroll
        for (int rb = 0; rb < 2; ++rb) {
            #pragma unroll
            for (int r = 0; r < 4; ++r) {
                float mx = fmaxf(sv[rb][0][r], sv[rb][1][r]);
                #pragma unroll
                for (int off = 1; off < 16; off <<= 1)
                    mx = fmaxf(mx, __shfl_xor(mx, off));
                float mnew = fmaxf(ms[rb][r], mx);
                scale[rb][r] = __expf(ms[rb][r] - mnew);
                ms[rb][r] = mnew;
                float p0 = __expf(sv[rb][0][r] - mnew);
                float p1 = __expf(sv[rb][1][r] - mnew);
                sv[rb][0][r] = p0; sv[rb][1][r] = p1;
                float psum = p0 + p1;
                #pragma unroll
                for (int off = 1; off < 16; off <<= 1)
                    psum += __shfl_xor(psum, off);
                ls[rb][r] = ls[rb][r] * scale[rb][r] + psum;
                need |= (scale[rb][r] != 1.0f);
            }
        }

        // ---- P -> LDS (rotated scalar stores, own wave's slice)
        #pragma unroll
        for (int rb = 0; rb < 2; ++rb)
            #pragma unroll
            for (int cb = 0; cb < 2; ++cb)
                #pragma unroll
                for (int r = 0; r < 4; ++r) {
                    int rr = (r + c) & 3;
                    QP[32*w + 16*rb + 4*g + rr][16*cb + c] = (__bf16)sv[rb][cb][rr];
                }

        // ---- rescale acc only when needed (exact skip: scale==1 otherwise)
        if (__any(need)) {
            #pragma unroll
            for (int rb = 0; rb < 2; ++rb)
                #pragma unroll
                for (int vbk = 0; vbk < 8; ++vbk)
                    #pragma unroll
                    for (int r = 0; r < 4; ++r)
                        acc[rb][vbk][r] *= scale[rb][r];
        }

        // ---- PV: 16 MFMAs per wave
        bf16x8 pa[2];
        #pragma unroll
        for (int rb = 0; rb < 2; ++rb)
            pa[rb] = *reinterpret_cast<const bf16x8*>(&QP[32*w + 16*rb + c][g * 8]);
        #pragma unroll
        for (int vbk = 0; vbk < 8; ++vbk) {
            bf16x8 vf = *reinterpret_cast<const bf16x8*>(&Vlds[16*vbk + c][g * 8]);
            #pragma unroll
            for (int rb = 0; rb < 2; ++rb)
                acc[rb][vbk] = __builtin_amdgcn_mfma_f32_16x16x32_bf16(
                    pa[rb], vf, acc[rb][vbk], 0, 0, 0);
        }
        __syncthreads();
    }

    // ---- epilogue: unnormalized partial O + per-row (m,l)
    #pragma unroll
    for (int rb = 0; rb < 2; ++rb)
        #pragma unroll
        for (int vbk = 0; vbk < 8; ++vbk) {
            float4 o = { acc[rb][vbk][0], acc[rb][vbk][1],
                         acc[rb][vbk][2], acc[rb][vbk][3] };
            *reinterpret_cast<float4*>(
                &Op[((size_t)(b * CI + 16*vbk + c)) * N + n0 + 32*w + 16*rb + 4*g]) = o;
        }
    if (c == 0) {
        #pragma unroll
        for (int rb = 0; rb < 2; ++rb)
            #pragma unroll
            for (int r = 0; r < 4; ++r) {
                int n = n0 + 32*w + 16*rb + 4*g + r;
                mp[(size_t)(s * B + b) * N + n] = ms[rb][r];
                lp[(size_t)(s * B + b) * N + n] = ls[rb][r];
            }
    }
}

// ---------------------------------------------------------------------------
// Merge NSPLIT=8 flash partials: per (b,c,n):
//   M = max_s m_s; w_s = exp(m_s-M); L = sum l_s w_s; O = sum O_s w_s / L;
//   sa = gamma*O + f1.  (partial 4 aliases sa's buffer: each element is
//   read only by its owning thread before that thread writes it.)
// ---------------------------------------------------------------------------
__global__ __launch_bounds__(256) void pam_merge(
    Ptr8 op8,
    const float* __restrict__ mp, const float* __restrict__ lp,
    const float* __restrict__ f1, const float* __restrict__ gamma_ptr,
    float* __restrict__ sa)
{
    size_t idx = (size_t)blockIdx.x * 256 + threadIdx.x;   // over B*CI*NN
    const int n = (int)(idx & (NN - 1));
    const int b = (int)(idx >> 19);                        // CI*NN = 2^19

    float m[NSPLIT], l[NSPLIT];
    float M = -1e30f;
    #pragma unroll
    for (int s = 0; s < NSPLIT; ++s) {
        m[s] = mp[(size_t)(s * B + b) * NN + n];
        l[s] = lp[(size_t)(s * B + b) * NN + n];
        M = fmaxf(M, m[s]);
    }
    float L = 0.f, O = 0.f;
    #pragma unroll
    for (int s = 0; s < NSPLIT; ++s) {
        float ws = __expf(m[s] - M);
        L += l[s] * ws;
        O += op8.p[s][idx] * ws;
    }
    sa[idx] = (*gamma_ptr) * (O / L) + f1[idx];
}

// ---------------------------------------------------------------------------
// CAM energy, K-split partials (unchanged from round 9).
// ---------------------------------------------------------------------------
constexpr int ESPLIT = 16;
__global__ __launch_bounds__(256) void cam_energy_part(
    const float* __restrict__ f2, float* __restrict__ ep, int N)
{
    const int b = blockIdx.x;
    const int s = blockIdx.y;
    const float* fb = f2 + (size_t)b * CI * N;
    const int kbase = s * (NN / ESPLIT);

    __shared__ float fs[128][33];
    const int t  = threadIdx.x;
    const int ti = t >> 4;
    const int tj = t & 15;

    float acc[8][8] = {};
    for (int st = 0; st < (NN / ESPLIT) / 32; ++st) {
        const int k0 = kbase + st * 32;
        {
            const int ch  = t >> 1;
            const int k16 = (t & 1) * 16;
            const float* src = fb + (size_t)ch * N + k0 + k16;
            #pragma unroll
            for (int j = 0; j < 4; ++j)
                *reinterpret_cast<float4*>(&fs[ch][k16 + 4*j]) =
                    *reinterpret_cast<const float4*>(src + 4*j);
        }
        __syncthreads();
        #pragma unroll 4
        for (int k = 0; k < 32; ++k) {
            float av[8], bv[8];
            #pragma unroll
            for (int ii = 0; ii < 8; ++ii) av[ii] = fs[ti * 8 + ii][k];
            #pragma unroll
            for (int jj = 0; jj < 8; ++jj) bv[jj] = fs[tj * 8 + jj][k];
            #pragma unroll
            for (int ii = 0; ii < 8; ++ii)
                #pragma unroll
                for (int jj = 0; jj < 8; ++jj)
                    acc[ii][jj] += av[ii] * bv[jj];
        }
        __syncthreads();
    }
    float* dst = ep + ((size_t)(s * B + b)) * CI * CI;
    #pragma unroll
    for (int ii = 0; ii < 8; ++ii)
        #pragma unroll
        for (int jj = 0; jj < 8; ++jj)
            dst[(size_t)(ti * 8 + ii) * CI + tj * 8 + jj] = acc[ii][jj];
}

__global__ __launch_bounds__(256) void cam_energy_reduce(
    const float* __restrict__ ep, float* __restrict__ came)
{
    const size_t n = (size_t)B * CI * CI;
    size_t idx = (size_t)blockIdx.x * 256 + threadIdx.x;
    float s = 0.f;
    #pragma unroll
    for (int j = 0; j < ESPLIT; ++j) s += ep[j * n + idx];
    came[idx] = s;
}

// ---------------------------------------------------------------------------
// CAM softmax (unchanged): softmax(rowmax - e) == exp(rowmin - e)/sum.
// ---------------------------------------------------------------------------
__global__ __launch_bounds__(64) void cam_softmax(
    const float* __restrict__ e, float* __restrict__ attn)
{
    const int row = blockIdx.x;
    const float* er = e + (size_t)row * CI;
    const int t = threadIdx.x;
    float v0 = er[t], v1 = er[t + 64];
    float mn = fminf(v0, v1);
    #pragma unroll
    for (int off = 32; off; off >>= 1) mn = fminf(mn, __shfl_xor(mn, off));
    float p0 = __expf(mn - v0), p1 = __expf(mn - v1);
    float s = p0 + p1;
    #pragma unroll
    for (int off = 32; off; off >>= 1) s += __shfl_xor(s, off);
    float inv = 1.f / s;
    attn[(size_t)row * CI + t]      = p0 * inv;
    attn[(size_t)row * CI + t + 64] = p1 * inv;
}

// ---------------------------------------------------------------------------
extern "C" void kernel_launch(void* const* d_in, const int* in_sizes, int n_in,
                              void* d_out, int out_size, void* d_ws, size_t ws_size,
                              hipStream_t stream)
{
    const float* x    = (const float*)d_in[0];
    const float* Wa   = (const float*)d_in[1];
    const float* Wc   = (const float*)d_in[2];
    const float* Wq   = (const float*)d_in[3];
    const float* bq   = (const float*)d_in[4];
    const float* Wk   = (const float*)d_in[5];
    const float* bk   = (const float*)d_in[6];
    const float* Wv   = (const float*)d_in[7];
    const float* bv   = (const float*)d_in[8];
    const float* gpam = (const float*)d_in[9];
    const float* gcam = (const float*)d_in[10];
    const float* Wa1  = (const float*)d_in[11];
    const float* Wc1  = (const float*)d_in[12];
    const float* W1   = (const float*)d_in[13];
    const float* b1   = (const float*)d_in[14];
    const float* W2   = (const float*)d_in[15];
    const float* b2   = (const float*)d_in[16];
    const float* W3   = (const float*)d_in[17];
    const float* b3   = (const float*)d_in[18];
    float* out = (float*)d_out;

    // workspace layout (fp32 elements) — ~77 MB total
    const size_t PART = (size_t)B * CI * NN;   // 2,097,152
    float* ws    = (float*)d_ws;
    float* A     = ws;                 // [B,128,N]  (f1, later f2)
    float* Bv    = A  + PART;          // [B,128,N]  (v, later sa2/sc2)
    float* C     = Bv + PART;          // [B,128,N]  (sa, later sc)
    float* T     = C  + PART;          // [B,256,N] 4,194,304 (t1+t2 acc)
    float* Q     = T  + 2 * PART;      // [B,32,N]   524,288
    float* K2    = Q  + 524288;        // [B,32,N]   524,288
    float* came  = K2 + 524288;        // [B,128,128] 65,536
    float* cama  = came + 65536;       // [B,128,128] 65,536
    float* Ob    = cama + 65536;       // 2 x PART flash partials
    float* mpart = Ob + 2 * PART;      // [8][B][N]  131,072
    float* lpart = mpart + 131072;     // [8][B][N]  131,072
    float* epart = lpart + 131072;     // [16][B][128][128] 1,048,576
    float* X7    = epart + 1048576;    // 1 x PART flash partial

    // 8 flash partials in dead-at-flash-time buffers:
    Ptr8 op8;
    op8.p[0] = T;            op8.p[1] = T + PART;     // T dead until W1-conv
    op8.p[2] = Ob;           op8.p[3] = Ob + PART;    // dedicated
    op8.p[4] = C;                                     // merge output (safe: per-elem)
    op8.p[5] = out;          op8.p[6] = out + PART;   // d_out overwritten at end
    op8.p[7] = X7;

    const dim3 blk(256);
    auto grid_c = [](int Co) { return dim3(NN / 64, (Co + 63) / 64, B); };

    // ---- PAM branch ----
    conv_mfma<true><<<grid_c(CI), blk, 0, stream>>>(
        Wa, 0, x, A, nullptr, nullptr, nullptr, CI, CIN, NN);
    conv_mfma<false><<<grid_c(CQ), blk, 0, stream>>>(
        Wq, 0, A, Q, bq, nullptr, nullptr, CQ, CI, NN);
    conv_mfma<false><<<grid_c(CQ), blk, 0, stream>>>(
        Wk, 0, A, K2, bk, nullptr, nullptr, CQ, CI, NN);
    conv_mfma<false><<<grid_c(CI), blk, 0, stream>>>(
        Wv, 0, A, Bv, bv, nullptr, nullptr, CI, CI, NN);
    pam_flash_mfma<<<dim3(NN / 128, B, NSPLIT), blk, 0, stream>>>(
        Q, K2, Bv, op8, mpart, lpart, NN);
    pam_merge<<<dim3((B * CI * NN) / 256), blk, 0, stream>>>(
        op8, mpart, lpart, A, gpam, C);
    conv_mfma<true><<<grid_c(CI), blk, 0, stream>>>(
        Wa1, 0, C, Bv, nullptr, nullptr, nullptr, CI, CI, NN);
    conv_mfma<false><<<grid_c(COUT), blk, 0, stream>>>(
        W1, 0, Bv, T, b1, nullptr, nullptr, COUT, CI, NN);

    // ---- CAM branch ----
    conv_mfma<true><<<grid_c(CI), blk, 0, stream>>>(
        Wc, 0, x, A, nullptr, nullptr, nullptr, CI, CIN, NN);
    cam_energy_part<<<dim3(B, ESPLIT), blk, 0, stream>>>(A, epart, NN);
    cam_energy_reduce<<<dim3((B * CI * CI) / 256), blk, 0, stream>>>(epart, came);
    cam_softmax<<<dim3(B * CI), dim3(64), 0, stream>>>(came, cama);
    conv_mfma<false><<<grid_c(CI), blk, 0, stream>>>(
        cama, (long)CI * CI, A, C, nullptr, gcam, A, CI, CI, NN);
    conv_mfma<true><<<grid_c(CI), blk, 0, stream>>>(
        Wc1, 0, C, Bv, nullptr, nullptr, nullptr, CI, CI, NN);
    conv_mfma<false><<<grid_c(COUT), blk, 0, stream>>>(
        W2, 0, Bv, T, b2, nullptr, T, COUT, CI, NN);

    // ---- out = W3 @ T + b3 ----
    conv_mfma<false><<<grid_c(COUT), blk, 0, stream>>>(
        W3, 0, T, out, b3, nullptr, nullptr, COUT, COUT, NN);
}

// Round 11
// 316.914 us; speedup vs baseline: 3.9178x; 1.0323x over previous
//
#include <hip/hip_runtime.h>
#include <hip/hip_bf16.h>

// Problem constants (fixed by setup_inputs)
constexpr int B    = 4;
constexpr int CIN  = 512;
constexpr int NN   = 4096;
constexpr int CI   = 128;   // inter_channels
constexpr int CQ   = 32;    // PAM q/k dim
constexpr int COUT = 256;
constexpr int NSPLIT = 4;              // KV splits for pam flash
constexpr int KVLEN  = NN / NSPLIT;    // 1024 KV cols per split

typedef __bf16 bf16x8 __attribute__((ext_vector_type(8)));
typedef float  f32x4  __attribute__((ext_vector_type(4)));

struct Ptr4 { float* p[4]; };

// ---------------------------------------------------------------------------
// MFMA 1x1-conv GEMM, plain bf16 (unchanged from round 10; absmax 0.0469 ok).
// Block: 64 n x 64 co, 4 waves, BK=32. Grid: (N/64, ceil(Co/64), B).
// ---------------------------------------------------------------------------
template<bool RELU>
__global__ __launch_bounds__(256) void conv_mfma(
    const float* __restrict__ W, long wbs,
    const float* __restrict__ X,
    float* __restrict__ Y,
    const float* __restrict__ bias,
    const float* __restrict__ gamma_ptr,
    const float* __restrict__ resid,
    int Co, int K, int N)
{
    const int b   = blockIdx.z;
    const int n0  = blockIdx.x * 64;
    const int co0 = blockIdx.y * 64;
    const float* Wb = W + (size_t)b * wbs;
    const float* Xb = X + (size_t)b * K * N;

    __shared__ __bf16 Xs[64][40];   // [n][k] (transposed)
    __shared__ __bf16 Ws[64][40];   // [co][k]

    const int t    = threadIdx.x;
    const int w    = t >> 6;
    const int lane = t & 63;
    const int gq   = lane >> 4;   // 0..3
    const int c    = lane & 15;   // 0..15

    f32x4 acc[4];
    #pragma unroll
    for (int cb = 0; cb < 4; ++cb) acc[cb] = (f32x4){0.f, 0.f, 0.f, 0.f};

    for (int kb = 0; kb < K; kb += 32) {
        {
            const int k  = t >> 3;          // 0..31
            const int n8 = (t & 7) * 8;     // 0..56
            const float* src = Xb + (size_t)(kb + k) * N + n0 + n8;
            float4 f0 = *reinterpret_cast<const float4*>(src);
            float4 f1 = *reinterpret_cast<const float4*>(src + 4);
            float fv[8] = {f0.x, f0.y, f0.z, f0.w, f1.x, f1.y, f1.z, f1.w};
            #pragma unroll
            for (int j = 0; j < 8; ++j) Xs[n8 + j][k] = (__bf16)fv[j];
        }
        {
            const int co = t >> 2;          // 0..63
            const int kh = (t & 3) * 8;     // 0,8,16,24
            float fv[8];
            if (co0 + co < Co) {
                const float* src = Wb + (size_t)(co0 + co) * K + kb + kh;
                float4 f0 = *reinterpret_cast<const float4*>(src);
                float4 f1 = *reinterpret_cast<const float4*>(src + 4);
                fv[0]=f0.x; fv[1]=f0.y; fv[2]=f0.z; fv[3]=f0.w;
                fv[4]=f1.x; fv[5]=f1.y; fv[6]=f1.z; fv[7]=f1.w;
            } else {
                #pragma unroll
                for (int j = 0; j < 8; ++j) fv[j] = 0.f;
            }
            bf16x8 u;
            #pragma unroll
            for (int j = 0; j < 8; ++j) u[j] = (__bf16)fv[j];
            *reinterpret_cast<bf16x8*>(&Ws[co][kh]) = u;
        }
        __syncthreads();

        bf16x8 xa = *reinterpret_cast<const bf16x8*>(&Xs[16*w + c][gq * 8]);
        #pragma unroll
        for (int cb = 0; cb < 4; ++cb) {
            bf16x8 wf = *reinterpret_cast<const bf16x8*>(&Ws[16*cb + c][gq * 8]);
            acc[cb] = __builtin_amdgcn_mfma_f32_16x16x32_bf16(xa, wf, acc[cb], 0, 0, 0);
        }
        __syncthreads();
    }

    const float g = gamma_ptr ? *gamma_ptr : 1.f;
    const int nb = n0 + 16 * w + 4 * gq;
    #pragma unroll
    for (int cb = 0; cb < 4; ++cb) {
        int co = co0 + 16 * cb + c;
        if (co >= Co) continue;
        float bv = bias ? bias[co] : 0.f;
        size_t base = (size_t)(b * Co + co) * N + nb;
        float4 o;
        float* op = &o.x;
        #pragma unroll
        for (int r = 0; r < 4; ++r) {
            float val = acc[cb][r] + bv;
            if (RELU) val = fmaxf(val, 0.f);
            val *= g;
            op[r] = val;
        }
        if (resid) {
            float4 rv = *reinterpret_cast<const float4*>(&resid[base]);
            o.x += rv.x; o.y += rv.y; o.z += rv.z; o.w += rv.w;
        }
        *reinterpret_cast<float4*>(&Y[base]) = o;
    }
}

// ---------------------------------------------------------------------------
// PAM flash attention partial, MFMA bf16, KV-tile = 64 (softmax amortized
// over 2x columns vs round 9/10). NSPLIT=4. Block 256 thr / 4 waves,
// 128 Q-rows. Grid: (NN/128, B, NSPLIT).
// Per 64-col tile: 8 QK^T MFMAs + 1 softmax pass (8 rows x 8 shfl) +
// 32 PV MFMAs + 2 barriers.   LDS ~42 KB.
// ---------------------------------------------------------------------------
__global__ __launch_bounds__(256) void pam_flash_mfma(
    const float* __restrict__ q, const float* __restrict__ k,
    const float* __restrict__ v,
    Ptr4 op4,
    float* __restrict__ mp, float* __restrict__ lp, int N)
{
    const int b  = blockIdx.y;
    const int s  = blockIdx.z;
    const int n0 = blockIdx.x * 128;
    const float* qb = q + (size_t)b * CQ * N;
    const float* kb = k + (size_t)b * CQ * N;
    const float* vb = v + (size_t)b * CI * N;
    float* Op = op4.p[s];

    __shared__ __bf16 Klds[64][40];    // [m][ck]  (K^T), 5 KB
    __shared__ __bf16 Vlds[128][72];   // [vc][m],  18.4 KB
    __shared__ __bf16 QP[128][72];     // Q^T staging [n][ck]; then per-wave P [row][m]

    const int t    = threadIdx.x;
    const int w    = t >> 6;
    const int lane = t & 63;
    const int g    = lane >> 4;   // 0..3
    const int c    = lane & 15;   // 0..15

    // ---- stage Q^T once: QP[n][cq] = q[cq][n0+n]
    {
        const int cq = t >> 3;           // 0..31
        const int nb = (t & 7) * 16;     // 0..112
        const float* src = qb + (size_t)cq * N + n0 + nb;
        #pragma unroll
        for (int j = 0; j < 4; ++j) {
            float4 f = *reinterpret_cast<const float4*>(src + 4 * j);
            QP[nb + 4*j + 0][cq] = (__bf16)f.x;
            QP[nb + 4*j + 1][cq] = (__bf16)f.y;
            QP[nb + 4*j + 2][cq] = (__bf16)f.z;
            QP[nb + 4*j + 3][cq] = (__bf16)f.w;
        }
    }
    __syncthreads();
    bf16x8 qa[2];
    #pragma unroll
    for (int rb = 0; rb < 2; ++rb)
        qa[rb] = *reinterpret_cast<const bf16x8*>(&QP[32*w + 16*rb + c][g * 8]);
    __syncthreads();   // QP recycled as per-wave P buffer [row][m<64]

    f32x4 acc[2][8];
    #pragma unroll
    for (int rb = 0; rb < 2; ++rb)
        #pragma unroll
        for (int vbk = 0; vbk < 8; ++vbk)
            acc[rb][vbk] = (f32x4){0.f, 0.f, 0.f, 0.f};
    float ms[2][4], ls[2][4];
    #pragma unroll
    for (int rb = 0; rb < 2; ++rb)
        #pragma unroll
        for (int r = 0; r < 4; ++r) { ms[rb][r] = -1e30f; ls[rb][r] = 0.f; }

    const int mstart = s * KVLEN;
    for (int mt = 0; mt < KVLEN / 64; ++mt) {
        const int m0 = mstart + mt * 64;
        // ---- stage K^T tile: Klds[m][ck] for 64 m
        {
            const int ck = t >> 3;        // 0..31
            const int m8 = (t & 7) * 8;   // 0..56
            const float* src = kb + (size_t)ck * N + m0 + m8;
            float4 f0 = *reinterpret_cast<const float4*>(src);
            float4 f1 = *reinterpret_cast<const float4*>(src + 4);
            float fk[8] = {f0.x, f0.y, f0.z, f0.w, f1.x, f1.y, f1.z, f1.w};
            #pragma unroll
            for (int j = 0; j < 8; ++j) Klds[m8 + j][ck] = (__bf16)fk[j];
        }
        // ---- stage V tile: Vlds[cv][m] for 64 m (vector stores)
        {
            const int cv = t >> 1;        // 0..127
            const int mh = (t & 1) * 32;
            const float* src = vb + (size_t)cv * N + m0 + mh;
            #pragma unroll
            for (int j = 0; j < 4; ++j) {
                float4 f0 = *reinterpret_cast<const float4*>(src + 8 * j);
                float4 f1 = *reinterpret_cast<const float4*>(src + 8 * j + 4);
                bf16x8 u;
                u[0]=(__bf16)f0.x; u[1]=(__bf16)f0.y; u[2]=(__bf16)f0.z; u[3]=(__bf16)f0.w;
                u[4]=(__bf16)f1.x; u[5]=(__bf16)f1.y; u[6]=(__bf16)f1.z; u[7]=(__bf16)f1.w;
                *reinterpret_cast<bf16x8*>(&Vlds[cv][mh + 8 * j]) = u;
            }
        }
        __syncthreads();

        // ---- QK^T: S[32 qrow x 64 m] per wave = 8 MFMAs
        f32x4 sv[2][4];
        #pragma unroll
        for (int cb = 0; cb < 4; ++cb) {
            bf16x8 kf = *reinterpret_cast<const bf16x8*>(&Klds[16*cb + c][g * 8]);
            #pragma unroll
            for (int rb = 0; rb < 2; ++rb)
                sv[rb][cb] = __builtin_amdgcn_mfma_f32_16x16x32_bf16(
                    qa[rb], kf, (f32x4){0.f, 0.f, 0.f, 0.f}, 0, 0, 0);
        }

        // ---- online softmax over 64 cols (one pass)
        float scale[2][4];
        bool need = false;
        #pragma unroll
        for (int rb = 0; rb < 2; ++rb) {
            #pragma unroll
            for (int r = 0; r < 4; ++r) {
                float mx = fmaxf(fmaxf(sv[rb][0][r], sv[rb][1][r]),
                                 fmaxf(sv[rb][2][r], sv[rb][3][r]));
                #pragma unroll
                for (int off = 1; off < 16; off <<= 1)
                    mx = fmaxf(mx, __shfl_xor(mx, off));
                float mnew = fmaxf(ms[rb][r], mx);
                scale[rb][r] = __expf(ms[rb][r] - mnew);
                ms[rb][r] = mnew;
                float psum = 0.f;
                #pragma unroll
                for (int cb = 0; cb < 4; ++cb) {
                    float p = __expf(sv[rb][cb][r] - mnew);
                    sv[rb][cb][r] = p;
                    psum += p;
                }
                #pragma unroll
                for (int off = 1; off < 16; off <<= 1)
                    psum += __shfl_xor(psum, off);
                ls[rb][r] = ls[rb][r] * scale[rb][r] + psum;
                need |= (scale[rb][r] != 1.0f);
            }
        }

        // ---- P -> LDS (own wave's 32-row slice; cols 0..63)
        #pragma unroll
        for (int rb = 0; rb < 2; ++rb)
            #pragma unroll
            for (int cb = 0; cb < 4; ++cb)
                #pragma unroll
                for (int r = 0; r < 4; ++r)
                    QP[32*w + 16*rb + 4*g + r][16*cb + c] = (__bf16)sv[rb][cb][r];

        // ---- rescale acc (exact skip when all scales == 1)
        if (__any(need)) {
            #pragma unroll
            for (int rb = 0; rb < 2; ++rb)
                #pragma unroll
                for (int vbk = 0; vbk < 8; ++vbk)
                    #pragma unroll
                    for (int r = 0; r < 4; ++r)
                        acc[rb][vbk][r] *= scale[rb][r];
        }

        // ---- PV over 64 m: 2 k-steps x 16 MFMAs
        #pragma unroll
        for (int ks = 0; ks < 2; ++ks) {
            bf16x8 pa[2];
            #pragma unroll
            for (int rb = 0; rb < 2; ++rb)
                pa[rb] = *reinterpret_cast<const bf16x8*>(
                    &QP[32*w + 16*rb + c][ks * 32 + g * 8]);
            #pragma unroll
            for (int vbk = 0; vbk < 8; ++vbk) {
                bf16x8 vf = *reinterpret_cast<const bf16x8*>(
                    &Vlds[16*vbk + c][ks * 32 + g * 8]);
                #pragma unroll
                for (int rb = 0; rb < 2; ++rb)
                    acc[rb][vbk] = __builtin_amdgcn_mfma_f32_16x16x32_bf16(
                        pa[rb], vf, acc[rb][vbk], 0, 0, 0);
            }
        }
        __syncthreads();
    }

    // ---- epilogue: unnormalized partial O + per-row (m,l)
    #pragma unroll
    for (int rb = 0; rb < 2; ++rb)
        #pragma unroll
        for (int vbk = 0; vbk < 8; ++vbk) {
            float4 o = { acc[rb][vbk][0], acc[rb][vbk][1],
                         acc[rb][vbk][2], acc[rb][vbk][3] };
            *reinterpret_cast<float4*>(
                &Op[((size_t)(b * CI + 16*vbk + c)) * N + n0 + 32*w + 16*rb + 4*g]) = o;
        }
    if (c == 0) {
        #pragma unroll
        for (int rb = 0; rb < 2; ++rb)
            #pragma unroll
            for (int r = 0; r < 4; ++r) {
                int n = n0 + 32*w + 16*rb + 4*g + r;
                mp[(size_t)(s * B + b) * N + n] = ms[rb][r];
                lp[(size_t)(s * B + b) * N + n] = ls[rb][r];
            }
    }
}

// ---------------------------------------------------------------------------
// Merge NSPLIT=4 flash partials.
// ---------------------------------------------------------------------------
__global__ __launch_bounds__(256) void pam_merge(
    Ptr4 op4,
    const float* __restrict__ mp, const float* __restrict__ lp,
    const float* __restrict__ f1, const float* __restrict__ gamma_ptr,
    float* __restrict__ sa)
{
    size_t idx = (size_t)blockIdx.x * 256 + threadIdx.x;   // over B*CI*NN
    const int n = (int)(idx & (NN - 1));
    const int b = (int)(idx >> 19);                        // CI*NN = 2^19

    float m[NSPLIT], l[NSPLIT];
    float M = -1e30f;
    #pragma unroll
    for (int s = 0; s < NSPLIT; ++s) {
        m[s] = mp[(size_t)(s * B + b) * NN + n];
        l[s] = lp[(size_t)(s * B + b) * NN + n];
        M = fmaxf(M, m[s]);
    }
    float L = 0.f, O = 0.f;
    #pragma unroll
    for (int s = 0; s < NSPLIT; ++s) {
        float ws = __expf(m[s] - M);
        L += l[s] * ws;
        O += op4.p[s][idx] * ws;
    }
    sa[idx] = (*gamma_ptr) * (O / L) + f1[idx];
}

// ---------------------------------------------------------------------------
// CAM energy, K-split partials (unchanged).
// ---------------------------------------------------------------------------
constexpr int ESPLIT = 16;
__global__ __launch_bounds__(256) void cam_energy_part(
    const float* __restrict__ f2, float* __restrict__ ep, int N)
{
    const int b = blockIdx.x;
    const int s = blockIdx.y;
    const float* fb = f2 + (size_t)b * CI * N;
    const int kbase = s * (NN / ESPLIT);

    __shared__ float fs[128][33];
    const int t  = threadIdx.x;
    const int ti = t >> 4;
    const int tj = t & 15;

    float acc[8][8] = {};
    for (int st = 0; st < (NN / ESPLIT) / 32; ++st) {
        const int k0 = kbase + st * 32;
        {
            const int ch  = t >> 1;
            const int k16 = (t & 1) * 16;
            const float* src = fb + (size_t)ch * N + k0 + k16;
            #pragma unroll
            for (int j = 0; j < 4; ++j)
                *reinterpret_cast<float4*>(&fs[ch][k16 + 4*j]) =
                    *reinterpret_cast<const float4*>(src + 4*j);
        }
        __syncthreads();
        #pragma unroll 4
        for (int k = 0; k < 32; ++k) {
            float av[8], bv[8];
            #pragma unroll
            for (int ii = 0; ii < 8; ++ii) av[ii] = fs[ti * 8 + ii][k];
            #pragma unroll
            for (int jj = 0; jj < 8; ++jj) bv[jj] = fs[tj * 8 + jj][k];
            #pragma unroll
            for (int ii = 0; ii < 8; ++ii)
                #pragma unroll
                for (int jj = 0; jj < 8; ++jj)
                    acc[ii][jj] += av[ii] * bv[jj];
        }
        __syncthreads();
    }
    float* dst = ep + ((size_t)(s * B + b)) * CI * CI;
    #pragma unroll
    for (int ii = 0; ii < 8; ++ii)
        #pragma unroll
        for (int jj = 0; jj < 8; ++jj)
            dst[(size_t)(ti * 8 + ii) * CI + tj * 8 + jj] = acc[ii][jj];
}

__global__ __launch_bounds__(256) void cam_energy_reduce(
    const float* __restrict__ ep, float* __restrict__ came)
{
    const size_t n = (size_t)B * CI * CI;
    size_t idx = (size_t)blockIdx.x * 256 + threadIdx.x;
    float s = 0.f;
    #pragma unroll
    for (int j = 0; j < ESPLIT; ++j) s += ep[j * n + idx];
    came[idx] = s;
}

// ---------------------------------------------------------------------------
// CAM softmax (unchanged): softmax(rowmax - e) == exp(rowmin - e)/sum.
// ---------------------------------------------------------------------------
__global__ __launch_bounds__(64) void cam_softmax(
    const float* __restrict__ e, float* __restrict__ attn)
{
    const int row = blockIdx.x;
    const float* er = e + (size_t)row * CI;
    const int t = threadIdx.x;
    float v0 = er[t], v1 = er[t + 64];
    float mn = fminf(v0, v1);
    #pragma unroll
    for (int off = 32; off; off >>= 1) mn = fminf(mn, __shfl_xor(mn, off));
    float p0 = __expf(mn - v0), p1 = __expf(mn - v1);
    float s = p0 + p1;
    #pragma unroll
    for (int off = 32; off; off >>= 1) s += __shfl_xor(s, off);
    float inv = 1.f / s;
    attn[(size_t)row * CI + t]      = p0 * inv;
    attn[(size_t)row * CI + t + 64] = p1 * inv;
}

// ---------------------------------------------------------------------------
extern "C" void kernel_launch(void* const* d_in, const int* in_sizes, int n_in,
                              void* d_out, int out_size, void* d_ws, size_t ws_size,
                              hipStream_t stream)
{
    const float* x    = (const float*)d_in[0];
    const float* Wa   = (const float*)d_in[1];
    const float* Wc   = (const float*)d_in[2];
    const float* Wq   = (const float*)d_in[3];
    const float* bq   = (const float*)d_in[4];
    const float* Wk   = (const float*)d_in[5];
    const float* bk   = (const float*)d_in[6];
    const float* Wv   = (const float*)d_in[7];
    const float* bv   = (const float*)d_in[8];
    const float* gpam = (const float*)d_in[9];
    const float* gcam = (const float*)d_in[10];
    const float* Wa1  = (const float*)d_in[11];
    const float* Wc1  = (const float*)d_in[12];
    const float* W1   = (const float*)d_in[13];
    const float* b1   = (const float*)d_in[14];
    const float* W2   = (const float*)d_in[15];
    const float* b2   = (const float*)d_in[16];
    const float* W3   = (const float*)d_in[17];
    const float* b3   = (const float*)d_in[18];
    float* out = (float*)d_out;

    // workspace layout (fp32 elements) — ~68 MB total
    const size_t PART = (size_t)B * CI * NN;   // 2,097,152
    float* ws    = (float*)d_ws;
    float* A     = ws;                 // [B,128,N]  (f1, later f2)
    float* Bv    = A  + PART;          // [B,128,N]  (v, later sa2/sc2)
    float* C     = Bv + PART;          // [B,128,N]  (sa, later sc)
    float* T     = C  + PART;          // [B,256,N] (t1+t2 acc; flash partials 0,1)
    float* Q     = T  + 2 * PART;      // [B,32,N]   524,288
    float* K2    = Q  + 524288;        // [B,32,N]   524,288
    float* came  = K2 + 524288;        // [B,128,128] 65,536
    float* cama  = came + 65536;       // [B,128,128] 65,536
    float* Ob    = cama + 65536;       // 2 x PART flash partials 2,3
    float* mpart = Ob + 2 * PART;      // [4][B][N]  65,536
    float* lpart = mpart + 65536;      // [4][B][N]  65,536
    float* epart = lpart + 65536;      // [16][B][128][128] 1,048,576

    Ptr4 op4;
    op4.p[0] = T;   op4.p[1] = T + PART;    // T dead until W1-conv
    op4.p[2] = Ob;  op4.p[3] = Ob + PART;   // dedicated

    const dim3 blk(256);
    auto grid_c = [](int Co) { return dim3(NN / 64, (Co + 63) / 64, B); };

    // ---- PAM branch ----
    conv_mfma<true><<<grid_c(CI), blk, 0, stream>>>(
        Wa, 0, x, A, nullptr, nullptr, nullptr, CI, CIN, NN);
    conv_mfma<false><<<grid_c(CQ), blk, 0, stream>>>(
        Wq, 0, A, Q, bq, nullptr, nullptr, CQ, CI, NN);
    conv_mfma<false><<<grid_c(CQ), blk, 0, stream>>>(
        Wk, 0, A, K2, bk, nullptr, nullptr, CQ, CI, NN);
    conv_mfma<false><<<grid_c(CI), blk, 0, stream>>>(
        Wv, 0, A, Bv, bv, nullptr, nullptr, CI, CI, NN);
    pam_flash_mfma<<<dim3(NN / 128, B, NSPLIT), blk, 0, stream>>>(
        Q, K2, Bv, op4, mpart, lpart, NN);
    pam_merge<<<dim3((B * CI * NN) / 256), blk, 0, stream>>>(
        op4, mpart, lpart, A, gpam, C);
    conv_mfma<true><<<grid_c(CI), blk, 0, stream>>>(
        Wa1, 0, C, Bv, nullptr, nullptr, nullptr, CI, CI, NN);
    conv_mfma<false><<<grid_c(COUT), blk, 0, stream>>>(
        W1, 0, Bv, T, b1, nullptr, nullptr, COUT, CI, NN);

    // ---- CAM branch ----
    conv_mfma<true><<<grid_c(CI), blk, 0, stream>>>(
        Wc, 0, x, A, nullptr, nullptr, nullptr, CI, CIN, NN);
    cam_energy_part<<<dim3(B, ESPLIT), blk, 0, stream>>>(A, epart, NN);
    cam_energy_reduce<<<dim3((B * CI * CI) / 256), blk, 0, stream>>>(epart, came);
    cam_softmax<<<dim3(B * CI), dim3(64), 0, stream>>>(came, cama);
    conv_mfma<false><<<grid_c(CI), blk, 0, stream>>>(
        cama, (long)CI * CI, A, C, nullptr, gcam, A, CI, CI, NN);
    conv_mfma<true><<<grid_c(CI), blk, 0, stream>>>(
        Wc1, 0, C, Bv, nullptr, nullptr, nullptr, CI, CI, NN);
    conv_mfma<false><<<grid_c(COUT), blk, 0, stream>>>(
        W2, 0, Bv, T, b2, nullptr, T, COUT, CI, NN);

    // ---- out = W3 @ T + b3 ----
    conv_mfma<false><<<grid_c(COUT), blk, 0, stream>>>(
        W3, 0, T, out, b3, nullptr, nullptr, COUT, COUT, NN);
}

// Round 13
// 252.313 us; speedup vs baseline: 4.9209x; 1.2560x over previous
//
#include <hip/hip_runtime.h>
#include <hip/hip_bf16.h>

// Problem constants (fixed by setup_inputs)
constexpr int B    = 4;
constexpr int CIN  = 512;
constexpr int NN   = 4096;
constexpr int CI   = 128;   // inter_channels
constexpr int CQ   = 32;    // PAM q/k dim
constexpr int COUT = 256;
constexpr int NSPLIT = 4;              // KV splits for pam flash
constexpr int KVLEN  = NN / NSPLIT;    // 1024 KV cols per split

typedef __bf16 bf16x8 __attribute__((ext_vector_type(8)));
typedef float  f32x4  __attribute__((ext_vector_type(4)));

struct Ptr4 { float* p[4]; };

// ---------------------------------------------------------------------------
// MFMA 1x1-conv GEMM, plain bf16 (unchanged from rounds 10/11; absmax 0.0469).
// Block: 64 n x 64 co, 4 waves, BK=32. Grid: (N/64, ceil(Co/64), B).
// ---------------------------------------------------------------------------
template<bool RELU>
__global__ __launch_bounds__(256) void conv_mfma(
    const float* __restrict__ W, long wbs,
    const float* __restrict__ X,
    float* __restrict__ Y,
    const float* __restrict__ bias,
    const float* __restrict__ gamma_ptr,
    const float* __restrict__ resid,
    int Co, int K, int N)
{
    const int b   = blockIdx.z;
    const int n0  = blockIdx.x * 64;
    const int co0 = blockIdx.y * 64;
    const float* Wb = W + (size_t)b * wbs;
    const float* Xb = X + (size_t)b * K * N;

    __shared__ __bf16 Xs[64][40];   // [n][k] (transposed)
    __shared__ __bf16 Ws[64][40];   // [co][k]

    const int t    = threadIdx.x;
    const int w    = t >> 6;
    const int lane = t & 63;
    const int gq   = lane >> 4;   // 0..3
    const int c    = lane & 15;   // 0..15

    f32x4 acc[4];
    #pragma unroll
    for (int cb = 0; cb < 4; ++cb) acc[cb] = (f32x4){0.f, 0.f, 0.f, 0.f};

    for (int kb = 0; kb < K; kb += 32) {
        {
            const int k  = t >> 3;          // 0..31
            const int n8 = (t & 7) * 8;     // 0..56
            const float* src = Xb + (size_t)(kb + k) * N + n0 + n8;
            float4 f0 = *reinterpret_cast<const float4*>(src);
            float4 f1 = *reinterpret_cast<const float4*>(src + 4);
            float fv[8] = {f0.x, f0.y, f0.z, f0.w, f1.x, f1.y, f1.z, f1.w};
            #pragma unroll
            for (int j = 0; j < 8; ++j) Xs[n8 + j][k] = (__bf16)fv[j];
        }
        {
            const int co = t >> 2;          // 0..63
            const int kh = (t & 3) * 8;     // 0,8,16,24
            float fv[8];
            if (co0 + co < Co) {
                const float* src = Wb + (size_t)(co0 + co) * K + kb + kh;
                float4 f0 = *reinterpret_cast<const float4*>(src);
                float4 f1 = *reinterpret_cast<const float4*>(src + 4);
                fv[0]=f0.x; fv[1]=f0.y; fv[2]=f0.z; fv[3]=f0.w;
                fv[4]=f1.x; fv[5]=f1.y; fv[6]=f1.z; fv[7]=f1.w;
            } else {
                #pragma unroll
                for (int j = 0; j < 8; ++j) fv[j] = 0.f;
            }
            bf16x8 u;
            #pragma unroll
            for (int j = 0; j < 8; ++j) u[j] = (__bf16)fv[j];
            *reinterpret_cast<bf16x8*>(&Ws[co][kh]) = u;
        }
        __syncthreads();

        bf16x8 xa = *reinterpret_cast<const bf16x8*>(&Xs[16*w + c][gq * 8]);
        #pragma unroll
        for (int cb = 0; cb < 4; ++cb) {
            bf16x8 wf = *reinterpret_cast<const bf16x8*>(&Ws[16*cb + c][gq * 8]);
            acc[cb] = __builtin_amdgcn_mfma_f32_16x16x32_bf16(xa, wf, acc[cb], 0, 0, 0);
        }
        __syncthreads();
    }

    const float g = gamma_ptr ? *gamma_ptr : 1.f;
    const int nb = n0 + 16 * w + 4 * gq;
    #pragma unroll
    for (int cb = 0; cb < 4; ++cb) {
        int co = co0 + 16 * cb + c;
        if (co >= Co) continue;
        float bv = bias ? bias[co] : 0.f;
        size_t base = (size_t)(b * Co + co) * N + nb;
        float4 o;
        float* op = &o.x;
        #pragma unroll
        for (int r = 0; r < 4; ++r) {
            float val = acc[cb][r] + bv;
            if (RELU) val = fmaxf(val, 0.f);
            val *= g;
            op[r] = val;
        }
        if (resid) {
            float4 rv = *reinterpret_cast<const float4*>(&resid[base]);
            o.x += rv.x; o.y += rv.y; o.z += rv.z; o.w += rv.w;
        }
        *reinterpret_cast<float4*>(&Y[base]) = o;
    }
}

// ---------------------------------------------------------------------------
// PAM flash attention partial, MFMA bf16, SWAPPED QK^T softmax.
// R9 geometry: KV-tile 32, NSPLIT=4, LDS 23 KB, 4 waves, 128 Q-rows/block.
// QK^T computed as S^T = mfma(K-frag, Q-frag): lane (g,c) holds
// S[m = 16*mb + 4g + r][q = 32w + 16*qb + c] -> softmax over m is
// 7 in-lane fmax + 2 shfl_xor (off 16,32) per qb, vs 64 shfls in the
// un-swapped layout. P written to LDS [q][m] (what PV's A-frag reads).
// Acc rescale fetches per-row scale via 8 dynamic shfls, only when needed.
// ---------------------------------------------------------------------------
__global__ __launch_bounds__(256) void pam_flash_mfma(
    const float* __restrict__ q, const float* __restrict__ k,
    const float* __restrict__ v,
    Ptr4 op4,
    float* __restrict__ mp, float* __restrict__ lp, int N)
{
    const int b  = blockIdx.y;
    const int s  = blockIdx.z;
    const int n0 = blockIdx.x * 128;
    const float* qb_ = q + (size_t)b * CQ * N;
    const float* kb_ = k + (size_t)b * CQ * N;
    const float* vb_ = v + (size_t)b * CI * N;
    float* Op = op4.p[s];

    __shared__ __bf16 Klds[32][40];    // [m][ck]  (K^T, A-operand row-major)
    __shared__ __bf16 Vlds[128][40];   // [vc][m]  (B-operand col-major)
    __shared__ __bf16 QP[128][40];     // Q^T staging [n][cq]; then P [q][m]

    const int t    = threadIdx.x;
    const int w    = t >> 6;
    const int lane = t & 63;
    const int g    = lane >> 4;   // 0..3
    const int c    = lane & 15;   // 0..15

    // ---- stage Q^T once: QP[n][cq] = q[cq][n0+n]
    {
        const int cq = t >> 3;           // 0..31
        const int nb = (t & 7) * 16;     // 0..112
        const float* src = qb_ + (size_t)cq * N + n0 + nb;
        #pragma unroll
        for (int j = 0; j < 4; ++j) {
            float4 f = *reinterpret_cast<const float4*>(src + 4 * j);
            QP[nb + 4*j + 0][cq] = (__bf16)f.x;
            QP[nb + 4*j + 1][cq] = (__bf16)f.y;
            QP[nb + 4*j + 2][cq] = (__bf16)f.z;
            QP[nb + 4*j + 3][cq] = (__bf16)f.w;
        }
    }
    __syncthreads();
    // Q fragments (used as MFMA *B* operand: col=q, k=cq) — same bytes as A-read
    bf16x8 qa[2];
    #pragma unroll
    for (int qb = 0; qb < 2; ++qb)
        qa[qb] = *reinterpret_cast<const bf16x8*>(&QP[32*w + 16*qb + c][g * 8]);
    __syncthreads();   // QP recycled as per-wave P buffer [q][m]

    f32x4 acc[2][8];
    #pragma unroll
    for (int qb = 0; qb < 2; ++qb)
        #pragma unroll
        for (int vbk = 0; vbk < 8; ++vbk)
            acc[qb][vbk] = (f32x4){0.f, 0.f, 0.f, 0.f};
    // per-lane softmax state for q = 32w + 16qb + c (identical across g)
    float ms[2], ls[2];
    ms[0] = ms[1] = -1e30f; ls[0] = ls[1] = 0.f;

    const int mstart = s * KVLEN;
    for (int mt = 0; mt < KVLEN / 32; ++mt) {
        const int m0 = mstart + mt * 32;
        // ---- stage K^T tile: Klds[m][ck]
        {
            const int ck = t >> 3;        // 0..31
            const int m4 = (t & 7) * 4;
            float4 f = *reinterpret_cast<const float4*>(kb_ + (size_t)ck * N + m0 + m4);
            Klds[m4 + 0][ck] = (__bf16)f.x;
            Klds[m4 + 1][ck] = (__bf16)f.y;
            Klds[m4 + 2][ck] = (__bf16)f.z;
            Klds[m4 + 3][ck] = (__bf16)f.w;
        }
        // ---- stage V tile: Vlds[cv][m]
        {
            const int cv = t >> 1;        // 0..127
            const int mh = (t & 1) * 16;
            const float* src = vb_ + (size_t)cv * N + m0 + mh;
            #pragma unroll
            for (int j = 0; j < 2; ++j) {
                float4 f0 = *reinterpret_cast<const float4*>(src + 8 * j);
                float4 f1 = *reinterpret_cast<const float4*>(src + 8 * j + 4);
                bf16x8 u;
                u[0]=(__bf16)f0.x; u[1]=(__bf16)f0.y; u[2]=(__bf16)f0.z; u[3]=(__bf16)f0.w;
                u[4]=(__bf16)f1.x; u[5]=(__bf16)f1.y; u[6]=(__bf16)f1.z; u[7]=(__bf16)f1.w;
                *reinterpret_cast<bf16x8*>(&Vlds[cv][mh + 8 * j]) = u;
            }
        }
        __syncthreads();

        // ---- swapped QK^T: S^T[32m x 32q] per wave = 4 MFMAs
        // sv[mb][qb][r] = S[m = m0 + 16mb + 4g + r][q = n0 + 32w + 16qb + c]
        f32x4 sv[2][2];
        #pragma unroll
        for (int mb = 0; mb < 2; ++mb) {
            bf16x8 kf = *reinterpret_cast<const bf16x8*>(&Klds[16*mb + c][g * 8]);
            #pragma unroll
            for (int qb = 0; qb < 2; ++qb)
                sv[mb][qb] = __builtin_amdgcn_mfma_f32_16x16x32_bf16(
                    kf, qa[qb], (f32x4){0.f, 0.f, 0.f, 0.f}, 0, 0, 0);
        }

        // ---- online softmax over m (per q-column, lane-local + 2 shfls)
        float scale[2];
        bool need = false;
        #pragma unroll
        for (int qb = 0; qb < 2; ++qb) {
            float mx = sv[0][qb][0];
            #pragma unroll
            for (int r = 1; r < 4; ++r) mx = fmaxf(mx, sv[0][qb][r]);
            #pragma unroll
            for (int r = 0; r < 4; ++r) mx = fmaxf(mx, sv[1][qb][r]);
            mx = fmaxf(mx, __shfl_xor(mx, 16));
            mx = fmaxf(mx, __shfl_xor(mx, 32));
            float mnew = fmaxf(ms[qb], mx);
            scale[qb] = __expf(ms[qb] - mnew);
            ms[qb] = mnew;
            float psum = 0.f;
            #pragma unroll
            for (int mb = 0; mb < 2; ++mb)
                #pragma unroll
                for (int r = 0; r < 4; ++r) {
                    float p = __expf(sv[mb][qb][r] - mnew);
                    sv[mb][qb][r] = p;
                    psum += p;
                }
            psum += __shfl_xor(psum, 16);
            psum += __shfl_xor(psum, 32);
            ls[qb] = ls[qb] * scale[qb] + psum;
            need |= (scale[qb] != 1.0f);
        }

        // ---- P -> LDS in [q][m] layout (what PV's A-frag reads)
        #pragma unroll
        for (int qb = 0; qb < 2; ++qb)
            #pragma unroll
            for (int mb = 0; mb < 2; ++mb)
                #pragma unroll
                for (int r = 0; r < 4; ++r)
                    QP[32*w + 16*qb + c][16*mb + 4*g + r] = (__bf16)sv[mb][qb][r];

        // ---- rescale acc (acc rows are q = 16qb + 4g + r; scale lives at
        //      q = 16qb + c -> fetch from lane 4g+r, identical across groups)
        if (__any(need)) {
            #pragma unroll
            for (int qb = 0; qb < 2; ++qb) {
                float sc[4];
                #pragma unroll
                for (int r = 0; r < 4; ++r)
                    sc[r] = __shfl(scale[qb], 4*g + r, 64);
                #pragma unroll
                for (int vbk = 0; vbk < 8; ++vbk)
                    #pragma unroll
                    for (int r = 0; r < 4; ++r)
                        acc[qb][vbk][r] *= sc[r];
            }
        }

        // ---- PV: 16 MFMAs per wave (unchanged structure)
        bf16x8 pa[2];
        #pragma unroll
        for (int qb = 0; qb < 2; ++qb)
            pa[qb] = *reinterpret_cast<const bf16x8*>(&QP[32*w + 16*qb + c][g * 8]);
        #pragma unroll
        for (int vbk = 0; vbk < 8; ++vbk) {
            bf16x8 vf = *reinterpret_cast<const bf16x8*>(&Vlds[16*vbk + c][g * 8]);
            #pragma unroll
            for (int qb = 0; qb < 2; ++qb)
                acc[qb][vbk] = __builtin_amdgcn_mfma_f32_16x16x32_bf16(
                    pa[qb], vf, acc[qb][vbk], 0, 0, 0);
        }
        __syncthreads();
    }

    // ---- epilogue: unnormalized partial O + per-row (m,l)
    #pragma unroll
    for (int qb = 0; qb < 2; ++qb)
        #pragma unroll
        for (int vbk = 0; vbk < 8; ++vbk) {
            float4 o = { acc[qb][vbk][0], acc[qb][vbk][1],
                         acc[qb][vbk][2], acc[qb][vbk][3] };
            *reinterpret_cast<float4*>(
                &Op[((size_t)(b * CI + 16*vbk + c)) * N + n0 + 32*w + 16*qb + 4*g]) = o;
        }
    if (g == 0) {   // lanes 0..15 hold state for q = 32w + 16qb + c
        #pragma unroll
        for (int qb = 0; qb < 2; ++qb) {
            int n = n0 + 32*w + 16*qb + c;
            mp[(size_t)(s * B + b) * N + n] = ms[qb];
            lp[(size_t)(s * B + b) * N + n] = ls[qb];
        }
    }
}

// ---------------------------------------------------------------------------
// Merge NSPLIT=4 flash partials (unchanged).
// ---------------------------------------------------------------------------
__global__ __launch_bounds__(256) void pam_merge(
    Ptr4 op4,
    const float* __restrict__ mp, const float* __restrict__ lp,
    const float* __restrict__ f1, const float* __restrict__ gamma_ptr,
    float* __restrict__ sa)
{
    size_t idx = (size_t)blockIdx.x * 256 + threadIdx.x;   // over B*CI*NN
    const int n = (int)(idx & (NN - 1));
    const int b = (int)(idx >> 19);                        // CI*NN = 2^19

    float m[NSPLIT], l[NSPLIT];
    float M = -1e30f;
    #pragma unroll
    for (int s = 0; s < NSPLIT; ++s) {
        m[s] = mp[(size_t)(s * B + b) * NN + n];
        l[s] = lp[(size_t)(s * B + b) * NN + n];
        M = fmaxf(M, m[s]);
    }
    float L = 0.f, O = 0.f;
    #pragma unroll
    for (int s = 0; s < NSPLIT; ++s) {
        float ws = __expf(m[s] - M);
        L += l[s] * ws;
        O += op4.p[s][idx] * ws;
    }
    sa[idx] = (*gamma_ptr) * (O / L) + f1[idx];
}

// ---------------------------------------------------------------------------
// CAM energy, K-split partials (unchanged).
// ---------------------------------------------------------------------------
constexpr int ESPLIT = 16;
__global__ __launch_bounds__(256) void cam_energy_part(
    const float* __restrict__ f2, float* __restrict__ ep, int N)
{
    const int b = blockIdx.x;
    const int s = blockIdx.y;
    const float* fb = f2 + (size_t)b * CI * N;
    const int kbase = s * (NN / ESPLIT);

    __shared__ float fs[128][33];
    const int t  = threadIdx.x;
    const int ti = t >> 4;
    const int tj = t & 15;

    float acc[8][8] = {};
    for (int st = 0; st < (NN / ESPLIT) / 32; ++st) {
        const int k0 = kbase + st * 32;
        {
            const int ch  = t >> 1;
            const int k16 = (t & 1) * 16;
            const float* src = fb + (size_t)ch * N + k0 + k16;
            #pragma unroll
            for (int j = 0; j < 4; ++j)
                *reinterpret_cast<float4*>(&fs[ch][k16 + 4*j]) =
                    *reinterpret_cast<const float4*>(src + 4*j);
        }
        __syncthreads();
        #pragma unroll 4
        for (int k = 0; k < 32; ++k) {
            float av[8], bv[8];
            #pragma unroll
            for (int ii = 0; ii < 8; ++ii) av[ii] = fs[ti * 8 + ii][k];
            #pragma unroll
            for (int jj = 0; jj < 8; ++jj) bv[jj] = fs[tj * 8 + jj][k];
            #pragma unroll
            for (int ii = 0; ii < 8; ++ii)
                #pragma unroll
                for (int jj = 0; jj < 8; ++jj)
                    acc[ii][jj] += av[ii] * bv[jj];
        }
        __syncthreads();
    }
    float* dst = ep + ((size_t)(s * B + b)) * CI * CI;
    #pragma unroll
    for (int ii = 0; ii < 8; ++ii)
        #pragma unroll
        for (int jj = 0; jj < 8; ++jj)
            dst[(size_t)(ti * 8 + ii) * CI + tj * 8 + jj] = acc[ii][jj];
}

__global__ __launch_bounds__(256) void cam_energy_reduce(
    const float* __restrict__ ep, float* __restrict__ came)
{
    const size_t n = (size_t)B * CI * CI;
    size_t idx = (size_t)blockIdx.x * 256 + threadIdx.x;
    float s = 0.f;
    #pragma unroll
    for (int j = 0; j < ESPLIT; ++j) s += ep[j * n + idx];
    came[idx] = s;
}

// ---------------------------------------------------------------------------
// CAM softmax (unchanged): softmax(rowmax - e) == exp(rowmin - e)/sum.
// ---------------------------------------------------------------------------
__global__ __launch_bounds__(64) void cam_softmax(
    const float* __restrict__ e, float* __restrict__ attn)
{
    const int row = blockIdx.x;
    const float* er = e + (size_t)row * CI;
    const int t = threadIdx.x;
    float v0 = er[t], v1 = er[t + 64];
    float mn = fminf(v0, v1);
    #pragma unroll
    for (int off = 32; off; off >>= 1) mn = fminf(mn, __shfl_xor(mn, off));
    float p0 = __expf(mn - v0), p1 = __expf(mn - v1);
    float s = p0 + p1;
    #pragma unroll
    for (int off = 32; off; off >>= 1) s += __shfl_xor(s, off);
    float inv = 1.f / s;
    attn[(size_t)row * CI + t]      = p0 * inv;
    attn[(size_t)row * CI + t + 64] = p1 * inv;
}

// ---------------------------------------------------------------------------
extern "C" void kernel_launch(void* const* d_in, const int* in_sizes, int n_in,
                              void* d_out, int out_size, void* d_ws, size_t ws_size,
                              hipStream_t stream)
{
    const float* x    = (const float*)d_in[0];
    const float* Wa   = (const float*)d_in[1];
    const float* Wc   = (const float*)d_in[2];
    const float* Wq   = (const float*)d_in[3];
    const float* bq   = (const float*)d_in[4];
    const float* Wk   = (const float*)d_in[5];
    const float* bk   = (const float*)d_in[6];
    const float* Wv   = (const float*)d_in[7];
    const float* bv   = (const float*)d_in[8];
    const float* gpam = (const float*)d_in[9];
    const float* gcam = (const float*)d_in[10];
    const float* Wa1  = (const float*)d_in[11];
    const float* Wc1  = (const float*)d_in[12];
    const float* W1   = (const float*)d_in[13];
    const float* b1   = (const float*)d_in[14];
    const float* W2   = (const float*)d_in[15];
    const float* b2   = (const float*)d_in[16];
    const float* W3   = (const float*)d_in[17];
    const float* b3   = (const float*)d_in[18];
    float* out = (float*)d_out;

    // workspace layout (fp32 elements) — ~68 MB total
    const size_t PART = (size_t)B * CI * NN;   // 2,097,152
    float* ws    = (float*)d_ws;
    float* A     = ws;                 // [B,128,N]  (f1, later f2)
    float* Bv    = A  + PART;          // [B,128,N]  (v, later sa2/sc2)
    float* C     = Bv + PART;          // [B,128,N]  (sa, later sc)
    float* T     = C  + PART;          // [B,256,N] (t1+t2 acc; flash partials 0,1)
    float* Q     = T  + 2 * PART;      // [B,32,N]   524,288
    float* K2    = Q  + 524288;        // [B,32,N]   524,288
    float* came  = K2 + 524288;        // [B,128,128] 65,536
    float* cama  = came + 65536;       // [B,128,128] 65,536
    float* Ob    = cama + 65536;       // 2 x PART flash partials 2,3
    float* mpart = Ob + 2 * PART;      // [4][B][N]  65,536
    float* lpart = mpart + 65536;      // [4][B][N]  65,536
    float* epart = lpart + 65536;      // [16][B][128][128] 1,048,576

    Ptr4 op4;
    op4.p[0] = T;   op4.p[1] = T + PART;    // T dead until W1-conv
    op4.p[2] = Ob;  op4.p[3] = Ob + PART;   // dedicated

    const dim3 blk(256);
    auto grid_c = [](int Co) { return dim3(NN / 64, (Co + 63) / 64, B); };

    // ---- PAM branch ----
    conv_mfma<true><<<grid_c(CI), blk, 0, stream>>>(
        Wa, 0, x, A, nullptr, nullptr, nullptr, CI, CIN, NN);
    conv_mfma<false><<<grid_c(CQ), blk, 0, stream>>>(
        Wq, 0, A, Q, bq, nullptr, nullptr, CQ, CI, NN);
    conv_mfma<false><<<grid_c(CQ), blk, 0, stream>>>(
        Wk, 0, A, K2, bk, nullptr, nullptr, CQ, CI, NN);
    conv_mfma<false><<<grid_c(CI), blk, 0, stream>>>(
        Wv, 0, A, Bv, bv, nullptr, nullptr, CI, CI, NN);
    pam_flash_mfma<<<dim3(NN / 128, B, NSPLIT), blk, 0, stream>>>(
        Q, K2, Bv, op4, mpart, lpart, NN);
    pam_merge<<<dim3((B * CI * NN) / 256), blk, 0, stream>>>(
        op4, mpart, lpart, A, gpam, C);
    conv_mfma<true><<<grid_c(CI), blk, 0, stream>>>(
        Wa1, 0, C, Bv, nullptr, nullptr, nullptr, CI, CI, NN);
    conv_mfma<false><<<grid_c(COUT), blk, 0, stream>>>(
        W1, 0, Bv, T, b1, nullptr, nullptr, COUT, CI, NN);

    // ---- CAM branch ----
    conv_mfma<true><<<grid_c(CI), blk, 0, stream>>>(
        Wc, 0, x, A, nullptr, nullptr, nullptr, CI, CIN, NN);
    cam_energy_part<<<dim3(B, ESPLIT), blk, 0, stream>>>(A, epart, NN);
    cam_energy_reduce<<<dim3((B * CI * CI) / 256), blk, 0, stream>>>(epart, came);
    cam_softmax<<<dim3(B * CI), dim3(64), 0, stream>>>(came, cama);
    conv_mfma<false><<<grid_c(CI), blk, 0, stream>>>(
        cama, (long)CI * CI, A, C, nullptr, gcam, A, CI, CI, NN);
    conv_mfma<true><<<grid_c(CI), blk, 0, stream>>>(
        Wc1, 0, C, Bv, nullptr, nullptr, nullptr, CI, CI, NN);
    conv_mfma<false><<<grid_c(COUT), blk, 0, stream>>>(
        W2, 0, Bv, T, b2, nullptr, T, COUT, CI, NN);

    // ---- out = W3 @ T + b3 ----
    conv_mfma<false><<<grid_c(COUT), blk, 0, stream>>>(
        W3, 0, T, out, b3, nullptr, nullptr, COUT, COUT, NN);
}

// Round 14
// 234.386 us; speedup vs baseline: 5.2973x; 1.0765x over previous
//
#include <hip/hip_runtime.h>
#include <hip/hip_bf16.h>

// Problem constants (fixed by setup_inputs)
constexpr int B    = 4;
constexpr int CIN  = 512;
constexpr int NN   = 4096;
constexpr int CI   = 128;   // inter_channels
constexpr int CQ   = 32;    // PAM q/k dim
constexpr int COUT = 256;
constexpr int NSPLIT = 4;              // KV splits for pam flash
constexpr int KVLEN  = NN / NSPLIT;    // 1024 KV cols per split
constexpr int CQKV   = 192;            // fused q(32)+k(32)+v(128) channels

typedef __bf16 bf16x8 __attribute__((ext_vector_type(8)));
typedef __bf16 bf16x4 __attribute__((ext_vector_type(4)));
typedef float  f32x4  __attribute__((ext_vector_type(4)));

struct Ptr4 { float* p[4]; };

// ---------------------------------------------------------------------------
// MFMA 1x1-conv GEMM, plain bf16, fp32 out (unchanged from R10-R13).
// Block: 64 n x 64 co, 4 waves, BK=32. Grid: (N/64, ceil(Co/64), B).
// ---------------------------------------------------------------------------
template<bool RELU>
__global__ __launch_bounds__(256) void conv_mfma(
    const float* __restrict__ W, long wbs,
    const float* __restrict__ X,
    float* __restrict__ Y,
    const float* __restrict__ bias,
    const float* __restrict__ gamma_ptr,
    const float* __restrict__ resid,
    int Co, int K, int N)
{
    const int b   = blockIdx.z;
    const int n0  = blockIdx.x * 64;
    const int co0 = blockIdx.y * 64;
    const float* Wb = W + (size_t)b * wbs;
    const float* Xb = X + (size_t)b * K * N;

    __shared__ __bf16 Xs[64][40];   // [n][k] (transposed)
    __shared__ __bf16 Ws[64][40];   // [co][k]

    const int t    = threadIdx.x;
    const int w    = t >> 6;
    const int lane = t & 63;
    const int gq   = lane >> 4;   // 0..3
    const int c    = lane & 15;   // 0..15

    f32x4 acc[4];
    #pragma unroll
    for (int cb = 0; cb < 4; ++cb) acc[cb] = (f32x4){0.f, 0.f, 0.f, 0.f};

    for (int kb = 0; kb < K; kb += 32) {
        {
            const int k  = t >> 3;          // 0..31
            const int n8 = (t & 7) * 8;     // 0..56
            const float* src = Xb + (size_t)(kb + k) * N + n0 + n8;
            float4 f0 = *reinterpret_cast<const float4*>(src);
            float4 f1 = *reinterpret_cast<const float4*>(src + 4);
            float fv[8] = {f0.x, f0.y, f0.z, f0.w, f1.x, f1.y, f1.z, f1.w};
            #pragma unroll
            for (int j = 0; j < 8; ++j) Xs[n8 + j][k] = (__bf16)fv[j];
        }
        {
            const int co = t >> 2;          // 0..63
            const int kh = (t & 3) * 8;     // 0,8,16,24
            float fv[8];
            if (co0 + co < Co) {
                const float* src = Wb + (size_t)(co0 + co) * K + kb + kh;
                float4 f0 = *reinterpret_cast<const float4*>(src);
                float4 f1 = *reinterpret_cast<const float4*>(src + 4);
                fv[0]=f0.x; fv[1]=f0.y; fv[2]=f0.z; fv[3]=f0.w;
                fv[4]=f1.x; fv[5]=f1.y; fv[6]=f1.z; fv[7]=f1.w;
            } else {
                #pragma unroll
                for (int j = 0; j < 8; ++j) fv[j] = 0.f;
            }
            bf16x8 u;
            #pragma unroll
            for (int j = 0; j < 8; ++j) u[j] = (__bf16)fv[j];
            *reinterpret_cast<bf16x8*>(&Ws[co][kh]) = u;
        }
        __syncthreads();

        bf16x8 xa = *reinterpret_cast<const bf16x8*>(&Xs[16*w + c][gq * 8]);
        #pragma unroll
        for (int cb = 0; cb < 4; ++cb) {
            bf16x8 wf = *reinterpret_cast<const bf16x8*>(&Ws[16*cb + c][gq * 8]);
            acc[cb] = __builtin_amdgcn_mfma_f32_16x16x32_bf16(xa, wf, acc[cb], 0, 0, 0);
        }
        __syncthreads();
    }

    const float g = gamma_ptr ? *gamma_ptr : 1.f;
    const int nb = n0 + 16 * w + 4 * gq;
    #pragma unroll
    for (int cb = 0; cb < 4; ++cb) {
        int co = co0 + 16 * cb + c;
        if (co >= Co) continue;
        float bv = bias ? bias[co] : 0.f;
        size_t base = (size_t)(b * Co + co) * N + nb;
        float4 o;
        float* op = &o.x;
        #pragma unroll
        for (int r = 0; r < 4; ++r) {
            float val = acc[cb][r] + bv;
            if (RELU) val = fmaxf(val, 0.f);
            val *= g;
            op[r] = val;
        }
        if (resid) {
            float4 rv = *reinterpret_cast<const float4*>(&resid[base]);
            o.x += rv.x; o.y += rv.y; o.z += rv.z; o.w += rv.w;
        }
        *reinterpret_cast<float4*>(&Y[base]) = o;
    }
}

// ---------------------------------------------------------------------------
// Fused q/k/v conv, bf16 output. QKV[b][co][n], co: 0-31=q, 32-63=k, 64-191=v.
// Same geometry as conv_mfma (64x64 tiles), K=CI=128, grid (N/64, 3, B).
// bf16 output == identical rounding to the old fp32-store + in-flash convert.
// ---------------------------------------------------------------------------
__global__ __launch_bounds__(256) void conv_qkv(
    const float* __restrict__ Wq, const float* __restrict__ bq,
    const float* __restrict__ Wk, const float* __restrict__ bk,
    const float* __restrict__ Wv, const float* __restrict__ bv,
    const float* __restrict__ X, __bf16* __restrict__ QKV, int N)
{
    const int b   = blockIdx.z;
    const int n0  = blockIdx.x * 64;
    const int co0 = blockIdx.y * 64;
    const float* Xb = X + (size_t)b * CI * N;

    __shared__ __bf16 Xs[64][40];
    __shared__ __bf16 Ws[64][40];

    const int t    = threadIdx.x;
    const int w    = t >> 6;
    const int lane = t & 63;
    const int gq   = lane >> 4;
    const int c    = lane & 15;

    f32x4 acc[4];
    #pragma unroll
    for (int cb = 0; cb < 4; ++cb) acc[cb] = (f32x4){0.f, 0.f, 0.f, 0.f};

    for (int kb = 0; kb < CI; kb += 32) {
        {
            const int k  = t >> 3;
            const int n8 = (t & 7) * 8;
            const float* src = Xb + (size_t)(kb + k) * N + n0 + n8;
            float4 f0 = *reinterpret_cast<const float4*>(src);
            float4 f1 = *reinterpret_cast<const float4*>(src + 4);
            float fv[8] = {f0.x, f0.y, f0.z, f0.w, f1.x, f1.y, f1.z, f1.w};
            #pragma unroll
            for (int j = 0; j < 8; ++j) Xs[n8 + j][k] = (__bf16)fv[j];
        }
        {
            const int co = co0 + (t >> 2);   // 0..191
            const int kh = (t & 3) * 8;
            const float* src = (co < 32) ? (Wq + (size_t)co * CI)
                             : (co < 64) ? (Wk + (size_t)(co - 32) * CI)
                                         : (Wv + (size_t)(co - 64) * CI);
            src += kb + kh;
            float4 f0 = *reinterpret_cast<const float4*>(src);
            float4 f1 = *reinterpret_cast<const float4*>(src + 4);
            float fv[8] = {f0.x, f0.y, f0.z, f0.w, f1.x, f1.y, f1.z, f1.w};
            bf16x8 u;
            #pragma unroll
            for (int j = 0; j < 8; ++j) u[j] = (__bf16)fv[j];
            *reinterpret_cast<bf16x8*>(&Ws[t >> 2][kh]) = u;
        }
        __syncthreads();

        bf16x8 xa = *reinterpret_cast<const bf16x8*>(&Xs[16*w + c][gq * 8]);
        #pragma unroll
        for (int cb = 0; cb < 4; ++cb) {
            bf16x8 wf = *reinterpret_cast<const bf16x8*>(&Ws[16*cb + c][gq * 8]);
            acc[cb] = __builtin_amdgcn_mfma_f32_16x16x32_bf16(xa, wf, acc[cb], 0, 0, 0);
        }
        __syncthreads();
    }

    const int nb = n0 + 16 * w + 4 * gq;
    #pragma unroll
    for (int cb = 0; cb < 4; ++cb) {
        int co = co0 + 16 * cb + c;
        float bias = (co < 32) ? bq[co] : (co < 64) ? bk[co - 32] : bv[co - 64];
        bf16x4 o;
        #pragma unroll
        for (int r = 0; r < 4; ++r) o[r] = (__bf16)(acc[cb][r] + bias);
        *reinterpret_cast<bf16x4*>(&QKV[(size_t)(b * CQKV + co) * N + nb]) = o;
    }
}

// ---------------------------------------------------------------------------
// PAM flash attention partial v3: bf16 QKV input, swapped QK^T softmax,
// 16 q-rows per wave (64/block) -> 4096 waves = 50% occupancy ceiling.
// Grid (NN/64, B, NSPLIT), 256 thr / 4 waves, LDS 17.9 KB. No converts.
// Lane (g,c) holds S[m=16mb+4g+r][q=16w+c]; softmax = in-lane + 2 shfl.
// ---------------------------------------------------------------------------
__global__ __launch_bounds__(256) void pam_flash_mfma(
    const __bf16* __restrict__ qkv,
    Ptr4 op4,
    float* __restrict__ mp, float* __restrict__ lp, int N)
{
    const int b  = blockIdx.y;
    const int s  = blockIdx.z;
    const int n0 = blockIdx.x * 64;
    const __bf16* qb_ = qkv + (size_t)b * CQKV * N;
    const __bf16* kb_ = qb_ + (size_t)32 * N;
    const __bf16* vb_ = qb_ + (size_t)64 * N;
    float* Op = op4.p[s];

    __shared__ __bf16 Klds[32][40];    // [m][ck]  K^T tile
    __shared__ __bf16 Vlds[128][40];   // [vc][m]
    __shared__ __bf16 QP[64][40];      // Q stage [n][cq]; then P [q][m]

    const int t    = threadIdx.x;
    const int w    = t >> 6;
    const int lane = t & 63;
    const int g    = lane >> 4;   // 0..3
    const int c    = lane & 15;   // 0..15

    // ---- stage Q^T once (bf16 copy, no converts)
    {
        const int cq = t >> 3;         // 0..31
        const int nb = (t & 7) * 8;    // 0..56
        bf16x8 f = *reinterpret_cast<const bf16x8*>(&qb_[(size_t)cq * N + n0 + nb]);
        #pragma unroll
        for (int j = 0; j < 8; ++j) QP[nb + j][cq] = f[j];
    }
    __syncthreads();
    bf16x8 qa = *reinterpret_cast<const bf16x8*>(&QP[16*w + c][g * 8]);
    // QP becomes the P buffer; first P write is after the first in-loop barrier

    f32x4 acc[8];
    #pragma unroll
    for (int vbk = 0; vbk < 8; ++vbk) acc[vbk] = (f32x4){0.f, 0.f, 0.f, 0.f};
    float ms = -1e30f, ls = 0.f;   // per-lane state for q = 16w + c

    const int mstart = s * KVLEN;
    for (int mt = 0; mt < KVLEN / 32; ++mt) {
        const int m0 = mstart + mt * 32;
        // ---- stage K^T tile (bf16)
        {
            const int ck = t >> 3;       // 0..31
            const int m4 = (t & 7) * 4;
            bf16x4 f = *reinterpret_cast<const bf16x4*>(&kb_[(size_t)ck * N + m0 + m4]);
            #pragma unroll
            for (int j = 0; j < 4; ++j) Klds[m4 + j][ck] = f[j];
        }
        // ---- stage V tile (bf16 vector copy)
        {
            const int cv = t >> 1;       // 0..127
            const int mh = (t & 1) * 16;
            const __bf16* src = &vb_[(size_t)cv * N + m0 + mh];
            *reinterpret_cast<bf16x8*>(&Vlds[cv][mh])     = *reinterpret_cast<const bf16x8*>(src);
            *reinterpret_cast<bf16x8*>(&Vlds[cv][mh + 8]) = *reinterpret_cast<const bf16x8*>(src + 8);
        }
        __syncthreads();

        // ---- swapped QK^T: 2 MFMAs
        f32x4 sv[2];
        #pragma unroll
        for (int mb = 0; mb < 2; ++mb) {
            bf16x8 kf = *reinterpret_cast<const bf16x8*>(&Klds[16*mb + c][g * 8]);
            sv[mb] = __builtin_amdgcn_mfma_f32_16x16x32_bf16(
                kf, qa, (f32x4){0.f, 0.f, 0.f, 0.f}, 0, 0, 0);
        }

        // ---- online softmax over m (in-lane + 2 shfl)
        float mx = sv[0][0];
        #pragma unroll
        for (int r = 1; r < 4; ++r) mx = fmaxf(mx, sv[0][r]);
        #pragma unroll
        for (int r = 0; r < 4; ++r) mx = fmaxf(mx, sv[1][r]);
        mx = fmaxf(mx, __shfl_xor(mx, 16));
        mx = fmaxf(mx, __shfl_xor(mx, 32));
        float mnew = fmaxf(ms, mx);
        float scale = __expf(ms - mnew);
        ms = mnew;
        float psum = 0.f;
        #pragma unroll
        for (int mb = 0; mb < 2; ++mb)
            #pragma unroll
            for (int r = 0; r < 4; ++r) {
                float p = __expf(sv[mb][r] - mnew);
                sv[mb][r] = p;
                psum += p;
            }
        psum += __shfl_xor(psum, 16);
        psum += __shfl_xor(psum, 32);
        ls = ls * scale + psum;

        // ---- P -> LDS [q][m] (own wave's 16-row slice)
        #pragma unroll
        for (int mb = 0; mb < 2; ++mb)
            #pragma unroll
            for (int r = 0; r < 4; ++r)
                QP[16*w + c][16*mb + 4*g + r] = (__bf16)sv[mb][r];

        // ---- rescale acc (exact skip; acc row q-offset = 4g+r, scale at lane 4g+r)
        if (__any(scale != 1.0f)) {
            float sc[4];
            #pragma unroll
            for (int r = 0; r < 4; ++r) sc[r] = __shfl(scale, 4*g + r, 64);
            #pragma unroll
            for (int vbk = 0; vbk < 8; ++vbk)
                #pragma unroll
                for (int r = 0; r < 4; ++r) acc[vbk][r] *= sc[r];
        }

        // ---- PV: 8 MFMAs (same-wave DS ordering covers P read-after-write)
        bf16x8 pa = *reinterpret_cast<const bf16x8*>(&QP[16*w + c][g * 8]);
        #pragma unroll
        for (int vbk = 0; vbk < 8; ++vbk) {
            bf16x8 vf = *reinterpret_cast<const bf16x8*>(&Vlds[16*vbk + c][g * 8]);
            acc[vbk] = __builtin_amdgcn_mfma_f32_16x16x32_bf16(pa, vf, acc[vbk], 0, 0, 0);
        }
        __syncthreads();
    }

    // ---- epilogue: unnormalized partial O + per-row (m,l)
    #pragma unroll
    for (int vbk = 0; vbk < 8; ++vbk) {
        float4 o = { acc[vbk][0], acc[vbk][1], acc[vbk][2], acc[vbk][3] };
        *reinterpret_cast<float4*>(
            &Op[((size_t)(b * CI + 16*vbk + c)) * N + n0 + 16*w + 4*g]) = o;
    }
    if (g == 0) {
        int n = n0 + 16*w + c;
        mp[(size_t)(s * B + b) * N + n] = ms;
        lp[(size_t)(s * B + b) * N + n] = ls;
    }
}

// ---------------------------------------------------------------------------
// Merge NSPLIT=4 flash partials (unchanged).
// ---------------------------------------------------------------------------
__global__ __launch_bounds__(256) void pam_merge(
    Ptr4 op4,
    const float* __restrict__ mp, const float* __restrict__ lp,
    const float* __restrict__ f1, const float* __restrict__ gamma_ptr,
    float* __restrict__ sa)
{
    size_t idx = (size_t)blockIdx.x * 256 + threadIdx.x;   // over B*CI*NN
    const int n = (int)(idx & (NN - 1));
    const int b = (int)(idx >> 19);                        // CI*NN = 2^19

    float m[NSPLIT], l[NSPLIT];
    float M = -1e30f;
    #pragma unroll
    for (int s = 0; s < NSPLIT; ++s) {
        m[s] = mp[(size_t)(s * B + b) * NN + n];
        l[s] = lp[(size_t)(s * B + b) * NN + n];
        M = fmaxf(M, m[s]);
    }
    float L = 0.f, O = 0.f;
    #pragma unroll
    for (int s = 0; s < NSPLIT; ++s) {
        float ws = __expf(m[s] - M);
        L += l[s] * ws;
        O += op4.p[s][idx] * ws;
    }
    sa[idx] = (*gamma_ptr) * (O / L) + f1[idx];
}

// ---------------------------------------------------------------------------
// CAM energy, K-split partials (unchanged, fp32 exact).
// ---------------------------------------------------------------------------
constexpr int ESPLIT = 16;
__global__ __launch_bounds__(256) void cam_energy_part(
    const float* __restrict__ f2, float* __restrict__ ep, int N)
{
    const int b = blockIdx.x;
    const int s = blockIdx.y;
    const float* fb = f2 + (size_t)b * CI * N;
    const int kbase = s * (NN / ESPLIT);

    __shared__ float fs[128][33];
    const int t  = threadIdx.x;
    const int ti = t >> 4;
    const int tj = t & 15;

    float acc[8][8] = {};
    for (int st = 0; st < (NN / ESPLIT) / 32; ++st) {
        const int k0 = kbase + st * 32;
        {
            const int ch  = t >> 1;
            const int k16 = (t & 1) * 16;
            const float* src = fb + (size_t)ch * N + k0 + k16;
            #pragma unroll
            for (int j = 0; j < 4; ++j)
                *reinterpret_cast<float4*>(&fs[ch][k16 + 4*j]) =
                    *reinterpret_cast<const float4*>(src + 4*j);
        }
        __syncthreads();
        #pragma unroll 4
        for (int k = 0; k < 32; ++k) {
            float av[8], bv[8];
            #pragma unroll
            for (int ii = 0; ii < 8; ++ii) av[ii] = fs[ti * 8 + ii][k];
            #pragma unroll
            for (int jj = 0; jj < 8; ++jj) bv[jj] = fs[tj * 8 + jj][k];
            #pragma unroll
            for (int ii = 0; ii < 8; ++ii)
                #pragma unroll
                for (int jj = 0; jj < 8; ++jj)
                    acc[ii][jj] += av[ii] * bv[jj];
        }
        __syncthreads();
    }
    float* dst = ep + ((size_t)(s * B + b)) * CI * CI;
    #pragma unroll
    for (int ii = 0; ii < 8; ++ii)
        #pragma unroll
        for (int jj = 0; jj < 8; ++jj)
            dst[(size_t)(ti * 8 + ii) * CI + tj * 8 + jj] = acc[ii][jj];
}

__global__ __launch_bounds__(256) void cam_energy_reduce(
    const float* __restrict__ ep, float* __restrict__ came)
{
    const size_t n = (size_t)B * CI * CI;
    size_t idx = (size_t)blockIdx.x * 256 + threadIdx.x;
    float s = 0.f;
    #pragma unroll
    for (int j = 0; j < ESPLIT; ++j) s += ep[j * n + idx];
    came[idx] = s;
}

// ---------------------------------------------------------------------------
// CAM softmax (unchanged): softmax(rowmax - e) == exp(rowmin - e)/sum.
// ---------------------------------------------------------------------------
__global__ __launch_bounds__(64) void cam_softmax(
    const float* __restrict__ e, float* __restrict__ attn)
{
    const int row = blockIdx.x;
    const float* er = e + (size_t)row * CI;
    const int t = threadIdx.x;
    float v0 = er[t], v1 = er[t + 64];
    float mn = fminf(v0, v1);
    #pragma unroll
    for (int off = 32; off; off >>= 1) mn = fminf(mn, __shfl_xor(mn, off));
    float p0 = __expf(mn - v0), p1 = __expf(mn - v1);
    float s = p0 + p1;
    #pragma unroll
    for (int off = 32; off; off >>= 1) s += __shfl_xor(s, off);
    float inv = 1.f / s;
    attn[(size_t)row * CI + t]      = p0 * inv;
    attn[(size_t)row * CI + t + 64] = p1 * inv;
}

// ---------------------------------------------------------------------------
extern "C" void kernel_launch(void* const* d_in, const int* in_sizes, int n_in,
                              void* d_out, int out_size, void* d_ws, size_t ws_size,
                              hipStream_t stream)
{
    const float* x    = (const float*)d_in[0];
    const float* Wa   = (const float*)d_in[1];
    const float* Wc   = (const float*)d_in[2];
    const float* Wq   = (const float*)d_in[3];
    const float* bq   = (const float*)d_in[4];
    const float* Wk   = (const float*)d_in[5];
    const float* bk   = (const float*)d_in[6];
    const float* Wv   = (const float*)d_in[7];
    const float* bv   = (const float*)d_in[8];
    const float* gpam = (const float*)d_in[9];
    const float* gcam = (const float*)d_in[10];
    const float* Wa1  = (const float*)d_in[11];
    const float* Wc1  = (const float*)d_in[12];
    const float* W1   = (const float*)d_in[13];
    const float* b1   = (const float*)d_in[14];
    const float* W2   = (const float*)d_in[15];
    const float* b2   = (const float*)d_in[16];
    const float* W3   = (const float*)d_in[17];
    const float* b3   = (const float*)d_in[18];
    float* out = (float*)d_out;

    // workspace layout (fp32 elements) — ~70 MB total
    const size_t PART = (size_t)B * CI * NN;   // 2,097,152
    float* ws    = (float*)d_ws;
    float* A     = ws;                 // [B,128,N]  (f1, later f2)
    float* Bv    = A  + PART;          // [B,128,N]  (sa2/sc2 scratch)
    float* C     = Bv + PART;          // [B,128,N]  (sa, later sc)
    float* T     = C  + PART;          // [B,256,N] (t1+t2 acc; flash partials 0,1)
    float* came  = T  + 2 * PART;      // [B,128,128] 65,536
    float* cama  = came + 65536;       // [B,128,128] 65,536
    float* Ob    = cama + 65536;       // 2 x PART flash partials 2,3
    float* mpart = Ob + 2 * PART;      // [4][B][N]  65,536
    float* lpart = mpart + 65536;      // [4][B][N]  65,536
    float* epart = lpart + 65536;      // [16][B][128][128] 1,048,576
    __bf16* qkv  = (__bf16*)(epart + 1048576);  // [B][192][N] bf16, 6.3 MB

    Ptr4 op4;
    op4.p[0] = T;   op4.p[1] = T + PART;    // T dead until W1-conv
    op4.p[2] = Ob;  op4.p[3] = Ob + PART;   // dedicated

    const dim3 blk(256);
    auto grid_c = [](int Co) { return dim3(NN / 64, (Co + 63) / 64, B); };

    // ---- PAM branch ----
    conv_mfma<true><<<grid_c(CI), blk, 0, stream>>>(
        Wa, 0, x, A, nullptr, nullptr, nullptr, CI, CIN, NN);
    conv_qkv<<<dim3(NN / 64, 3, B), blk, 0, stream>>>(
        Wq, bq, Wk, bk, Wv, bv, A, qkv, NN);
    pam_flash_mfma<<<dim3(NN / 64, B, NSPLIT), blk, 0, stream>>>(
        qkv, op4, mpart, lpart, NN);
    pam_merge<<<dim3((B * CI * NN) / 256), blk, 0, stream>>>(
        op4, mpart, lpart, A, gpam, C);
    conv_mfma<true><<<grid_c(CI), blk, 0, stream>>>(
        Wa1, 0, C, Bv, nullptr, nullptr, nullptr, CI, CI, NN);
    conv_mfma<false><<<grid_c(COUT), blk, 0, stream>>>(
        W1, 0, Bv, T, b1, nullptr, nullptr, COUT, CI, NN);

    // ---- CAM branch ----
    conv_mfma<true><<<grid_c(CI), blk, 0, stream>>>(
        Wc, 0, x, A, nullptr, nullptr, nullptr, CI, CIN, NN);
    cam_energy_part<<<dim3(B, ESPLIT), blk, 0, stream>>>(A, epart, NN);
    cam_energy_reduce<<<dim3((B * CI * CI) / 256), blk, 0, stream>>>(epart, came);
    cam_softmax<<<dim3(B * CI), dim3(64), 0, stream>>>(came, cama);
    conv_mfma<false><<<grid_c(CI), blk, 0, stream>>>(
        cama, (long)CI * CI, A, C, nullptr, gcam, A, CI, CI, NN);
    conv_mfma<true><<<grid_c(CI), blk, 0, stream>>>(
        Wc1, 0, C, Bv, nullptr, nullptr, nullptr, CI, CI, NN);
    conv_mfma<false><<<grid_c(COUT), blk, 0, stream>>>(
        W2, 0, Bv, T, b2, nullptr, T, COUT, CI, NN);

    // ---- out = W3 @ T + b3 ----
    conv_mfma<false><<<grid_c(COUT), blk, 0, stream>>>(
        W3, 0, T, out, b3, nullptr, nullptr, COUT, COUT, NN);
}

// Round 15
// 195.123 us; speedup vs baseline: 6.3632x; 1.2012x over previous
//
#include <hip/hip_runtime.h>
#include <hip/hip_bf16.h>

// Problem constants (fixed by setup_inputs)
constexpr int B    = 4;
constexpr int CIN  = 512;
constexpr int NN   = 4096;
constexpr int CI   = 128;   // inter_channels
constexpr int CQ   = 32;    // PAM q/k dim
constexpr int COUT = 256;
constexpr int NSPLIT = 4;              // KV splits for pam flash
constexpr int KVLEN  = NN / NSPLIT;    // 1024 KV cols per split
constexpr int ESPLIT = 32;             // K splits for cam energy

typedef __bf16 bf16x8 __attribute__((ext_vector_type(8)));
typedef __bf16 bf16x4 __attribute__((ext_vector_type(4)));
typedef float  f32x4  __attribute__((ext_vector_type(4)));

struct Ptr4 { float* p[4]; };

// ---------------------------------------------------------------------------
// General MFMA 1x1-conv (bf16 compute, fp32 out). Used for attn-conv and W3.
// Block 64n x 64co, 4 waves, BK=32. Grid (N/64, Co/64, B).
// xbs/rbs = per-batch element strides of X / resid (for tensors embedded in
// larger channel blocks). Y stride = Co*N (natural).
// ---------------------------------------------------------------------------
template<bool RELU>
__global__ __launch_bounds__(256) void conv_mfma(
    const float* __restrict__ W, long wbs,
    const float* __restrict__ X, long xbs,
    float* __restrict__ Y,
    const float* __restrict__ bias,
    const float* __restrict__ gamma_ptr,
    const float* __restrict__ resid, long rbs,
    int Co, int K, int N)
{
    const int b   = blockIdx.z;
    const int n0  = blockIdx.x * 64;
    const int co0 = blockIdx.y * 64;
    const float* Wb = W + (size_t)b * wbs;
    const float* Xb = X + (size_t)b * xbs;

    __shared__ __bf16 Xs[64][40];
    __shared__ __bf16 Ws[64][40];

    const int t    = threadIdx.x;
    const int w    = t >> 6;
    const int lane = t & 63;
    const int gq   = lane >> 4;
    const int c    = lane & 15;

    f32x4 acc[4];
    #pragma unroll
    for (int cb = 0; cb < 4; ++cb) acc[cb] = (f32x4){0.f, 0.f, 0.f, 0.f};

    for (int kb = 0; kb < K; kb += 32) {
        {
            const int k  = t >> 3;
            const int n8 = (t & 7) * 8;
            const float* src = Xb + (size_t)(kb + k) * N + n0 + n8;
            float4 f0 = *reinterpret_cast<const float4*>(src);
            float4 f1 = *reinterpret_cast<const float4*>(src + 4);
            float fv[8] = {f0.x, f0.y, f0.z, f0.w, f1.x, f1.y, f1.z, f1.w};
            #pragma unroll
            for (int j = 0; j < 8; ++j) Xs[n8 + j][k] = (__bf16)fv[j];
        }
        {
            const int co = t >> 2;
            const int kh = (t & 3) * 8;
            const float* src = Wb + (size_t)(co0 + co) * K + kb + kh;
            float4 f0 = *reinterpret_cast<const float4*>(src);
            float4 f1 = *reinterpret_cast<const float4*>(src + 4);
            float fv[8] = {f0.x, f0.y, f0.z, f0.w, f1.x, f1.y, f1.z, f1.w};
            bf16x8 u;
            #pragma unroll
            for (int j = 0; j < 8; ++j) u[j] = (__bf16)fv[j];
            *reinterpret_cast<bf16x8*>(&Ws[co][kh]) = u;
        }
        __syncthreads();

        bf16x8 xa = *reinterpret_cast<const bf16x8*>(&Xs[16*w + c][gq * 8]);
        #pragma unroll
        for (int cb = 0; cb < 4; ++cb) {
            bf16x8 wf = *reinterpret_cast<const bf16x8*>(&Ws[16*cb + c][gq * 8]);
            acc[cb] = __builtin_amdgcn_mfma_f32_16x16x32_bf16(xa, wf, acc[cb], 0, 0, 0);
        }
        __syncthreads();
    }

    const float g = gamma_ptr ? *gamma_ptr : 1.f;
    const int nb = n0 + 16 * w + 4 * gq;
    #pragma unroll
    for (int cb = 0; cb < 4; ++cb) {
        int co = co0 + 16 * cb + c;
        float bv = bias ? bias[co] : 0.f;
        float4 o;
        float* op = &o.x;
        #pragma unroll
        for (int r = 0; r < 4; ++r) {
            float val = acc[cb][r] + bv;
            if (RELU) val = fmaxf(val, 0.f);
            val *= g;
            op[r] = val;
        }
        if (resid) {
            size_t roff = (size_t)b * rbs + (size_t)co * N + nb;
            float4 rv = *reinterpret_cast<const float4*>(&resid[roff]);
            o.x += rv.x; o.y += rv.y; o.z += rv.z; o.w += rv.w;
        }
        *reinterpret_cast<float4*>(&Y[(size_t)b * Co * N + (size_t)co * N + nb]) = o;
    }
}

// ---------------------------------------------------------------------------
// Dual conv: out rows [0,128) = relu(Wlo @ Xlo), [128,256) = relu(Whi @ Xhi).
// Used for (Wa,Wc)@x -> F and (Wa1@sa, Wc1@sc) -> S2. Co=256 fixed; grid.y=4.
// ---------------------------------------------------------------------------
template<bool RELU>
__global__ __launch_bounds__(256) void conv_dual(
    const float* __restrict__ Wlo, const float* __restrict__ Whi, int K,
    const float* __restrict__ Xlo, long xbslo,
    const float* __restrict__ Xhi, long xbshi,
    float* __restrict__ Y, long ybs, int N)
{
    const int b   = blockIdx.z;
    const int n0  = blockIdx.x * 64;
    const int co0 = blockIdx.y * 64;
    const bool lo = (co0 < 128);
    const float* Wb = lo ? (Wlo + (size_t)co0 * K) : (Whi + (size_t)(co0 - 128) * K);
    const float* Xb = lo ? (Xlo + (size_t)b * xbslo) : (Xhi + (size_t)b * xbshi);

    __shared__ __bf16 Xs[64][40];
    __shared__ __bf16 Ws[64][40];

    const int t    = threadIdx.x;
    const int w    = t >> 6;
    const int lane = t & 63;
    const int gq   = lane >> 4;
    const int c    = lane & 15;

    f32x4 acc[4];
    #pragma unroll
    for (int cb = 0; cb < 4; ++cb) acc[cb] = (f32x4){0.f, 0.f, 0.f, 0.f};

    for (int kb = 0; kb < K; kb += 32) {
        {
            const int k  = t >> 3;
            const int n8 = (t & 7) * 8;
            const float* src = Xb + (size_t)(kb + k) * N + n0 + n8;
            float4 f0 = *reinterpret_cast<const float4*>(src);
            float4 f1 = *reinterpret_cast<const float4*>(src + 4);
            float fv[8] = {f0.x, f0.y, f0.z, f0.w, f1.x, f1.y, f1.z, f1.w};
            #pragma unroll
            for (int j = 0; j < 8; ++j) Xs[n8 + j][k] = (__bf16)fv[j];
        }
        {
            const int co = t >> 2;
            const int kh = (t & 3) * 8;
            const float* src = Wb + (size_t)co * K + kb + kh;
            float4 f0 = *reinterpret_cast<const float4*>(src);
            float4 f1 = *reinterpret_cast<const float4*>(src + 4);
            float fv[8] = {f0.x, f0.y, f0.z, f0.w, f1.x, f1.y, f1.z, f1.w};
            bf16x8 u;
            #pragma unroll
            for (int j = 0; j < 8; ++j) u[j] = (__bf16)fv[j];
            *reinterpret_cast<bf16x8*>(&Ws[co][kh]) = u;
        }
        __syncthreads();

        bf16x8 xa = *reinterpret_cast<const bf16x8*>(&Xs[16*w + c][gq * 8]);
        #pragma unroll
        for (int cb = 0; cb < 4; ++cb) {
            bf16x8 wf = *reinterpret_cast<const bf16x8*>(&Ws[16*cb + c][gq * 8]);
            acc[cb] = __builtin_amdgcn_mfma_f32_16x16x32_bf16(xa, wf, acc[cb], 0, 0, 0);
        }
        __syncthreads();
    }

    const int nb = n0 + 16 * w + 4 * gq;
    #pragma unroll
    for (int cb = 0; cb < 4; ++cb) {
        int co = co0 + 16 * cb + c;
        float4 o;
        float* op = &o.x;
        #pragma unroll
        for (int r = 0; r < 4; ++r) {
            float val = acc[cb][r];
            if (RELU) val = fmaxf(val, 0.f);
            op[r] = val;
        }
        *reinterpret_cast<float4*>(&Y[(size_t)b * ybs + (size_t)co * N + nb]) = o;
    }
}

// ---------------------------------------------------------------------------
// Concat-K conv: T = W1 @ X[0:128] + W2 @ X[128:256] + b1 + b2.
// Co=256, K=256 (k<128 -> W1, else W2). Grid (N/64, 4, B).
// ---------------------------------------------------------------------------
__global__ __launch_bounds__(256) void conv_catk(
    const float* __restrict__ W1, const float* __restrict__ W2,
    const float* __restrict__ b1, const float* __restrict__ b2,
    const float* __restrict__ X, long xbs,
    float* __restrict__ Y, int N)
{
    const int b   = blockIdx.z;
    const int n0  = blockIdx.x * 64;
    const int co0 = blockIdx.y * 64;
    const float* Xb = X + (size_t)b * xbs;

    __shared__ __bf16 Xs[64][40];
    __shared__ __bf16 Ws[64][40];

    const int t    = threadIdx.x;
    const int w    = t >> 6;
    const int lane = t & 63;
    const int gq   = lane >> 4;
    const int c    = lane & 15;

    f32x4 acc[4];
    #pragma unroll
    for (int cb = 0; cb < 4; ++cb) acc[cb] = (f32x4){0.f, 0.f, 0.f, 0.f};

    for (int kb = 0; kb < 256; kb += 32) {
        {
            const int k  = t >> 3;
            const int n8 = (t & 7) * 8;
            const float* src = Xb + (size_t)(kb + k) * N + n0 + n8;
            float4 f0 = *reinterpret_cast<const float4*>(src);
            float4 f1 = *reinterpret_cast<const float4*>(src + 4);
            float fv[8] = {f0.x, f0.y, f0.z, f0.w, f1.x, f1.y, f1.z, f1.w};
            #pragma unroll
            for (int j = 0; j < 8; ++j) Xs[n8 + j][k] = (__bf16)fv[j];
        }
        {
            const int co = co0 + (t >> 2);
            const int kh = (t & 3) * 8;
            const int kcol = kb + kh;
            const float* src = (kcol < 128) ? (W1 + (size_t)co * 128 + kcol)
                                            : (W2 + (size_t)co * 128 + kcol - 128);
            float4 f0 = *reinterpret_cast<const float4*>(src);
            float4 f1 = *reinterpret_cast<const float4*>(src + 4);
            float fv[8] = {f0.x, f0.y, f0.z, f0.w, f1.x, f1.y, f1.z, f1.w};
            bf16x8 u;
            #pragma unroll
            for (int j = 0; j < 8; ++j) u[j] = (__bf16)fv[j];
            *reinterpret_cast<bf16x8*>(&Ws[t >> 2][kh]) = u;
        }
        __syncthreads();

        bf16x8 xa = *reinterpret_cast<const bf16x8*>(&Xs[16*w + c][gq * 8]);
        #pragma unroll
        for (int cb = 0; cb < 4; ++cb) {
            bf16x8 wf = *reinterpret_cast<const bf16x8*>(&Ws[16*cb + c][gq * 8]);
            acc[cb] = __builtin_amdgcn_mfma_f32_16x16x32_bf16(xa, wf, acc[cb], 0, 0, 0);
        }
        __syncthreads();
    }

    const int nb = n0 + 16 * w + 4 * gq;
    #pragma unroll
    for (int cb = 0; cb < 4; ++cb) {
        int co = co0 + 16 * cb + c;
        float bv = b1[co] + b2[co];
        float4 o = { acc[cb][0] + bv, acc[cb][1] + bv, acc[cb][2] + bv, acc[cb][3] + bv };
        *reinterpret_cast<float4*>(&Y[(size_t)b * 256 * N + (size_t)co * N + nb]) = o;
    }
}

// ---------------------------------------------------------------------------
// Fused q/k/v conv from f1 (= F rows 0-127, batch stride 256N).
// co<64: writes TRANSPOSED qkT[b][n][64] (cols 0-31 q, 32-63 k) bf16.
// co>=64: writes Vbuf[b][co-64][n] bf16.  Grid (N/64, 3, B).
// ---------------------------------------------------------------------------
__global__ __launch_bounds__(256) void conv_qkv(
    const float* __restrict__ Wq, const float* __restrict__ bq,
    const float* __restrict__ Wk, const float* __restrict__ bk,
    const float* __restrict__ Wv, const float* __restrict__ bv,
    const float* __restrict__ F, __bf16* __restrict__ qkT,
    __bf16* __restrict__ Vbuf, int N)
{
    const int b   = blockIdx.z;
    const int n0  = blockIdx.x * 64;
    const int co0 = blockIdx.y * 64;
    const float* Xb = F + (size_t)b * 256 * N;   // f1 rows 0-127

    __shared__ __bf16 Xs[64][40];
    __shared__ __bf16 Ws[64][40];

    const int t    = threadIdx.x;
    const int w    = t >> 6;
    const int lane = t & 63;
    const int gq   = lane >> 4;
    const int c    = lane & 15;

    f32x4 acc[4];
    #pragma unroll
    for (int cb = 0; cb < 4; ++cb) acc[cb] = (f32x4){0.f, 0.f, 0.f, 0.f};

    for (int kb = 0; kb < CI; kb += 32) {
        {
            const int k  = t >> 3;
            const int n8 = (t & 7) * 8;
            const float* src = Xb + (size_t)(kb + k) * N + n0 + n8;
            float4 f0 = *reinterpret_cast<const float4*>(src);
            float4 f1 = *reinterpret_cast<const float4*>(src + 4);
            float fv[8] = {f0.x, f0.y, f0.z, f0.w, f1.x, f1.y, f1.z, f1.w};
            #pragma unroll
            for (int j = 0; j < 8; ++j) Xs[n8 + j][k] = (__bf16)fv[j];
        }
        {
            const int co = co0 + (t >> 2);
            const int kh = (t & 3) * 8;
            const float* src = (co < 32) ? (Wq + (size_t)co * CI)
                             : (co < 64) ? (Wk + (size_t)(co - 32) * CI)
                                         : (Wv + (size_t)(co - 64) * CI);
            src += kb + kh;
            float4 f0 = *reinterpret_cast<const float4*>(src);
            float4 f1 = *reinterpret_cast<const float4*>(src + 4);
            float fv[8] = {f0.x, f0.y, f0.z, f0.w, f1.x, f1.y, f1.z, f1.w};
            bf16x8 u;
            #pragma unroll
            for (int j = 0; j < 8; ++j) u[j] = (__bf16)fv[j];
            *reinterpret_cast<bf16x8*>(&Ws[t >> 2][kh]) = u;
        }
        __syncthreads();

        bf16x8 xa = *reinterpret_cast<const bf16x8*>(&Xs[16*w + c][gq * 8]);
        #pragma unroll
        for (int cb = 0; cb < 4; ++cb) {
            bf16x8 wf = *reinterpret_cast<const bf16x8*>(&Ws[16*cb + c][gq * 8]);
            acc[cb] = __builtin_amdgcn_mfma_f32_16x16x32_bf16(xa, wf, acc[cb], 0, 0, 0);
        }
        __syncthreads();
    }

    const int nb = n0 + 16 * w + 4 * gq;
    #pragma unroll
    for (int cb = 0; cb < 4; ++cb) {
        int co = co0 + 16 * cb + c;
        float bias = (co < 32) ? bq[co] : (co < 64) ? bk[co - 32] : bv[co - 64];
        if (co < 64) {
            #pragma unroll
            for (int r = 0; r < 4; ++r)
                qkT[((size_t)b * NN + nb + r) * 64 + co] = (__bf16)(acc[cb][r] + bias);
        } else {
            bf16x4 o;
            #pragma unroll
            for (int r = 0; r < 4; ++r) o[r] = (__bf16)(acc[cb][r] + bias);
            *reinterpret_cast<bf16x4*>(&Vbuf[((size_t)b * CI + co - 64) * NN + nb]) = o;
        }
    }
}

// ---------------------------------------------------------------------------
// PAM flash v4: q/k A/B-frags loaded DIRECTLY from transposed qkT (global,
// L2-resident, zero LDS staging/converts). V double-buffered in LDS
// (1 barrier/tile). P packed bf16x4 b64 stores. Swapped QK^T softmax.
// Grid (NN/64, B, NSPLIT), 256 thr / 4 waves, 16 q-rows/wave, LDS 25.6 KB.
// ---------------------------------------------------------------------------
__global__ __launch_bounds__(256) void pam_flash_mfma(
    const __bf16* __restrict__ qkT, const __bf16* __restrict__ Vbuf,
    Ptr4 op4,
    float* __restrict__ mp, float* __restrict__ lp, int N)
{
    const int b  = blockIdx.y;
    const int s  = blockIdx.z;
    const int n0 = blockIdx.x * 64;
    float* Op = op4.p[s];

    __shared__ __bf16 Vlds[2][128][40];   // [buf][vc][m]
    __shared__ __bf16 QP[64][40];         // P [q][m] (per-wave slice)

    const int t    = threadIdx.x;
    const int w    = t >> 6;
    const int lane = t & 63;
    const int g    = lane >> 4;   // 0..3
    const int c    = lane & 15;   // 0..15

    // Q fragment: direct global (B-operand: col=q, k=cq)
    bf16x8 qa = *reinterpret_cast<const bf16x8*>(
        &qkT[((size_t)b * NN + n0 + 16*w + c) * 64 + g * 8]);

    f32x4 acc[8];
    #pragma unroll
    for (int vbk = 0; vbk < 8; ++vbk) acc[vbk] = (f32x4){0.f, 0.f, 0.f, 0.f};
    float ms = -1e30f, ls = 0.f;   // per-lane state for q = 16w + c

    const int mstart = s * KVLEN;
    const int NT = KVLEN / 32;

    auto stageV = [&](int mt, int buf) {
        const int cv = t >> 1;
        const int mh = (t & 1) * 16;
        const __bf16* src = &Vbuf[((size_t)b * CI + cv) * NN + mstart + mt * 32 + mh];
        *reinterpret_cast<bf16x8*>(&Vlds[buf][cv][mh])     = *reinterpret_cast<const bf16x8*>(src);
        *reinterpret_cast<bf16x8*>(&Vlds[buf][cv][mh + 8]) = *reinterpret_cast<const bf16x8*>(src + 8);
    };

    stageV(0, 0);
    __syncthreads();

    for (int mt = 0; mt < NT; ++mt) {
        const int buf = mt & 1;
        const int m0  = mstart + mt * 32;
        if (mt + 1 < NT) stageV(mt + 1, buf ^ 1);

        // ---- swapped QK^T: kf direct global; 2 MFMAs
        f32x4 sv[2];
        #pragma unroll
        for (int mb = 0; mb < 2; ++mb) {
            bf16x8 kf = *reinterpret_cast<const bf16x8*>(
                &qkT[((size_t)b * NN + m0 + 16*mb + c) * 64 + 32 + g * 8]);
            sv[mb] = __builtin_amdgcn_mfma_f32_16x16x32_bf16(
                kf, qa, (f32x4){0.f, 0.f, 0.f, 0.f}, 0, 0, 0);
        }

        // ---- online softmax over m (in-lane + 2 shfl)
        float mx = sv[0][0];
        #pragma unroll
        for (int r = 1; r < 4; ++r) mx = fmaxf(mx, sv[0][r]);
        #pragma unroll
        for (int r = 0; r < 4; ++r) mx = fmaxf(mx, sv[1][r]);
        mx = fmaxf(mx, __shfl_xor(mx, 16));
        mx = fmaxf(mx, __shfl_xor(mx, 32));
        float mnew = fmaxf(ms, mx);
        float scale = __expf(ms - mnew);
        ms = mnew;
        float psum = 0.f;
        #pragma unroll
        for (int mb = 0; mb < 2; ++mb)
            #pragma unroll
            for (int r = 0; r < 4; ++r) {
                float p = __expf(sv[mb][r] - mnew);
                sv[mb][r] = p;
                psum += p;
            }
        psum += __shfl_xor(psum, 16);
        psum += __shfl_xor(psum, 32);
        ls = ls * scale + psum;

        // ---- P -> LDS [q][m], packed b64 stores (cols 16mb+4g..+3)
        #pragma unroll
        for (int mb = 0; mb < 2; ++mb) {
            bf16x4 pk;
            #pragma unroll
            for (int r = 0; r < 4; ++r) pk[r] = (__bf16)sv[mb][r];
            *reinterpret_cast<bf16x4*>(&QP[16*w + c][16*mb + 4*g]) = pk;
        }

        // ---- rescale acc (exact skip)
        if (__any(scale != 1.0f)) {
            float sc[4];
            #pragma unroll
            for (int r = 0; r < 4; ++r) sc[r] = __shfl(scale, 4*g + r, 64);
            #pragma unroll
            for (int vbk = 0; vbk < 8; ++vbk)
                #pragma unroll
                for (int r = 0; r < 4; ++r) acc[vbk][r] *= sc[r];
        }

        // ---- PV: 8 MFMAs (same-wave DS ordering covers P RAW)
        bf16x8 pa = *reinterpret_cast<const bf16x8*>(&QP[16*w + c][g * 8]);
        #pragma unroll
        for (int vbk = 0; vbk < 8; ++vbk) {
            bf16x8 vf = *reinterpret_cast<const bf16x8*>(&Vlds[buf][16*vbk + c][g * 8]);
            acc[vbk] = __builtin_amdgcn_mfma_f32_16x16x32_bf16(pa, vf, acc[vbk], 0, 0, 0);
        }
        __syncthreads();
    }

    // ---- epilogue: unnormalized partial O + per-row (m,l)
    #pragma unroll
    for (int vbk = 0; vbk < 8; ++vbk) {
        float4 o = { acc[vbk][0], acc[vbk][1], acc[vbk][2], acc[vbk][3] };
        *reinterpret_cast<float4*>(
            &Op[((size_t)(b * CI + 16*vbk + c)) * N + n0 + 16*w + 4*g]) = o;
    }
    if (g == 0) {
        int n = n0 + 16*w + c;
        mp[(size_t)(s * B + b) * N + n] = ms;
        lp[(size_t)(s * B + b) * N + n] = ls;
    }
}

// ---------------------------------------------------------------------------
// Merge NSPLIT=4 partials; writes sa IN-PLACE into f1 (F rows 0-127).
// Each element read+written by its own thread only -> race-free.
// ---------------------------------------------------------------------------
__global__ __launch_bounds__(256) void pam_merge(
    Ptr4 op4,
    const float* __restrict__ mp, const float* __restrict__ lp,
    float* __restrict__ F, const float* __restrict__ gamma_ptr)
{
    size_t idx = (size_t)blockIdx.x * 256 + threadIdx.x;   // over B*CI*NN
    const int n = (int)(idx & (NN - 1));
    const int b = (int)(idx >> 19);                        // CI*NN = 2^19

    float m[NSPLIT], l[NSPLIT];
    float M = -1e30f;
    #pragma unroll
    for (int s = 0; s < NSPLIT; ++s) {
        m[s] = mp[(size_t)(s * B + b) * NN + n];
        l[s] = lp[(size_t)(s * B + b) * NN + n];
        M = fmaxf(M, m[s]);
    }
    float L = 0.f, O = 0.f;
    #pragma unroll
    for (int s = 0; s < NSPLIT; ++s) {
        float ws = __expf(m[s] - M);
        L += l[s] * ws;
        O += op4.p[s][idx] * ws;
    }
    size_t foff = (size_t)b * (256 * (size_t)NN) + (idx & ((1u << 19) - 1));
    F[foff] = (*gamma_ptr) * (O / L) + F[foff];
}

// ---------------------------------------------------------------------------
// CAM energy, K-split partials (strided f2 input).
// ---------------------------------------------------------------------------
__global__ __launch_bounds__(256) void cam_energy_part(
    const float* __restrict__ f2, long f2bs, float* __restrict__ ep, int N)
{
    const int b = blockIdx.x;
    const int s = blockIdx.y;
    const float* fb = f2 + (size_t)b * f2bs;
    const int kbase = s * (NN / ESPLIT);

    __shared__ float fs[128][33];
    const int t  = threadIdx.x;
    const int ti = t >> 4;
    const int tj = t & 15;

    float acc[8][8] = {};
    for (int st = 0; st < (NN / ESPLIT) / 32; ++st) {
        const int k0 = kbase + st * 32;
        {
            const int ch  = t >> 1;
            const int k16 = (t & 1) * 16;
            const float* src = fb + (size_t)ch * N + k0 + k16;
            #pragma unroll
            for (int j = 0; j < 4; ++j)
                *reinterpret_cast<float4*>(&fs[ch][k16 + 4*j]) =
                    *reinterpret_cast<const float4*>(src + 4*j);
        }
        __syncthreads();
        #pragma unroll 4
        for (int k = 0; k < 32; ++k) {
            float av[8], bv[8];
            #pragma unroll
            for (int ii = 0; ii < 8; ++ii) av[ii] = fs[ti * 8 + ii][k];
            #pragma unroll
            for (int jj = 0; jj < 8; ++jj) bv[jj] = fs[tj * 8 + jj][k];
            #pragma unroll
            for (int ii = 0; ii < 8; ++ii)
                #pragma unroll
                for (int jj = 0; jj < 8; ++jj)
                    acc[ii][jj] += av[ii] * bv[jj];
        }
        __syncthreads();
    }
    float* dst = ep + ((size_t)(s * B + b)) * CI * CI;
    #pragma unroll
    for (int ii = 0; ii < 8; ++ii)
        #pragma unroll
        for (int jj = 0; jj < 8; ++jj)
            dst[(size_t)(ti * 8 + ii) * CI + tj * 8 + jj] = acc[ii][jj];
}

__global__ __launch_bounds__(256) void cam_energy_reduce(
    const float* __restrict__ ep, float* __restrict__ came)
{
    const size_t n = (size_t)B * CI * CI;
    size_t idx = (size_t)blockIdx.x * 256 + threadIdx.x;
    float s = 0.f;
    #pragma unroll
    for (int j = 0; j < ESPLIT; ++j) s += ep[j * n + idx];
    came[idx] = s;
}

// ---------------------------------------------------------------------------
// CAM softmax: softmax(rowmax - e) == exp(rowmin - e)/sum.
// ---------------------------------------------------------------------------
__global__ __launch_bounds__(64) void cam_softmax(
    const float* __restrict__ e, float* __restrict__ attn)
{
    const int row = blockIdx.x;
    const float* er = e + (size_t)row * CI;
    const int t = threadIdx.x;
    float v0 = er[t], v1 = er[t + 64];
    float mn = fminf(v0, v1);
    #pragma unroll
    for (int off = 32; off; off >>= 1) mn = fminf(mn, __shfl_xor(mn, off));
    float p0 = __expf(mn - v0), p1 = __expf(mn - v1);
    float s = p0 + p1;
    #pragma unroll
    for (int off = 32; off; off >>= 1) s += __shfl_xor(s, off);
    float inv = 1.f / s;
    attn[(size_t)row * CI + t]      = p0 * inv;
    attn[(size_t)row * CI + t + 64] = p1 * inv;
}

// ---------------------------------------------------------------------------
extern "C" void kernel_launch(void* const* d_in, const int* in_sizes, int n_in,
                              void* d_out, int out_size, void* d_ws, size_t ws_size,
                              hipStream_t stream)
{
    const float* x    = (const float*)d_in[0];
    const float* Wa   = (const float*)d_in[1];
    const float* Wc   = (const float*)d_in[2];
    const float* Wq   = (const float*)d_in[3];
    const float* bq   = (const float*)d_in[4];
    const float* Wk   = (const float*)d_in[5];
    const float* bk   = (const float*)d_in[6];
    const float* Wv   = (const float*)d_in[7];
    const float* bv   = (const float*)d_in[8];
    const float* gpam = (const float*)d_in[9];
    const float* gcam = (const float*)d_in[10];
    const float* Wa1  = (const float*)d_in[11];
    const float* Wc1  = (const float*)d_in[12];
    const float* W1   = (const float*)d_in[13];
    const float* b1   = (const float*)d_in[14];
    const float* W2   = (const float*)d_in[15];
    const float* b2   = (const float*)d_in[16];
    const float* W3   = (const float*)d_in[17];
    const float* b3   = (const float*)d_in[18];
    float* out = (float*)d_out;

    // workspace layout (fp32 elements) — ~66 MB
    const size_t PART = (size_t)B * CI * NN;   // 2,097,152
    float* ws    = (float*)d_ws;
    float* F     = ws;                 // [B,256,N]: rows 0-127 f1 (later sa), 128-255 f2
    float* S2    = F  + 2 * PART;      // [B,256,N]: sa2 | sc2  (early: epart alias)
    float* Csc   = S2 + 2 * PART;      // [B,128,N]: sc
    float* T     = Csc + PART;         // [B,256,N]: Tcat out; flash partials 0,1
    float* mpart = T  + 2 * PART;      // [4][B][N]  65,536
    float* lpart = mpart + 65536;      // [4][B][N]  65,536
    float* came  = lpart + 65536;      // [B,128,128] 65,536
    float* cama  = came + 65536;       // [B,128,128] 65,536
    __bf16* qkT  = (__bf16*)(cama + 65536);      // [B][N][64] bf16   (524,288 f32-eq)
    __bf16* Vbuf = (__bf16*)(cama + 65536 + 524288); // [B][128][N] bf16 (1,048,576 f32-eq)
    float* epart = S2;                 // [32][B][128][128] = 2.1M, dead before S2 written

    Ptr4 op4;
    op4.p[0] = T;    op4.p[1] = T + PART;     // T dead until conv_catk
    op4.p[2] = out;  op4.p[3] = out + PART;   // d_out overwritten by W3 at the end

    const dim3 blk(256);

    // 1. F = relu([Wa;Wc] @ x)  (x read once)
    conv_dual<true><<<dim3(NN / 64, 4, B), blk, 0, stream>>>(
        Wa, Wc, CIN, x, (long)CIN * NN, x, (long)CIN * NN, F, (long)256 * NN, NN);
    // 2. qkT + Vbuf from f1
    conv_qkv<<<dim3(NN / 64, 3, B), blk, 0, stream>>>(
        Wq, bq, Wk, bk, Wv, bv, F, qkT, Vbuf, NN);
    // 3. flash partials
    pam_flash_mfma<<<dim3(NN / 64, B, NSPLIT), blk, 0, stream>>>(
        qkT, Vbuf, op4, mpart, lpart, NN);
    // 4. merge -> sa in-place into F rows 0-127
    pam_merge<<<dim3((B * CI * NN) / 256), blk, 0, stream>>>(
        op4, mpart, lpart, F, gpam);
    // 5. CAM energy (f2 = F rows 128+), partials into epart (alias S2)
    cam_energy_part<<<dim3(B, ESPLIT), blk, 0, stream>>>(
        F + (size_t)128 * NN, (long)256 * NN, epart, NN);
    cam_energy_reduce<<<dim3((B * CI * CI) / 256), blk, 0, stream>>>(epart, came);
    cam_softmax<<<dim3(B * CI), dim3(64), 0, stream>>>(came, cama);
    // 6. sc = gamma_cam * (attn @ f2) + f2 -> Csc
    conv_mfma<false><<<dim3(NN / 64, 2, B), blk, 0, stream>>>(
        cama, (long)CI * CI, F + (size_t)128 * NN, (long)256 * NN, Csc,
        nullptr, gcam, F + (size_t)128 * NN, (long)256 * NN, CI, CI, NN);
    // 7. S2 = [relu(Wa1@sa) ; relu(Wc1@sc)]
    conv_dual<true><<<dim3(NN / 64, 4, B), blk, 0, stream>>>(
        Wa1, Wc1, CI, F, (long)256 * NN, Csc, (long)CI * NN, S2, (long)256 * NN, NN);
    // 8. T = [W1 W2] @ S2 + b1 + b2
    conv_catk<<<dim3(NN / 64, 4, B), blk, 0, stream>>>(
        W1, W2, b1, b2, S2, (long)256 * NN, T, NN);
    // 9. out = W3 @ T + b3
    conv_mfma<false><<<dim3(NN / 64, 4, B), blk, 0, stream>>>(
        W3, 0, T, (long)COUT * NN, out, b3, nullptr, nullptr, 0, COUT, COUT, NN);
}